// Round 1
// baseline (5937.051 us; speedup 1.0000x reference)
//
#include <hip/hip_runtime.h>
#include <math.h>

// ---- problem constants ----
#define NTOK    4096      // B*S
#define DMODEL  512
#define NEXP    32
#define RRANK   64
#define HEXP    512
#define HSHARED 4096
#define SEQ     1024
#define BATCH   4
#define NHEAD   8
#define TOPK    4
#define NLAYER  2

__device__ __forceinline__ float gelu_f(float x) {
    // jax.nn.gelu(approximate=True): 0.5*x*(1+tanh(sqrt(2/pi)*(x+0.044715x^3)))
    float t = tanhf(0.7978845608028654f * (x + 0.044715f * x * x * x));
    return 0.5f * x * (1.f + t);
}

// ---------------- LayerNorm: one wave (64 lanes) per row of 512 ----------------
__global__ __launch_bounds__(256) void ln_kernel(const float* __restrict__ x,
                                                 const float* __restrict__ s,
                                                 const float* __restrict__ b,
                                                 float* __restrict__ out) {
    int wave = threadIdx.x >> 6, lane = threadIdx.x & 63;
    int row = blockIdx.x * 4 + wave;
    const float* xr = x + (size_t)row * DMODEL;
    float v[8];
    float sum = 0.f;
#pragma unroll
    for (int i = 0; i < 8; i++) { v[i] = xr[lane + i * 64]; sum += v[i]; }
#pragma unroll
    for (int o = 32; o; o >>= 1) sum += __shfl_xor(sum, o);
    float m = sum * (1.f / DMODEL);
    float vs = 0.f;
#pragma unroll
    for (int i = 0; i < 8; i++) { float d = v[i] - m; vs += d * d; }
#pragma unroll
    for (int o = 32; o; o >>= 1) vs += __shfl_xor(vs, o);
    float rstd = rsqrtf(vs * (1.f / DMODEL) + 1e-5f);
    float* orow = out + (size_t)row * DMODEL;
#pragma unroll
    for (int i = 0; i < 8; i++) {
        int c = lane + i * 64;
        orow[c] = (v[i] - m) * rstd * s[c] + b[c];
    }
}

// ---------------- generic tiled fp32 GEMM: C = A @ W (+bias)(+gelu)(+res) ----------------
// 64x64 tile, K-step 16, 256 threads, 4x4 acc per thread.
// GATHER: A row index via rowmap. EXPERT: per-expert M/W/bias/C from cnt/off (blockIdx.z = expert).
template <bool GELU, bool DORES, bool GATHER, bool EXPERT>
__global__ __launch_bounds__(256) void gemm_tile(
    const float* __restrict__ A, const float* __restrict__ W,
    const float* __restrict__ bias, const float* __restrict__ res,
    float* __restrict__ C, int M, int Nn, int Kk, int lda,
    const int* __restrict__ rowmap, const int* __restrict__ cntp,
    const int* __restrict__ offp) {
    int n0 = blockIdx.x * 64;
    int m0 = blockIdx.y * 64;
    if (EXPERT) {
        int e = blockIdx.z;
        M = cntp[e];
        if (m0 >= M) return;
        W += (size_t)e * Kk * Nn;
        bias += (size_t)e * Nn;
        int oe = offp[e];
        C += (size_t)oe * Nn;
        if (GATHER) rowmap += oe; else A += (size_t)oe * lda;
    }
    __shared__ float As[16][68];
    __shared__ float Ws[16][68];
    int tid = threadIdx.x;
    int ml = tid >> 2, kl = (tid & 3) << 2;           // A loader: 64 rows x 16 k
    bool avalid = (m0 + ml) < M;
    int arow = m0 + ml;
    if (GATHER) arow = avalid ? rowmap[arow] : 0;
    const float* aptr = A + (size_t)arow * lda + kl;
    int kr = tid >> 4, nc = (tid & 15) << 2;          // W loader: 16 k x 64 cols
    bool wvalid = (n0 + nc) < Nn;
    const float* wptr = W + (size_t)kr * Nn + n0 + nc;
    int tm = (tid >> 4) << 2, tn = (tid & 15) << 2;
    float acc[4][4] = {{0.f}};
    for (int k0 = 0; k0 < Kk; k0 += 16) {
        float4 av = make_float4(0.f, 0.f, 0.f, 0.f);
        float4 wv = make_float4(0.f, 0.f, 0.f, 0.f);
        if (avalid) av = *(const float4*)(aptr + k0);
        if (wvalid) wv = *(const float4*)(wptr + (size_t)k0 * Nn);
        As[kl + 0][ml] = av.x; As[kl + 1][ml] = av.y;
        As[kl + 2][ml] = av.z; As[kl + 3][ml] = av.w;
        *(float4*)&Ws[kr][nc] = wv;
        __syncthreads();
#pragma unroll
        for (int kk = 0; kk < 16; kk++) {
            float4 a4 = *(const float4*)&As[kk][tm];
            float4 w4 = *(const float4*)&Ws[kk][tn];
            acc[0][0] += a4.x * w4.x; acc[0][1] += a4.x * w4.y; acc[0][2] += a4.x * w4.z; acc[0][3] += a4.x * w4.w;
            acc[1][0] += a4.y * w4.x; acc[1][1] += a4.y * w4.y; acc[1][2] += a4.y * w4.z; acc[1][3] += a4.y * w4.w;
            acc[2][0] += a4.z * w4.x; acc[2][1] += a4.z * w4.y; acc[2][2] += a4.z * w4.z; acc[2][3] += a4.z * w4.w;
            acc[3][0] += a4.w * w4.x; acc[3][1] += a4.w * w4.y; acc[3][2] += a4.w * w4.z; acc[3][3] += a4.w * w4.w;
        }
        __syncthreads();
    }
#pragma unroll
    for (int i = 0; i < 4; i++) {
        int mm = m0 + tm + i;
        if (mm >= M) break;
        float* crow = C + (size_t)mm * Nn;
#pragma unroll
        for (int j = 0; j < 4; j++) {
            int nn = n0 + tn + j;
            if (nn >= Nn) continue;
            float val = acc[i][j];
            if (bias) val += bias[nn];
            if (GELU) val = gelu_f(val);
            if (DORES) val += res[(size_t)mm * Nn + nn];
            crow[nn] = val;
        }
    }
}

// ---------------- attention: one block per (b, h, q_row); full softmax over S=1024 ----------------
__global__ __launch_bounds__(256) void attn_kernel(const float* __restrict__ Q,
                                                   const float* __restrict__ Kb,
                                                   const float* __restrict__ Vb,
                                                   float* __restrict__ O) {
    int qi = blockIdx.x, hh = blockIdx.y, bb = blockIdx.z;
    __shared__ float qs[64];
    __shared__ float sc[SEQ];
    __shared__ float red[8];
    __shared__ float obuf[4][64];
    size_t headbase = (size_t)bb * SEQ * DMODEL + hh * 64;
    int tid = threadIdx.x;
    if (tid < 64) qs[tid] = Q[headbase + (size_t)qi * DMODEL + tid];
    __syncthreads();
    // pass 1: scores + local max
    float lmax = -1e30f;
    for (int j = tid; j < SEQ; j += 256) {
        const float* kr = Kb + headbase + (size_t)j * DMODEL;
        float a = 0.f;
#pragma unroll
        for (int d = 0; d < 64; d += 4) {
            float4 kv = *(const float4*)(kr + d);
            a += qs[d] * kv.x + qs[d + 1] * kv.y + qs[d + 2] * kv.z + qs[d + 3] * kv.w;
        }
        a *= 0.125f;   // 1/sqrt(64)
        sc[j] = a;
        lmax = fmaxf(lmax, a);
    }
#pragma unroll
    for (int o = 32; o; o >>= 1) lmax = fmaxf(lmax, __shfl_xor(lmax, o));
    if ((tid & 63) == 0) red[tid >> 6] = lmax;
    __syncthreads();
    float bmax = fmaxf(fmaxf(red[0], red[1]), fmaxf(red[2], red[3]));
    // pass 2: exp + sum
    float lsum = 0.f;
    for (int j = tid; j < SEQ; j += 256) {
        float e = __expf(sc[j] - bmax);
        sc[j] = e;
        lsum += e;
    }
#pragma unroll
    for (int o = 32; o; o >>= 1) lsum += __shfl_xor(lsum, o);
    if ((tid & 63) == 0) red[4 + (tid >> 6)] = lsum;
    __syncthreads();
    float inv = 1.f / (red[4] + red[5] + red[6] + red[7]);
    // pass 3: O = P @ V ; thread owns (d = tid&63), partial j-range per wave
    int d = tid & 63, part = tid >> 6;
    const float* vcol = Vb + headbase + d;
    float acc = 0.f;
    int j0 = part * 256;
    for (int j = j0; j < j0 + 256; ++j) acc += sc[j] * vcol[(size_t)j * DMODEL];
    obuf[part][d] = acc;
    __syncthreads();
    if (tid < 64) {
        float r = (obuf[0][tid] + obuf[1][tid] + obuf[2][tid] + obuf[3][tid]) * inv;
        O[headbase + (size_t)qi * DMODEL + tid] = r;
    }
}

// ---------------- router: softmax over 32, top-4, renorm; aux-loss accumulators ----------------
__global__ __launch_bounds__(256) void router_topk(const float* __restrict__ rsc,
                                                   float* __restrict__ topw,
                                                   int* __restrict__ topi,
                                                   int* __restrict__ cnt,
                                                   float* __restrict__ sumP,
                                                   float* __restrict__ zacc) {
    int n = blockIdx.x * blockDim.x + threadIdx.x;
    if (n >= NTOK) return;
    float sc[NEXP];
    float mx = -1e30f;
#pragma unroll
    for (int e = 0; e < NEXP; e++) { sc[e] = rsc[n * NEXP + e]; mx = fmaxf(mx, sc[e]); }
    float se = 0.f;
#pragma unroll
    for (int e = 0; e < NEXP; e++) { sc[e] = expf(sc[e] - mx); se += sc[e]; }
    float invse = 1.f / se;
    float lse = mx + logf(se);
    atomicAdd(zacc, lse * lse);
#pragma unroll
    for (int e = 0; e < NEXP; e++) atomicAdd(&sumP[e], sc[e] * invse);
    float tv[TOPK]; int ti[TOPK];
#pragma unroll
    for (int k = 0; k < TOPK; k++) {
        float best = -1.f; int bi = 0;
#pragma unroll
        for (int e = 0; e < NEXP; e++) {
            if (sc[e] > best) { best = sc[e]; bi = e; }
        }
        tv[k] = best * invse; ti[k] = bi; sc[bi] = -1.f;
    }
    float s4 = tv[0] + tv[1] + tv[2] + tv[3];
#pragma unroll
    for (int k = 0; k < TOPK; k++) {
        topw[n * TOPK + k] = tv[k] / s4;
        topi[n * TOPK + k] = ti[k];
        atomicAdd(&cnt[ti[k]], 1);
    }
}

__global__ void scan_kernel(const int* __restrict__ cnt, int* __restrict__ off) {
    int a = 0;
    for (int e = 0; e < NEXP; e++) { off[e] = a; a += cnt[e]; }
}

__global__ __launch_bounds__(256) void scatter_kernel(const int* __restrict__ topi,
                                                      const int* __restrict__ off,
                                                      int* __restrict__ cursor,
                                                      int* __restrict__ perm,
                                                      int* __restrict__ pos) {
    int i = blockIdx.x * 256 + threadIdx.x;   // i < NTOK*TOPK
    int e = topi[i];
    int r = atomicAdd(&cursor[e], 1);
    int g = off[e] + r;
    perm[g] = i >> 2;   // token id
    pos[i] = g;
}

// t2[n,d] = x[n,d] + sum_k topw[n,k] * eog[pos[n,k], d]
__global__ __launch_bounds__(256) void combine_kernel(const float* __restrict__ xb,
                                                      const float* __restrict__ eog,
                                                      const float* __restrict__ topw,
                                                      const int* __restrict__ pos,
                                                      float* __restrict__ t2) {
    int idx = blockIdx.x * 256 + threadIdx.x;
    int n = idx >> 9;
    int d = idx & 511;
    float acc = xb[idx];
#pragma unroll
    for (int k = 0; k < TOPK; k++)
        acc += topw[n * TOPK + k] * eog[(size_t)pos[n * TOPK + k] * DMODEL + d];
    t2[idx] = acc;
}

__global__ void aux_kernel(const int* __restrict__ cnt, const float* __restrict__ sumP,
                           const float* __restrict__ zacc, float* __restrict__ out_aux, int l) {
    float lb = 0.f;
    for (int e = 0; e < NEXP; e++)
        lb += ((float)cnt[e] / (float)NTOK) * (sumP[e] / (float)NTOK);
    lb *= (float)NEXP / (float)TOPK;
    out_aux[l] = lb;                       // lbs[l]
    out_aux[NLAYER + l] = zacc[0] / (float)NTOK;  // zs[l]
}

// ---------------- launcher ----------------
extern "C" void kernel_launch(void* const* d_in, const int* in_sizes, int n_in,
                              void* d_out, int out_size, void* d_ws, size_t ws_size,
                              hipStream_t stream) {
    (void)in_sizes; (void)n_in; (void)out_size; (void)ws_size;
    const float* x_in  = (const float*)d_in[0];
    const float* ln1_s = (const float*)d_in[1];
    const float* ln1_b = (const float*)d_in[2];
    const float* ln2_s = (const float*)d_in[3];
    const float* ln2_b = (const float*)d_in[4];
    const float* wq = (const float*)d_in[5];
    const float* bq = (const float*)d_in[6];
    const float* wk = (const float*)d_in[7];
    const float* bk = (const float*)d_in[8];
    const float* wv = (const float*)d_in[9];
    const float* bv = (const float*)d_in[10];
    const float* wo = (const float*)d_in[11];
    const float* bo = (const float*)d_in[12];
    const float* rdw = (const float*)d_in[13];
    const float* ruw = (const float*)d_in[14];
    const float* w1 = (const float*)d_in[15];
    const float* b1 = (const float*)d_in[16];
    const float* w2 = (const float*)d_in[17];
    const float* b2 = (const float*)d_in[18];
    const float* ws1 = (const float*)d_in[19];
    const float* bs1 = (const float*)d_in[20];
    const float* ws2 = (const float*)d_in[21];
    const float* bs2 = (const float*)d_in[22];
    const float* fn_s = (const float*)d_in[23];
    const float* fn_b = (const float*)d_in[24];

    float* ws = (float*)d_ws;
    const size_t ND = (size_t)NTOK * DMODEL;   // 2,097,152
    size_t o = 0;
    float* xb  = ws + o; o += ND;
    float* h   = ws + o; o += ND;
    float* q   = ws + o; o += ND;
    float* k   = ws + o; o += ND;
    float* v   = ws + o; o += ND;
    float* t1  = ws + o; o += ND;
    float* t2  = ws + o; o += ND;
    float* hid = ws + o; o += (size_t)NTOK * HSHARED;          // also reused as gathered expert hidden
    float* eog = ws + o; o += (size_t)NTOK * TOPK * DMODEL;
    float* rhid = ws + o; o += (size_t)NTOK * RRANK;
    float* rsc  = ws + o; o += (size_t)NTOK * NEXP;
    float* topw = ws + o; o += (size_t)NTOK * TOPK;
    int* topi = (int*)(ws + o); o += (size_t)NTOK * TOPK;
    int* pos  = (int*)(ws + o); o += (size_t)NTOK * TOPK;
    int* perm = (int*)(ws + o); o += (size_t)NTOK * TOPK;
    int* stats = (int*)(ws + o); // cnt[32], cursor[32], off[32], sumP[32]f, zacc[1]f
    int* cnt = stats;
    int* cursor = stats + 32;
    int* off = stats + 64;
    float* sumP = (float*)(stats + 96);
    float* zacc = sumP + 32;

    float* out_x = (float*)d_out;
    float* out_aux = out_x + ND;

    hipMemcpyAsync(xb, x_in, ND * sizeof(float), hipMemcpyDeviceToDevice, stream);

    dim3 blk(256);
    dim3 gD(DMODEL / 64, NTOK / 64);        // (8, 64) M=4096,N=512
    dim3 gHS(HSHARED / 64, NTOK / 64);      // (64, 64)
    dim3 gR1(1, NTOK / 64);                 // N=64
    dim3 gR2(1, NTOK / 64);                 // N=32 (guarded)
    dim3 gE(HEXP / 64, NTOK / 64, NEXP);    // expert GEMMs, early-exit on cnt

    for (int l = 0; l < NLAYER; l++) {
        const size_t DD = (size_t)DMODEL * DMODEL;
        // ---- LN1 ----
        ln_kernel<<<NTOK / 4, blk, 0, stream>>>(xb, ln1_s + l * DMODEL, ln1_b + l * DMODEL, h);
        // ---- QKV ----
        gemm_tile<false, false, false, false><<<gD, blk, 0, stream>>>(
            h, wq + l * DD, bq + l * DMODEL, nullptr, q, NTOK, DMODEL, DMODEL, DMODEL, nullptr, nullptr, nullptr);
        gemm_tile<false, false, false, false><<<gD, blk, 0, stream>>>(
            h, wk + l * DD, bk + l * DMODEL, nullptr, k, NTOK, DMODEL, DMODEL, DMODEL, nullptr, nullptr, nullptr);
        gemm_tile<false, false, false, false><<<gD, blk, 0, stream>>>(
            h, wv + l * DD, bv + l * DMODEL, nullptr, v, NTOK, DMODEL, DMODEL, DMODEL, nullptr, nullptr, nullptr);
        // ---- attention ----
        attn_kernel<<<dim3(SEQ, NHEAD, BATCH), blk, 0, stream>>>(q, k, v, t1);
        // ---- out proj + residual: xb = t1@wo + bo + xb ----
        gemm_tile<false, true, false, false><<<gD, blk, 0, stream>>>(
            t1, wo + l * DD, bo + l * DMODEL, xb, xb, NTOK, DMODEL, DMODEL, DMODEL, nullptr, nullptr, nullptr);
        // ---- LN2 ----
        ln_kernel<<<NTOK / 4, blk, 0, stream>>>(xb, ln2_s + l * DMODEL, ln2_b + l * DMODEL, h);
        // ---- router ----
        hipMemsetAsync(stats, 0, 640, stream);
        gemm_tile<false, false, false, false><<<gR1, blk, 0, stream>>>(
            h, rdw + (size_t)l * DMODEL * RRANK, nullptr, nullptr, rhid, NTOK, RRANK, DMODEL, DMODEL, nullptr, nullptr, nullptr);
        gemm_tile<false, false, false, false><<<gR2, blk, 0, stream>>>(
            rhid, ruw + (size_t)l * RRANK * NEXP, nullptr, nullptr, rsc, NTOK, NEXP, RRANK, RRANK, nullptr, nullptr, nullptr);
        router_topk<<<NTOK / 256, blk, 0, stream>>>(rsc, topw, topi, cnt, sumP, zacc);
        scan_kernel<<<1, 1, 0, stream>>>(cnt, off);
        scatter_kernel<<<NTOK * TOPK / 256, blk, 0, stream>>>(topi, off, cursor, perm, pos);
        aux_kernel<<<1, 1, 0, stream>>>(cnt, sumP, zacc, out_aux, l);
        // ---- expert FFN (gathered) ----
        float* hidg = hid;  // [NTOK*TOPK, HEXP] fits in hid region
        gemm_tile<true, false, true, true><<<gE, blk, 0, stream>>>(
            h, w1 + (size_t)l * NEXP * DMODEL * HEXP, b1 + (size_t)l * NEXP * HEXP, nullptr,
            hidg, 0, HEXP, DMODEL, DMODEL, perm, cnt, off);
        gemm_tile<false, false, false, true><<<gE, blk, 0, stream>>>(
            hidg, w2 + (size_t)l * NEXP * HEXP * DMODEL, b2 + (size_t)l * NEXP * DMODEL, nullptr,
            eog, 0, DMODEL, HEXP, HEXP, nullptr, cnt, off);
        // ---- combine: t2 = xb + routed ----
        combine_kernel<<<ND / 256, blk, 0, stream>>>(xb, eog, topw, pos, t2);
        // ---- shared FFN: hid = gelu(h@ws1+bs1); xb = hid@ws2 + bs2 + t2 ----
        gemm_tile<true, false, false, false><<<gHS, blk, 0, stream>>>(
            h, ws1 + (size_t)l * DMODEL * HSHARED, bs1 + (size_t)l * HSHARED, nullptr,
            hid, NTOK, HSHARED, DMODEL, DMODEL, nullptr, nullptr, nullptr);
        gemm_tile<false, true, false, false><<<gD, blk, 0, stream>>>(
            hid, ws2 + (size_t)l * HSHARED * DMODEL, bs2 + l * DMODEL, t2,
            xb, NTOK, DMODEL, HSHARED, HSHARED, nullptr, nullptr, nullptr);
    }
    // ---- final LN -> d_out ----
    ln_kernel<<<NTOK / 4, blk, 0, stream>>>(xb, fn_s, fn_b, out_x);
}

// Round 2
// 2660.199 us; speedup vs baseline: 2.2318x; 2.2318x over previous
//
#include <hip/hip_runtime.h>
#include <math.h>

// ---- problem constants ----
#define NTOK    4096      // B*S
#define DMODEL  512
#define NEXP    32
#define RRANK   64
#define HEXP    512
#define HSHARED 4096
#define SEQ     1024
#define BATCH   4
#define NHEAD   8
#define TOPK    4
#define NLAYER  2

__device__ __forceinline__ float gelu_f(float x) {
    float t = tanhf(0.7978845608028654f * (x + 0.044715f * x * x * x));
    return 0.5f * x * (1.f + t);
}

// ---------------- LayerNorm: one wave (64 lanes) per row of 512 ----------------
__global__ __launch_bounds__(256) void ln_kernel(const float* __restrict__ x,
                                                 const float* __restrict__ s,
                                                 const float* __restrict__ b,
                                                 float* __restrict__ out) {
    int wave = threadIdx.x >> 6, lane = threadIdx.x & 63;
    int row = blockIdx.x * 4 + wave;
    const float* xr = x + (size_t)row * DMODEL;
    float v[8];
    float sum = 0.f;
#pragma unroll
    for (int i = 0; i < 8; i++) { v[i] = xr[lane + i * 64]; sum += v[i]; }
#pragma unroll
    for (int o = 32; o; o >>= 1) sum += __shfl_xor(sum, o);
    float m = sum * (1.f / DMODEL);
    float vs = 0.f;
#pragma unroll
    for (int i = 0; i < 8; i++) { float d = v[i] - m; vs += d * d; }
#pragma unroll
    for (int o = 32; o; o >>= 1) vs += __shfl_xor(vs, o);
    float rstd = rsqrtf(vs * (1.f / DMODEL) + 1e-5f);
    float* orow = out + (size_t)row * DMODEL;
#pragma unroll
    for (int i = 0; i < 8; i++) {
        int c = lane + i * 64;
        orow[c] = (v[i] - m) * rstd * s[c] + b[c];
    }
}

// ---------------- generic tiled fp32 GEMM (unchanged from R1) ----------------
template <bool GELU, bool DORES, bool GATHER, bool EXPERT>
__global__ __launch_bounds__(256) void gemm_tile(
    const float* __restrict__ A, const float* __restrict__ W,
    const float* __restrict__ bias, const float* __restrict__ res,
    float* __restrict__ C, int M, int Nn, int Kk, int lda,
    const int* __restrict__ rowmap, const int* __restrict__ cntp,
    const int* __restrict__ offp) {
    int n0 = blockIdx.x * 64;
    int m0 = blockIdx.y * 64;
    if (EXPERT) {
        int e = blockIdx.z;
        M = cntp[e];
        if (m0 >= M) return;
        W += (size_t)e * Kk * Nn;
        bias += (size_t)e * Nn;
        int oe = offp[e];
        C += (size_t)oe * Nn;
        if (GATHER) rowmap += oe; else A += (size_t)oe * lda;
    }
    __shared__ float As[16][68];
    __shared__ float Ws[16][68];
    int tid = threadIdx.x;
    int ml = tid >> 2, kl = (tid & 3) << 2;
    bool avalid = (m0 + ml) < M;
    int arow = m0 + ml;
    if (GATHER) arow = avalid ? rowmap[arow] : 0;
    const float* aptr = A + (size_t)arow * lda + kl;
    int kr = tid >> 4, nc = (tid & 15) << 2;
    bool wvalid = (n0 + nc) < Nn;
    const float* wptr = W + (size_t)kr * Nn + n0 + nc;
    int tm = (tid >> 4) << 2, tn = (tid & 15) << 2;
    float acc[4][4] = {{0.f}};
    for (int k0 = 0; k0 < Kk; k0 += 16) {
        float4 av = make_float4(0.f, 0.f, 0.f, 0.f);
        float4 wv = make_float4(0.f, 0.f, 0.f, 0.f);
        if (avalid) av = *(const float4*)(aptr + k0);
        if (wvalid) wv = *(const float4*)(wptr + (size_t)k0 * Nn);
        As[kl + 0][ml] = av.x; As[kl + 1][ml] = av.y;
        As[kl + 2][ml] = av.z; As[kl + 3][ml] = av.w;
        *(float4*)&Ws[kr][nc] = wv;
        __syncthreads();
#pragma unroll
        for (int kk = 0; kk < 16; kk++) {
            float4 a4 = *(const float4*)&As[kk][tm];
            float4 w4 = *(const float4*)&Ws[kk][tn];
            acc[0][0] += a4.x * w4.x; acc[0][1] += a4.x * w4.y; acc[0][2] += a4.x * w4.z; acc[0][3] += a4.x * w4.w;
            acc[1][0] += a4.y * w4.x; acc[1][1] += a4.y * w4.y; acc[1][2] += a4.y * w4.z; acc[1][3] += a4.y * w4.w;
            acc[2][0] += a4.z * w4.x; acc[2][1] += a4.z * w4.y; acc[2][2] += a4.z * w4.z; acc[2][3] += a4.z * w4.w;
            acc[3][0] += a4.w * w4.x; acc[3][1] += a4.w * w4.y; acc[3][2] += a4.w * w4.z; acc[3][3] += a4.w * w4.w;
        }
        __syncthreads();
    }
#pragma unroll
    for (int i = 0; i < 4; i++) {
        int mm = m0 + tm + i;
        if (mm >= M) break;
        float* crow = C + (size_t)mm * Nn;
#pragma unroll
        for (int j = 0; j < 4; j++) {
            int nn = n0 + tn + j;
            if (nn >= Nn) continue;
            float val = acc[i][j];
            if (bias) val += bias[nn];
            if (GELU) val = gelu_f(val);
            if (DORES) val += res[(size_t)mm * Nn + nn];
            crow[nn] = val;
        }
    }
}

// ---------------- flash attention: block per (b, h, 64-row Q-tile) ----------------
// 256 threads as 16x16 grid of 4x4-accum owners (same layout as gemm_tile).
// K/V staged per 64-row tile in LDS; online softmax with 16-lane shfl reductions.
__global__ __launch_bounds__(256) void attn_flash(const float* __restrict__ Q,
                                                  const float* __restrict__ Kb,
                                                  const float* __restrict__ Vb,
                                                  float* __restrict__ O) {
    int qt = blockIdx.x, hh = blockIdx.y, bb = blockIdx.z;
    size_t headbase = (size_t)bb * SEQ * DMODEL + hh * 64;
    __shared__ float Qs[64][68];   // [d][qi]  (transposed)
    __shared__ float Ks[64][68];   // [d][kj]  (transposed)
    __shared__ float Vs[64][68];   // [j][d]   (natural)
    __shared__ float Ps[64][68];   // [j][qi]  (transposed)
    int tid = threadIdx.x;
    int lrow = tid >> 2;           // 0..63
    int dseg = (tid & 3) << 4;     // 0,16,32,48

    // stage Q tile (transposed into Qs[d][qi])
    {
        const float* qsrc = Q + headbase + (size_t)(qt * 64 + lrow) * DMODEL + dseg;
#pragma unroll
        for (int i = 0; i < 4; i++) {
            float4 t4 = *(const float4*)(qsrc + i * 4);
            Qs[dseg + i * 4 + 0][lrow] = t4.x;
            Qs[dseg + i * 4 + 1][lrow] = t4.y;
            Qs[dseg + i * 4 + 2][lrow] = t4.z;
            Qs[dseg + i * 4 + 3][lrow] = t4.w;
        }
    }

    int tm = (tid >> 4) << 2;      // q-row group 0..60
    int tn = (tid & 15) << 2;      // k-col group 0..60
    float accO[4][4] = {{0.f}};
    float m_r[4], l_r[4];
#pragma unroll
    for (int i = 0; i < 4; i++) { m_r[i] = -1e30f; l_r[i] = 0.f; }

    for (int kt = 0; kt < SEQ / 64; kt++) {
        __syncthreads();   // prev PV done; Qs visible (kt=0)
        const float* ksrc = Kb + headbase + (size_t)(kt * 64 + lrow) * DMODEL + dseg;
        const float* vsrc = Vb + headbase + (size_t)(kt * 64 + lrow) * DMODEL + dseg;
#pragma unroll
        for (int i = 0; i < 4; i++) {
            float4 t4 = *(const float4*)(ksrc + i * 4);
            Ks[dseg + i * 4 + 0][lrow] = t4.x;
            Ks[dseg + i * 4 + 1][lrow] = t4.y;
            Ks[dseg + i * 4 + 2][lrow] = t4.z;
            Ks[dseg + i * 4 + 3][lrow] = t4.w;
            *(float4*)&Vs[lrow][dseg + i * 4] = *(const float4*)(vsrc + i * 4);
        }
        __syncthreads();

        // S tile = Q-tile @ K-tile^T (scaled)
        float acc[4][4] = {{0.f}};
#pragma unroll 8
        for (int d = 0; d < 64; d++) {
            float4 a4 = *(const float4*)&Qs[d][tm];
            float4 b4 = *(const float4*)&Ks[d][tn];
            acc[0][0] += a4.x * b4.x; acc[0][1] += a4.x * b4.y; acc[0][2] += a4.x * b4.z; acc[0][3] += a4.x * b4.w;
            acc[1][0] += a4.y * b4.x; acc[1][1] += a4.y * b4.y; acc[1][2] += a4.y * b4.z; acc[1][3] += a4.y * b4.w;
            acc[2][0] += a4.z * b4.x; acc[2][1] += a4.z * b4.y; acc[2][2] += a4.z * b4.z; acc[2][3] += a4.z * b4.w;
            acc[3][0] += a4.w * b4.x; acc[3][1] += a4.w * b4.y; acc[3][2] += a4.w * b4.z; acc[3][3] += a4.w * b4.w;
        }

        // online softmax per q-row (rows tm..tm+3 owned by 16 lanes sharing tm)
#pragma unroll
        for (int i = 0; i < 4; i++) {
            float s0 = acc[i][0] * 0.125f, s1 = acc[i][1] * 0.125f;
            float s2 = acc[i][2] * 0.125f, s3 = acc[i][3] * 0.125f;
            float mx = fmaxf(fmaxf(s0, s1), fmaxf(s2, s3));
#pragma unroll
            for (int o = 1; o < 16; o <<= 1) mx = fmaxf(mx, __shfl_xor(mx, o));
            float m_new = fmaxf(m_r[i], mx);
            float rescale = __expf(m_r[i] - m_new);
            float p0 = __expf(s0 - m_new), p1 = __expf(s1 - m_new);
            float p2 = __expf(s2 - m_new), p3 = __expf(s3 - m_new);
            float ls = p0 + p1 + p2 + p3;
#pragma unroll
            for (int o = 1; o < 16; o <<= 1) ls += __shfl_xor(ls, o);
            l_r[i] = l_r[i] * rescale + ls;
            m_r[i] = m_new;
            accO[i][0] *= rescale; accO[i][1] *= rescale;
            accO[i][2] *= rescale; accO[i][3] *= rescale;
            acc[i][0] = p0; acc[i][1] = p1; acc[i][2] = p2; acc[i][3] = p3;
        }
        // write P transposed: Ps[kj][qi]
#pragma unroll
        for (int j = 0; j < 4; j++)
            *(float4*)&Ps[tn + j][tm] = make_float4(acc[0][j], acc[1][j], acc[2][j], acc[3][j]);
        __syncthreads();

        // O += P @ V-tile
#pragma unroll 8
        for (int j = 0; j < 64; j++) {
            float4 p4 = *(const float4*)&Ps[j][tm];
            float4 v4 = *(const float4*)&Vs[j][tn];
            accO[0][0] += p4.x * v4.x; accO[0][1] += p4.x * v4.y; accO[0][2] += p4.x * v4.z; accO[0][3] += p4.x * v4.w;
            accO[1][0] += p4.y * v4.x; accO[1][1] += p4.y * v4.y; accO[1][2] += p4.y * v4.z; accO[1][3] += p4.y * v4.w;
            accO[2][0] += p4.z * v4.x; accO[2][1] += p4.z * v4.y; accO[2][2] += p4.z * v4.z; accO[2][3] += p4.z * v4.w;
            accO[3][0] += p4.w * v4.x; accO[3][1] += p4.w * v4.y; accO[3][2] += p4.w * v4.z; accO[3][3] += p4.w * v4.w;
        }
    }

    // epilogue: normalize and store
#pragma unroll
    for (int i = 0; i < 4; i++) {
        float inv = 1.f / l_r[i];
        float4 r = make_float4(accO[i][0] * inv, accO[i][1] * inv, accO[i][2] * inv, accO[i][3] * inv);
        *(float4*)(O + headbase + (size_t)(qt * 64 + tm + i) * DMODEL + tn) = r;
    }
}

// ---------------- router: softmax over 32, top-4, renorm; aux accumulators ----------------
__global__ __launch_bounds__(256) void router_topk(const float* __restrict__ rsc,
                                                   float* __restrict__ topw,
                                                   int* __restrict__ topi,
                                                   int* __restrict__ cnt,
                                                   float* __restrict__ sumP,
                                                   float* __restrict__ zacc) {
    int n = blockIdx.x * blockDim.x + threadIdx.x;
    if (n >= NTOK) return;
    float sc[NEXP];
    float mx = -1e30f;
#pragma unroll
    for (int e = 0; e < NEXP; e++) { sc[e] = rsc[n * NEXP + e]; mx = fmaxf(mx, sc[e]); }
    float se = 0.f;
#pragma unroll
    for (int e = 0; e < NEXP; e++) { sc[e] = expf(sc[e] - mx); se += sc[e]; }
    float invse = 1.f / se;
    float lse = mx + logf(se);
    atomicAdd(zacc, lse * lse);
#pragma unroll
    for (int e = 0; e < NEXP; e++) atomicAdd(&sumP[e], sc[e] * invse);
    float tv[TOPK]; int ti[TOPK];
#pragma unroll
    for (int k = 0; k < TOPK; k++) {
        float best = -1.f; int bi = 0;
#pragma unroll
        for (int e = 0; e < NEXP; e++) {
            if (sc[e] > best) { best = sc[e]; bi = e; }
        }
        tv[k] = best * invse; ti[k] = bi; sc[bi] = -1.f;
    }
    float s4 = tv[0] + tv[1] + tv[2] + tv[3];
#pragma unroll
    for (int k = 0; k < TOPK; k++) {
        topw[n * TOPK + k] = tv[k] / s4;
        topi[n * TOPK + k] = ti[k];
        atomicAdd(&cnt[ti[k]], 1);
    }
}

__global__ void scan_kernel(const int* __restrict__ cnt, int* __restrict__ off) {
    int a = 0;
    for (int e = 0; e < NEXP; e++) { off[e] = a; a += cnt[e]; }
}

__global__ __launch_bounds__(256) void scatter_kernel(const int* __restrict__ topi,
                                                      const int* __restrict__ off,
                                                      int* __restrict__ cursor,
                                                      int* __restrict__ perm,
                                                      int* __restrict__ pos) {
    int i = blockIdx.x * 256 + threadIdx.x;
    int e = topi[i];
    int r = atomicAdd(&cursor[e], 1);
    int g = off[e] + r;
    perm[g] = i >> 2;
    pos[i] = g;
}

__global__ __launch_bounds__(256) void combine_kernel(const float* __restrict__ xb,
                                                      const float* __restrict__ eog,
                                                      const float* __restrict__ topw,
                                                      const int* __restrict__ pos,
                                                      float* __restrict__ t2) {
    int idx = blockIdx.x * 256 + threadIdx.x;
    int n = idx >> 9;
    int d = idx & 511;
    float acc = xb[idx];
#pragma unroll
    for (int k = 0; k < TOPK; k++)
        acc += topw[n * TOPK + k] * eog[(size_t)pos[n * TOPK + k] * DMODEL + d];
    t2[idx] = acc;
}

__global__ void aux_kernel(const int* __restrict__ cnt, const float* __restrict__ sumP,
                           const float* __restrict__ zacc, float* __restrict__ out_aux, int l) {
    float lb = 0.f;
    for (int e = 0; e < NEXP; e++)
        lb += ((float)cnt[e] / (float)NTOK) * (sumP[e] / (float)NTOK);
    lb *= (float)NEXP / (float)TOPK;
    out_aux[l] = lb;
    out_aux[NLAYER + l] = zacc[0] / (float)NTOK;
}

// ---------------- launcher ----------------
extern "C" void kernel_launch(void* const* d_in, const int* in_sizes, int n_in,
                              void* d_out, int out_size, void* d_ws, size_t ws_size,
                              hipStream_t stream) {
    (void)in_sizes; (void)n_in; (void)out_size; (void)ws_size;
    const float* x_in  = (const float*)d_in[0];
    const float* ln1_s = (const float*)d_in[1];
    const float* ln1_b = (const float*)d_in[2];
    const float* ln2_s = (const float*)d_in[3];
    const float* ln2_b = (const float*)d_in[4];
    const float* wq = (const float*)d_in[5];
    const float* bq = (const float*)d_in[6];
    const float* wk = (const float*)d_in[7];
    const float* bk = (const float*)d_in[8];
    const float* wv = (const float*)d_in[9];
    const float* bv = (const float*)d_in[10];
    const float* wo = (const float*)d_in[11];
    const float* bo = (const float*)d_in[12];
    const float* rdw = (const float*)d_in[13];
    const float* ruw = (const float*)d_in[14];
    const float* w1 = (const float*)d_in[15];
    const float* b1 = (const float*)d_in[16];
    const float* w2 = (const float*)d_in[17];
    const float* b2 = (const float*)d_in[18];
    const float* ws1 = (const float*)d_in[19];
    const float* bs1 = (const float*)d_in[20];
    const float* ws2 = (const float*)d_in[21];
    const float* bs2 = (const float*)d_in[22];
    const float* fn_s = (const float*)d_in[23];
    const float* fn_b = (const float*)d_in[24];

    float* ws = (float*)d_ws;
    const size_t ND = (size_t)NTOK * DMODEL;
    size_t o = 0;
    float* xb  = ws + o; o += ND;
    float* h   = ws + o; o += ND;
    float* q   = ws + o; o += ND;
    float* k   = ws + o; o += ND;
    float* v   = ws + o; o += ND;
    float* t1  = ws + o; o += ND;
    float* t2  = ws + o; o += ND;
    float* hid = ws + o; o += (size_t)NTOK * HSHARED;
    float* eog = ws + o; o += (size_t)NTOK * TOPK * DMODEL;
    float* rhid = ws + o; o += (size_t)NTOK * RRANK;
    float* rsc  = ws + o; o += (size_t)NTOK * NEXP;
    float* topw = ws + o; o += (size_t)NTOK * TOPK;
    int* topi = (int*)(ws + o); o += (size_t)NTOK * TOPK;
    int* pos  = (int*)(ws + o); o += (size_t)NTOK * TOPK;
    int* perm = (int*)(ws + o); o += (size_t)NTOK * TOPK;
    int* stats = (int*)(ws + o);
    int* cnt = stats;
    int* cursor = stats + 32;
    int* off = stats + 64;
    float* sumP = (float*)(stats + 96);
    float* zacc = sumP + 32;

    float* out_x = (float*)d_out;
    float* out_aux = out_x + ND;

    hipMemcpyAsync(xb, x_in, ND * sizeof(float), hipMemcpyDeviceToDevice, stream);

    dim3 blk(256);
    dim3 gD(DMODEL / 64, NTOK / 64);
    dim3 gHS(HSHARED / 64, NTOK / 64);
    dim3 gR1(1, NTOK / 64);
    dim3 gR2(1, NTOK / 64);
    dim3 gE(HEXP / 64, NTOK / 64, NEXP);

    for (int l = 0; l < NLAYER; l++) {
        const size_t DD = (size_t)DMODEL * DMODEL;
        ln_kernel<<<NTOK / 4, blk, 0, stream>>>(xb, ln1_s + l * DMODEL, ln1_b + l * DMODEL, h);
        gemm_tile<false, false, false, false><<<gD, blk, 0, stream>>>(
            h, wq + l * DD, bq + l * DMODEL, nullptr, q, NTOK, DMODEL, DMODEL, DMODEL, nullptr, nullptr, nullptr);
        gemm_tile<false, false, false, false><<<gD, blk, 0, stream>>>(
            h, wk + l * DD, bk + l * DMODEL, nullptr, k, NTOK, DMODEL, DMODEL, DMODEL, nullptr, nullptr, nullptr);
        gemm_tile<false, false, false, false><<<gD, blk, 0, stream>>>(
            h, wv + l * DD, bv + l * DMODEL, nullptr, v, NTOK, DMODEL, DMODEL, DMODEL, nullptr, nullptr, nullptr);
        attn_flash<<<dim3(SEQ / 64, NHEAD, BATCH), blk, 0, stream>>>(q, k, v, t1);
        gemm_tile<false, true, false, false><<<gD, blk, 0, stream>>>(
            t1, wo + l * DD, bo + l * DMODEL, xb, xb, NTOK, DMODEL, DMODEL, DMODEL, nullptr, nullptr, nullptr);
        ln_kernel<<<NTOK / 4, blk, 0, stream>>>(xb, ln2_s + l * DMODEL, ln2_b + l * DMODEL, h);
        hipMemsetAsync(stats, 0, 640, stream);
        gemm_tile<false, false, false, false><<<gR1, blk, 0, stream>>>(
            h, rdw + (size_t)l * DMODEL * RRANK, nullptr, nullptr, rhid, NTOK, RRANK, DMODEL, DMODEL, nullptr, nullptr, nullptr);
        gemm_tile<false, false, false, false><<<gR2, blk, 0, stream>>>(
            rhid, ruw + (size_t)l * RRANK * NEXP, nullptr, nullptr, rsc, NTOK, NEXP, RRANK, RRANK, nullptr, nullptr, nullptr);
        router_topk<<<NTOK / 256, blk, 0, stream>>>(rsc, topw, topi, cnt, sumP, zacc);
        scan_kernel<<<1, 1, 0, stream>>>(cnt, off);
        scatter_kernel<<<NTOK * TOPK / 256, blk, 0, stream>>>(topi, off, cursor, perm, pos);
        aux_kernel<<<1, 1, 0, stream>>>(cnt, sumP, zacc, out_aux, l);
        float* hidg = hid;
        gemm_tile<true, false, true, true><<<gE, blk, 0, stream>>>(
            h, w1 + (size_t)l * NEXP * DMODEL * HEXP, b1 + (size_t)l * NEXP * HEXP, nullptr,
            hidg, 0, HEXP, DMODEL, DMODEL, perm, cnt, off);
        gemm_tile<false, false, false, true><<<gE, blk, 0, stream>>>(
            hidg, w2 + (size_t)l * NEXP * HEXP * DMODEL, b2 + (size_t)l * NEXP * DMODEL, nullptr,
            eog, 0, DMODEL, HEXP, HEXP, nullptr, cnt, off);
        combine_kernel<<<ND / 256, blk, 0, stream>>>(xb, eog, topw, pos, t2);
        gemm_tile<true, false, false, false><<<gHS, blk, 0, stream>>>(
            h, ws1 + (size_t)l * DMODEL * HSHARED, bs1 + (size_t)l * HSHARED, nullptr,
            hid, NTOK, HSHARED, DMODEL, DMODEL, nullptr, nullptr, nullptr);
        gemm_tile<false, true, false, false><<<gD, blk, 0, stream>>>(
            hid, ws2 + (size_t)l * HSHARED * DMODEL, bs2 + l * DMODEL, t2,
            xb, NTOK, DMODEL, HSHARED, HSHARED, nullptr, nullptr, nullptr);
    }
    ln_kernel<<<NTOK / 4, blk, 0, stream>>>(xb, fn_s, fn_b, out_x);
}

// Round 3
// 1640.405 us; speedup vs baseline: 3.6193x; 1.6217x over previous
//
#include <hip/hip_runtime.h>
#include <math.h>

// ---- problem constants ----
#define NTOK    4096      // B*S
#define DMODEL  512
#define NEXP    32
#define RRANK   64
#define HEXP    512
#define HSHARED 4096
#define SEQ     1024
#define BATCH   4
#define NHEAD   8
#define TOPK    4
#define NLAYER  2

typedef __attribute__((ext_vector_type(8))) short bf16x8;   // 8 bf16 (4 VGPRs)
typedef __attribute__((ext_vector_type(4))) float f32x4;

__device__ __forceinline__ float gelu_f(float x) {
    float t = tanhf(0.7978845608028654f * (x + 0.044715f * x * x * x));
    return 0.5f * x * (1.f + t);
}

// fp32 -> bf16 round-to-nearest-even
__device__ __forceinline__ unsigned short f2bf(float f) {
    unsigned int u = __float_as_uint(f);
    u += 0x7FFFu + ((u >> 16) & 1u);
    return (unsigned short)(u >> 16);
}

// ---------------- LayerNorm: one wave per row of 512 ----------------
__global__ __launch_bounds__(256) void ln_kernel(const float* __restrict__ x,
                                                 const float* __restrict__ s,
                                                 const float* __restrict__ b,
                                                 float* __restrict__ out) {
    int wave = threadIdx.x >> 6, lane = threadIdx.x & 63;
    int row = blockIdx.x * 4 + wave;
    const float* xr = x + (size_t)row * DMODEL;
    float v[8];
    float sum = 0.f;
#pragma unroll
    for (int i = 0; i < 8; i++) { v[i] = xr[lane + i * 64]; sum += v[i]; }
#pragma unroll
    for (int o = 32; o; o >>= 1) sum += __shfl_xor(sum, o);
    float m = sum * (1.f / DMODEL);
    float vs = 0.f;
#pragma unroll
    for (int i = 0; i < 8; i++) { float d = v[i] - m; vs += d * d; }
#pragma unroll
    for (int o = 32; o; o >>= 1) vs += __shfl_xor(vs, o);
    float rstd = rsqrtf(vs * (1.f / DMODEL) + 1e-5f);
    float* orow = out + (size_t)row * DMODEL;
#pragma unroll
    for (int i = 0; i < 8; i++) {
        int c = lane + i * 64;
        orow[c] = (v[i] - m) * rstd * s[c] + b[c];
    }
}

// ---------------- weight transpose + fp32->bf16: src [K][N] -> dst [N][K] bf16 ----------------
__global__ __launch_bounds__(256) void wt_kernel(const float* __restrict__ src,
                                                 unsigned short* __restrict__ dst,
                                                 int K, int N) {
    src += (size_t)blockIdx.z * K * N;
    dst += (size_t)blockIdx.z * K * N;
    __shared__ float t[32][33];
    int k0 = blockIdx.y * 32, n0 = blockIdx.x * 32;
    int tx = threadIdx.x & 31, ty = threadIdx.x >> 5;   // ty 0..7
#pragma unroll
    for (int i = 0; i < 4; i++)
        t[ty * 4 + i][tx] = src[(size_t)(k0 + ty * 4 + i) * N + n0 + tx];
    __syncthreads();
#pragma unroll
    for (int i = 0; i < 4; i++)
        dst[(size_t)(n0 + ty * 4 + i) * K + k0 + tx] = f2bf(t[tx][ty * 4 + i]);
}

// ---------------- bf16 MFMA GEMM: C = A @ W (+bias)(+gelu)(+res) ----------------
// 128x128 tile, BK=64, 256 threads = 4 waves in 2x2, 16x16x32 MFMA, 4x4 frags/wave.
// A: fp32 (inline-converted) or bf16 per ABF16. Wt: bf16 [N][K]. XOR-swizzled LDS.
template <bool GELU, bool DORES, bool GATHER, bool EXPERT, bool ABF16, bool OUTBF16>
__global__ __launch_bounds__(256, 2) void gemm_mfma(
    const void* __restrict__ Avoid, const unsigned short* __restrict__ Wt,
    const float* __restrict__ bias, const float* __restrict__ res,
    void* __restrict__ Cvoid, int M, int Nn, int Kk,
    const int* __restrict__ rowmap, const int* __restrict__ cntp,
    const int* __restrict__ offp) {
    int n0 = blockIdx.x * 128;
    int m0 = blockIdx.y * 128;
    const float* Af = (const float*)Avoid;
    const unsigned short* Ab = (const unsigned short*)Avoid;
    size_t cbase = 0;
    if (EXPERT) {
        int e = blockIdx.z;
        M = cntp[e];
        if (m0 >= M) return;
        Wt += (size_t)e * Nn * Kk;
        bias += (size_t)e * Nn;
        int oe = offp[e];
        cbase = (size_t)oe * Nn;
        if (GATHER) rowmap += oe;
        else { Af += (size_t)oe * Kk; Ab += (size_t)oe * Kk; }
    }
    __shared__ short As[128 * 64];
    __shared__ short Bs[128 * 64];
    char* asb = (char*)As;
    char* bsb = (char*)Bs;
    int tid = threadIdx.x;
    int wave = tid >> 6, lane = tid & 63;
    int wm = wave >> 1, wn = wave & 1;
    int l15 = lane & 15, l16 = lane >> 4;   // 0..15, 0..3
    int srow = tid >> 3;                    // 0..31
    int sk8 = tid & 7;                      // k-group of 8 elems

    f32x4 acc[4][4];
#pragma unroll
    for (int m = 0; m < 4; m++)
#pragma unroll
        for (int n = 0; n < 4; n++)
#pragma unroll
            for (int j = 0; j < 4; j++) acc[m][n][j] = 0.f;

    for (int k0 = 0; k0 < Kk; k0 += 64) {
        // ---- stage A tile [128 rows][64 k] ----
#pragma unroll
        for (int i = 0; i < 4; i++) {
            int row = srow + i * 32;
            int grow = m0 + row;
            bool valid = grow < M;
            int arow = grow;
            if (GATHER) arow = valid ? rowmap[grow] : 0;
            bf16x8 v;
            if (ABF16) {
#pragma unroll
                for (int j = 0; j < 8; j++) v[j] = 0;
                if (valid) v = *(const bf16x8*)(Ab + (size_t)arow * Kk + k0 + sk8 * 8);
            } else {
                float4 f0 = make_float4(0.f, 0.f, 0.f, 0.f), f1 = f0;
                if (valid) {
                    const float* p = Af + (size_t)arow * Kk + k0 + sk8 * 8;
                    f0 = *(const float4*)p;
                    f1 = *(const float4*)(p + 4);
                }
                v[0] = (short)f2bf(f0.x); v[1] = (short)f2bf(f0.y);
                v[2] = (short)f2bf(f0.z); v[3] = (short)f2bf(f0.w);
                v[4] = (short)f2bf(f1.x); v[5] = (short)f2bf(f1.y);
                v[6] = (short)f2bf(f1.z); v[7] = (short)f2bf(f1.w);
            }
            *(bf16x8*)(asb + row * 128 + ((sk8 * 16) ^ ((row & 7) << 4))) = v;
        }
        // ---- stage B tile [128 n][64 k] from Wt [N][K] bf16 ----
#pragma unroll
        for (int i = 0; i < 4; i++) {
            int nrow = srow + i * 32;
            bf16x8 v = *(const bf16x8*)(Wt + (size_t)(n0 + nrow) * Kk + k0 + sk8 * 8);
            *(bf16x8*)(bsb + nrow * 128 + ((sk8 * 16) ^ ((nrow & 7) << 4))) = v;
        }
        __syncthreads();
        // ---- MFMA: 2 sub-steps of K=32 ----
#pragma unroll
        for (int kk = 0; kk < 2; kk++) {
            int k8 = kk * 4 + l16;
            bf16x8 a[4], b[4];
#pragma unroll
            for (int m = 0; m < 4; m++) {
                int row = wm * 64 + m * 16 + l15;
                a[m] = *(const bf16x8*)(asb + row * 128 + ((k8 * 16) ^ ((row & 7) << 4)));
            }
#pragma unroll
            for (int n = 0; n < 4; n++) {
                int row = wn * 64 + n * 16 + l15;
                b[n] = *(const bf16x8*)(bsb + row * 128 + ((k8 * 16) ^ ((row & 7) << 4)));
            }
#pragma unroll
            for (int m = 0; m < 4; m++)
#pragma unroll
                for (int n = 0; n < 4; n++)
                    acc[m][n] = __builtin_amdgcn_mfma_f32_16x16x32_bf16(a[m], b[n], acc[m][n], 0, 0, 0);
        }
        __syncthreads();
    }

    // ---- epilogue: C/D layout col=lane&15, row=(lane>>4)*4+j ----
#pragma unroll
    for (int m = 0; m < 4; m++) {
#pragma unroll
        for (int n = 0; n < 4; n++) {
            int col = n0 + wn * 64 + n * 16 + l15;
            float bv = bias ? bias[col] : 0.f;
#pragma unroll
            for (int j = 0; j < 4; j++) {
                int row = m0 + wm * 64 + m * 16 + l16 * 4 + j;
                if (row >= M) continue;
                float val = acc[m][n][j] + bv;
                if (GELU) val = gelu_f(val);
                if (DORES) val += res[(size_t)row * Nn + col];
                if (OUTBF16)
                    ((unsigned short*)Cvoid)[cbase + (size_t)row * Nn + col] = f2bf(val);
                else
                    ((float*)Cvoid)[cbase + (size_t)row * Nn + col] = val;
            }
        }
    }
}

// ---------------- small fp32 GEMM (router only) ----------------
template <bool GELU, bool DORES, bool GATHER, bool EXPERT>
__global__ __launch_bounds__(256) void gemm_tile(
    const float* __restrict__ A, const float* __restrict__ W,
    const float* __restrict__ bias, const float* __restrict__ res,
    float* __restrict__ C, int M, int Nn, int Kk, int lda,
    const int* __restrict__ rowmap, const int* __restrict__ cntp,
    const int* __restrict__ offp) {
    int n0 = blockIdx.x * 64;
    int m0 = blockIdx.y * 64;
    if (EXPERT) {
        int e = blockIdx.z;
        M = cntp[e];
        if (m0 >= M) return;
        W += (size_t)e * Kk * Nn;
        bias += (size_t)e * Nn;
        int oe = offp[e];
        C += (size_t)oe * Nn;
        if (GATHER) rowmap += oe; else A += (size_t)oe * lda;
    }
    __shared__ float Asf[16][68];
    __shared__ float Wsf[16][68];
    int tid = threadIdx.x;
    int ml = tid >> 2, kl = (tid & 3) << 2;
    bool avalid = (m0 + ml) < M;
    int arow = m0 + ml;
    if (GATHER) arow = avalid ? rowmap[arow] : 0;
    const float* aptr = A + (size_t)arow * lda + kl;
    int kr = tid >> 4, nc = (tid & 15) << 2;
    bool wvalid = (n0 + nc) < Nn;
    const float* wptr = W + (size_t)kr * Nn + n0 + nc;
    int tm = (tid >> 4) << 2, tn = (tid & 15) << 2;
    float acc[4][4] = {{0.f}};
    for (int k0 = 0; k0 < Kk; k0 += 16) {
        float4 av = make_float4(0.f, 0.f, 0.f, 0.f);
        float4 wv = make_float4(0.f, 0.f, 0.f, 0.f);
        if (avalid) av = *(const float4*)(aptr + k0);
        if (wvalid) wv = *(const float4*)(wptr + (size_t)k0 * Nn);
        Asf[kl + 0][ml] = av.x; Asf[kl + 1][ml] = av.y;
        Asf[kl + 2][ml] = av.z; Asf[kl + 3][ml] = av.w;
        *(float4*)&Wsf[kr][nc] = wv;
        __syncthreads();
#pragma unroll
        for (int kk = 0; kk < 16; kk++) {
            float4 a4 = *(const float4*)&Asf[kk][tm];
            float4 w4 = *(const float4*)&Wsf[kk][tn];
            acc[0][0] += a4.x * w4.x; acc[0][1] += a4.x * w4.y; acc[0][2] += a4.x * w4.z; acc[0][3] += a4.x * w4.w;
            acc[1][0] += a4.y * w4.x; acc[1][1] += a4.y * w4.y; acc[1][2] += a4.y * w4.z; acc[1][3] += a4.y * w4.w;
            acc[2][0] += a4.z * w4.x; acc[2][1] += a4.z * w4.y; acc[2][2] += a4.z * w4.z; acc[2][3] += a4.z * w4.w;
            acc[3][0] += a4.w * w4.x; acc[3][1] += a4.w * w4.y; acc[3][2] += a4.w * w4.z; acc[3][3] += a4.w * w4.w;
        }
        __syncthreads();
    }
#pragma unroll
    for (int i = 0; i < 4; i++) {
        int mm = m0 + tm + i;
        if (mm >= M) break;
        float* crow = C + (size_t)mm * Nn;
#pragma unroll
        for (int j = 0; j < 4; j++) {
            int nn = n0 + tn + j;
            if (nn >= Nn) continue;
            float val = acc[i][j];
            if (bias) val += bias[nn];
            if (GELU) val = gelu_f(val);
            if (DORES) val += res[(size_t)mm * Nn + nn];
            crow[nn] = val;
        }
    }
}

// ---------------- flash attention (fp32, unchanged from R2) ----------------
__global__ __launch_bounds__(256) void attn_flash(const float* __restrict__ Q,
                                                  const float* __restrict__ Kb,
                                                  const float* __restrict__ Vb,
                                                  float* __restrict__ O) {
    int qt = blockIdx.x, hh = blockIdx.y, bb = blockIdx.z;
    size_t headbase = (size_t)bb * SEQ * DMODEL + hh * 64;
    __shared__ float Qs[64][68];
    __shared__ float Ks[64][68];
    __shared__ float Vs[64][68];
    __shared__ float Ps[64][68];
    int tid = threadIdx.x;
    int lrow = tid >> 2;
    int dseg = (tid & 3) << 4;
    {
        const float* qsrc = Q + headbase + (size_t)(qt * 64 + lrow) * DMODEL + dseg;
#pragma unroll
        for (int i = 0; i < 4; i++) {
            float4 t4 = *(const float4*)(qsrc + i * 4);
            Qs[dseg + i * 4 + 0][lrow] = t4.x;
            Qs[dseg + i * 4 + 1][lrow] = t4.y;
            Qs[dseg + i * 4 + 2][lrow] = t4.z;
            Qs[dseg + i * 4 + 3][lrow] = t4.w;
        }
    }
    int tm = (tid >> 4) << 2;
    int tn = (tid & 15) << 2;
    float accO[4][4] = {{0.f}};
    float m_r[4], l_r[4];
#pragma unroll
    for (int i = 0; i < 4; i++) { m_r[i] = -1e30f; l_r[i] = 0.f; }

    for (int kt = 0; kt < SEQ / 64; kt++) {
        __syncthreads();
        const float* ksrc = Kb + headbase + (size_t)(kt * 64 + lrow) * DMODEL + dseg;
        const float* vsrc = Vb + headbase + (size_t)(kt * 64 + lrow) * DMODEL + dseg;
#pragma unroll
        for (int i = 0; i < 4; i++) {
            float4 t4 = *(const float4*)(ksrc + i * 4);
            Ks[dseg + i * 4 + 0][lrow] = t4.x;
            Ks[dseg + i * 4 + 1][lrow] = t4.y;
            Ks[dseg + i * 4 + 2][lrow] = t4.z;
            Ks[dseg + i * 4 + 3][lrow] = t4.w;
            *(float4*)&Vs[lrow][dseg + i * 4] = *(const float4*)(vsrc + i * 4);
        }
        __syncthreads();
        float acc[4][4] = {{0.f}};
#pragma unroll 8
        for (int d = 0; d < 64; d++) {
            float4 a4 = *(const float4*)&Qs[d][tm];
            float4 b4 = *(const float4*)&Ks[d][tn];
            acc[0][0] += a4.x * b4.x; acc[0][1] += a4.x * b4.y; acc[0][2] += a4.x * b4.z; acc[0][3] += a4.x * b4.w;
            acc[1][0] += a4.y * b4.x; acc[1][1] += a4.y * b4.y; acc[1][2] += a4.y * b4.z; acc[1][3] += a4.y * b4.w;
            acc[2][0] += a4.z * b4.x; acc[2][1] += a4.z * b4.y; acc[2][2] += a4.z * b4.z; acc[2][3] += a4.z * b4.w;
            acc[3][0] += a4.w * b4.x; acc[3][1] += a4.w * b4.y; acc[3][2] += a4.w * b4.z; acc[3][3] += a4.w * b4.w;
        }
#pragma unroll
        for (int i = 0; i < 4; i++) {
            float s0 = acc[i][0] * 0.125f, s1 = acc[i][1] * 0.125f;
            float s2 = acc[i][2] * 0.125f, s3 = acc[i][3] * 0.125f;
            float mx = fmaxf(fmaxf(s0, s1), fmaxf(s2, s3));
#pragma unroll
            for (int o = 1; o < 16; o <<= 1) mx = fmaxf(mx, __shfl_xor(mx, o));
            float m_new = fmaxf(m_r[i], mx);
            float rescale = __expf(m_r[i] - m_new);
            float p0 = __expf(s0 - m_new), p1 = __expf(s1 - m_new);
            float p2 = __expf(s2 - m_new), p3 = __expf(s3 - m_new);
            float ls = p0 + p1 + p2 + p3;
#pragma unroll
            for (int o = 1; o < 16; o <<= 1) ls += __shfl_xor(ls, o);
            l_r[i] = l_r[i] * rescale + ls;
            m_r[i] = m_new;
            accO[i][0] *= rescale; accO[i][1] *= rescale;
            accO[i][2] *= rescale; accO[i][3] *= rescale;
            acc[i][0] = p0; acc[i][1] = p1; acc[i][2] = p2; acc[i][3] = p3;
        }
#pragma unroll
        for (int j = 0; j < 4; j++)
            *(float4*)&Ps[tn + j][tm] = make_float4(acc[0][j], acc[1][j], acc[2][j], acc[3][j]);
        __syncthreads();
#pragma unroll 8
        for (int j = 0; j < 64; j++) {
            float4 p4 = *(const float4*)&Ps[j][tm];
            float4 v4 = *(const float4*)&Vs[j][tn];
            accO[0][0] += p4.x * v4.x; accO[0][1] += p4.x * v4.y; accO[0][2] += p4.x * v4.z; accO[0][3] += p4.x * v4.w;
            accO[1][0] += p4.y * v4.x; accO[1][1] += p4.y * v4.y; accO[1][2] += p4.y * v4.z; accO[1][3] += p4.y * v4.w;
            accO[2][0] += p4.z * v4.x; accO[2][1] += p4.z * v4.y; accO[2][2] += p4.z * v4.z; accO[2][3] += p4.z * v4.w;
            accO[3][0] += p4.w * v4.x; accO[3][1] += p4.w * v4.y; accO[3][2] += p4.w * v4.z; accO[3][3] += p4.w * v4.w;
        }
    }
#pragma unroll
    for (int i = 0; i < 4; i++) {
        float inv = 1.f / l_r[i];
        float4 r = make_float4(accO[i][0] * inv, accO[i][1] * inv, accO[i][2] * inv, accO[i][3] * inv);
        *(float4*)(O + headbase + (size_t)(qt * 64 + tm + i) * DMODEL + tn) = r;
    }
}

// ---------------- router / MoE plumbing (unchanged) ----------------
__global__ __launch_bounds__(256) void router_topk(const float* __restrict__ rsc,
                                                   float* __restrict__ topw,
                                                   int* __restrict__ topi,
                                                   int* __restrict__ cnt,
                                                   float* __restrict__ sumP,
                                                   float* __restrict__ zacc) {
    int n = blockIdx.x * blockDim.x + threadIdx.x;
    if (n >= NTOK) return;
    float sc[NEXP];
    float mx = -1e30f;
#pragma unroll
    for (int e = 0; e < NEXP; e++) { sc[e] = rsc[n * NEXP + e]; mx = fmaxf(mx, sc[e]); }
    float se = 0.f;
#pragma unroll
    for (int e = 0; e < NEXP; e++) { sc[e] = expf(sc[e] - mx); se += sc[e]; }
    float invse = 1.f / se;
    float lse = mx + logf(se);
    atomicAdd(zacc, lse * lse);
#pragma unroll
    for (int e = 0; e < NEXP; e++) atomicAdd(&sumP[e], sc[e] * invse);
    float tv[TOPK]; int ti[TOPK];
#pragma unroll
    for (int k = 0; k < TOPK; k++) {
        float best = -1.f; int bi = 0;
#pragma unroll
        for (int e = 0; e < NEXP; e++) {
            if (sc[e] > best) { best = sc[e]; bi = e; }
        }
        tv[k] = best * invse; ti[k] = bi; sc[bi] = -1.f;
    }
    float s4 = tv[0] + tv[1] + tv[2] + tv[3];
#pragma unroll
    for (int k = 0; k < TOPK; k++) {
        topw[n * TOPK + k] = tv[k] / s4;
        topi[n * TOPK + k] = ti[k];
        atomicAdd(&cnt[ti[k]], 1);
    }
}

__global__ void scan_kernel(const int* __restrict__ cnt, int* __restrict__ off) {
    int a = 0;
    for (int e = 0; e < NEXP; e++) { off[e] = a; a += cnt[e]; }
}

__global__ __launch_bounds__(256) void scatter_kernel(const int* __restrict__ topi,
                                                      const int* __restrict__ off,
                                                      int* __restrict__ cursor,
                                                      int* __restrict__ perm,
                                                      int* __restrict__ pos) {
    int i = blockIdx.x * 256 + threadIdx.x;
    int e = topi[i];
    int r = atomicAdd(&cursor[e], 1);
    int g = off[e] + r;
    perm[g] = i >> 2;
    pos[i] = g;
}

__global__ __launch_bounds__(256) void combine_kernel(const float* __restrict__ xb,
                                                      const float* __restrict__ eog,
                                                      const float* __restrict__ topw,
                                                      const int* __restrict__ pos,
                                                      float* __restrict__ t2) {
    int idx = blockIdx.x * 256 + threadIdx.x;
    int n = idx >> 9;
    int d = idx & 511;
    float acc = xb[idx];
#pragma unroll
    for (int k = 0; k < TOPK; k++)
        acc += topw[n * TOPK + k] * eog[(size_t)pos[n * TOPK + k] * DMODEL + d];
    t2[idx] = acc;
}

__global__ void aux_kernel(const int* __restrict__ cnt, const float* __restrict__ sumP,
                           const float* __restrict__ zacc, float* __restrict__ out_aux, int l) {
    float lb = 0.f;
    for (int e = 0; e < NEXP; e++)
        lb += ((float)cnt[e] / (float)NTOK) * (sumP[e] / (float)NTOK);
    lb *= (float)NEXP / (float)TOPK;
    out_aux[l] = lb;
    out_aux[NLAYER + l] = zacc[0] / (float)NTOK;
}

// ---------------- launcher ----------------
extern "C" void kernel_launch(void* const* d_in, const int* in_sizes, int n_in,
                              void* d_out, int out_size, void* d_ws, size_t ws_size,
                              hipStream_t stream) {
    (void)in_sizes; (void)n_in; (void)out_size; (void)ws_size;
    const float* x_in  = (const float*)d_in[0];
    const float* ln1_s = (const float*)d_in[1];
    const float* ln1_b = (const float*)d_in[2];
    const float* ln2_s = (const float*)d_in[3];
    const float* ln2_b = (const float*)d_in[4];
    const float* wq = (const float*)d_in[5];
    const float* bq = (const float*)d_in[6];
    const float* wk = (const float*)d_in[7];
    const float* bk = (const float*)d_in[8];
    const float* wv = (const float*)d_in[9];
    const float* bv = (const float*)d_in[10];
    const float* wo = (const float*)d_in[11];
    const float* bo = (const float*)d_in[12];
    const float* rdw = (const float*)d_in[13];
    const float* ruw = (const float*)d_in[14];
    const float* w1 = (const float*)d_in[15];
    const float* b1 = (const float*)d_in[16];
    const float* w2 = (const float*)d_in[17];
    const float* b2 = (const float*)d_in[18];
    const float* ws1 = (const float*)d_in[19];
    const float* bs1 = (const float*)d_in[20];
    const float* ws2 = (const float*)d_in[21];
    const float* bs2 = (const float*)d_in[22];
    const float* fn_s = (const float*)d_in[23];
    const float* fn_b = (const float*)d_in[24];

    float* ws = (float*)d_ws;
    const size_t ND = (size_t)NTOK * DMODEL;
    size_t o = 0;
    float* xb  = ws + o; o += ND;
    float* h   = ws + o; o += ND;
    float* q   = ws + o; o += ND;
    float* k   = ws + o; o += ND;
    float* v   = ws + o; o += ND;
    float* t1  = ws + o; o += ND;
    float* t2  = ws + o; o += ND;
    unsigned short* hidb = (unsigned short*)(ws + o); o += (size_t)NTOK * HSHARED / 2;  // bf16 [NTOK][HS]; also expert hidden bf16
    float* eog = ws + o; o += (size_t)NTOK * TOPK * DMODEL;
    float* rhid = ws + o; o += (size_t)NTOK * RRANK;
    float* rsc  = ws + o; o += (size_t)NTOK * NEXP;
    float* topw = ws + o; o += (size_t)NTOK * TOPK;
    int* topi = (int*)(ws + o); o += (size_t)NTOK * TOPK;
    int* pos  = (int*)(ws + o); o += (size_t)NTOK * TOPK;
    int* perm = (int*)(ws + o); o += (size_t)NTOK * TOPK;
    int* stats = (int*)(ws + o); o += 256;
    int* cnt = stats;
    int* cursor = stats + 32;
    int* off = stats + 64;
    float* sumP = (float*)(stats + 96);
    float* zacc = sumP + 32;
    // per-layer bf16 transposed weights (reused across layers)
    unsigned short* wbf = (unsigned short*)(ws + o);
    const size_t DDu = (size_t)DMODEL * DMODEL;   // 262144
    unsigned short* wqt  = wbf;
    unsigned short* wkt  = wqt + DDu;
    unsigned short* wvt  = wkt + DDu;
    unsigned short* wot  = wvt + DDu;
    unsigned short* w1t  = wot + DDu;                       // 32 mats [H][D]
    unsigned short* w2t  = w1t + (size_t)NEXP * DDu;        // 32 mats [D][H]
    unsigned short* ws1t = w2t + (size_t)NEXP * DDu;        // [HS][D]
    unsigned short* ws2t = ws1t + (size_t)DMODEL * HSHARED; // [D][HS]

    float* out_x = (float*)d_out;
    float* out_aux = out_x + ND;

    hipMemcpyAsync(xb, x_in, ND * sizeof(float), hipMemcpyDeviceToDevice, stream);

    dim3 blk(256);
    dim3 gD(DMODEL / 128, NTOK / 128);        // (4, 32)
    dim3 gHS(HSHARED / 128, NTOK / 128);      // (32, 32)
    dim3 gE1(HEXP / 128, NTOK * TOPK / 128, NEXP);   // (4, 128, 32)
    dim3 gE2(DMODEL / 128, NTOK * TOPK / 128, NEXP);
    dim3 gR1(1, NTOK / 64);
    dim3 gR2(1, NTOK / 64);

    for (int l = 0; l < NLAYER; l++) {
        const size_t DD = (size_t)DMODEL * DMODEL;
        // ---- weight transpose+convert for this layer ----
        wt_kernel<<<dim3(16, 16, 1), blk, 0, stream>>>(wq + l * DD, wqt, DMODEL, DMODEL);
        wt_kernel<<<dim3(16, 16, 1), blk, 0, stream>>>(wk + l * DD, wkt, DMODEL, DMODEL);
        wt_kernel<<<dim3(16, 16, 1), blk, 0, stream>>>(wv + l * DD, wvt, DMODEL, DMODEL);
        wt_kernel<<<dim3(16, 16, 1), blk, 0, stream>>>(wo + l * DD, wot, DMODEL, DMODEL);
        wt_kernel<<<dim3(16, 16, NEXP), blk, 0, stream>>>(w1 + (size_t)l * NEXP * DD, w1t, DMODEL, HEXP);
        wt_kernel<<<dim3(16, 16, NEXP), blk, 0, stream>>>(w2 + (size_t)l * NEXP * DD, w2t, HEXP, DMODEL);
        wt_kernel<<<dim3(HSHARED / 32, 16, 1), blk, 0, stream>>>(ws1 + (size_t)l * DMODEL * HSHARED, ws1t, DMODEL, HSHARED);
        wt_kernel<<<dim3(16, HSHARED / 32, 1), blk, 0, stream>>>(ws2 + (size_t)l * HSHARED * DMODEL, ws2t, HSHARED, DMODEL);

        // ---- LN1 ----
        ln_kernel<<<NTOK / 4, blk, 0, stream>>>(xb, ln1_s + l * DMODEL, ln1_b + l * DMODEL, h);
        // ---- QKV (bf16 MFMA) ----
        gemm_mfma<false, false, false, false, false, false><<<gD, blk, 0, stream>>>(
            h, wqt, bq + l * DMODEL, nullptr, q, NTOK, DMODEL, DMODEL, nullptr, nullptr, nullptr);
        gemm_mfma<false, false, false, false, false, false><<<gD, blk, 0, stream>>>(
            h, wkt, bk + l * DMODEL, nullptr, k, NTOK, DMODEL, DMODEL, nullptr, nullptr, nullptr);
        gemm_mfma<false, false, false, false, false, false><<<gD, blk, 0, stream>>>(
            h, wvt, bv + l * DMODEL, nullptr, v, NTOK, DMODEL, DMODEL, nullptr, nullptr, nullptr);
        // ---- attention ----
        attn_flash<<<dim3(SEQ / 64, NHEAD, BATCH), blk, 0, stream>>>(q, k, v, t1);
        // ---- out proj + residual ----
        gemm_mfma<false, true, false, false, false, false><<<gD, blk, 0, stream>>>(
            t1, wot, bo + l * DMODEL, xb, xb, NTOK, DMODEL, DMODEL, nullptr, nullptr, nullptr);
        // ---- LN2 ----
        ln_kernel<<<NTOK / 4, blk, 0, stream>>>(xb, ln2_s + l * DMODEL, ln2_b + l * DMODEL, h);
        // ---- router (fp32) ----
        hipMemsetAsync(stats, 0, 640, stream);
        gemm_tile<false, false, false, false><<<gR1, blk, 0, stream>>>(
            h, rdw + (size_t)l * DMODEL * RRANK, nullptr, nullptr, rhid, NTOK, RRANK, DMODEL, DMODEL, nullptr, nullptr, nullptr);
        gemm_tile<false, false, false, false><<<gR2, blk, 0, stream>>>(
            rhid, ruw + (size_t)l * RRANK * NEXP, nullptr, nullptr, rsc, NTOK, NEXP, RRANK, RRANK, nullptr, nullptr, nullptr);
        router_topk<<<NTOK / 256, blk, 0, stream>>>(rsc, topw, topi, cnt, sumP, zacc);
        scan_kernel<<<1, 1, 0, stream>>>(cnt, off);
        scatter_kernel<<<NTOK * TOPK / 256, blk, 0, stream>>>(topi, off, cursor, perm, pos);
        aux_kernel<<<1, 1, 0, stream>>>(cnt, sumP, zacc, out_aux, l);
        // ---- expert FFN (gathered, bf16 MFMA) ----
        gemm_mfma<true, false, true, true, false, true><<<gE1, blk, 0, stream>>>(
            h, w1t, b1 + (size_t)l * NEXP * HEXP, nullptr,
            hidb, 0, HEXP, DMODEL, perm, cnt, off);
        gemm_mfma<false, false, false, true, true, false><<<gE2, blk, 0, stream>>>(
            hidb, w2t, b2 + (size_t)l * NEXP * DMODEL, nullptr,
            eog, 0, DMODEL, HEXP, nullptr, cnt, off);
        // ---- combine ----
        combine_kernel<<<ND / 256, blk, 0, stream>>>(xb, eog, topw, pos, t2);
        // ---- shared FFN (bf16 MFMA) ----
        gemm_mfma<true, false, false, false, false, true><<<gHS, blk, 0, stream>>>(
            h, ws1t, bs1 + (size_t)l * HSHARED, nullptr,
            hidb, NTOK, HSHARED, DMODEL, nullptr, nullptr, nullptr);
        gemm_mfma<false, true, false, false, true, false><<<gD, blk, 0, stream>>>(
            hidb, ws2t, bs2 + l * DMODEL, t2,
            xb, NTOK, DMODEL, HSHARED, nullptr, nullptr, nullptr);
    }
    ln_kernel<<<NTOK / 4, blk, 0, stream>>>(xb, fn_s, fn_b, out_x);
}

// Round 4
// 1347.580 us; speedup vs baseline: 4.4057x; 1.2173x over previous
//
#include <hip/hip_runtime.h>
#include <math.h>

// ---- problem constants ----
#define NTOK    4096      // B*S
#define DMODEL  512
#define NEXP    32
#define RRANK   64
#define HEXP    512
#define HSHARED 4096
#define SEQ     1024
#define BATCH   4
#define NHEAD   8
#define TOPK    4
#define NLAYER  2
#define QBLK    64
#define KBLK    64

typedef __attribute__((ext_vector_type(8))) short bf16x8;   // 8 bf16 (4 VGPRs)
typedef __attribute__((ext_vector_type(4))) float f32x4;

__device__ __forceinline__ float gelu_f(float x) {
    float t = tanhf(0.7978845608028654f * (x + 0.044715f * x * x * x));
    return 0.5f * x * (1.f + t);
}

// fp32 -> bf16 round-to-nearest-even
__device__ __forceinline__ unsigned short f2bf(float f) {
    unsigned int u = __float_as_uint(f);
    u += 0x7FFFu + ((u >> 16) & 1u);
    return (unsigned short)(u >> 16);
}
__device__ __forceinline__ float bf2f(unsigned short u) {
    return __uint_as_float((unsigned int)u << 16);
}

// ---------------- LayerNorm: one wave per row of 512 ----------------
__global__ __launch_bounds__(256) void ln_kernel(const float* __restrict__ x,
                                                 const float* __restrict__ s,
                                                 const float* __restrict__ b,
                                                 float* __restrict__ out) {
    int wave = threadIdx.x >> 6, lane = threadIdx.x & 63;
    int row = blockIdx.x * 4 + wave;
    const float* xr = x + (size_t)row * DMODEL;
    float v[8];
    float sum = 0.f;
#pragma unroll
    for (int i = 0; i < 8; i++) { v[i] = xr[lane + i * 64]; sum += v[i]; }
#pragma unroll
    for (int o = 32; o; o >>= 1) sum += __shfl_xor(sum, o);
    float m = sum * (1.f / DMODEL);
    float vs = 0.f;
#pragma unroll
    for (int i = 0; i < 8; i++) { float d = v[i] - m; vs += d * d; }
#pragma unroll
    for (int o = 32; o; o >>= 1) vs += __shfl_xor(vs, o);
    float rstd = rsqrtf(vs * (1.f / DMODEL) + 1e-5f);
    float* orow = out + (size_t)row * DMODEL;
#pragma unroll
    for (int i = 0; i < 8; i++) {
        int c = lane + i * 64;
        orow[c] = (v[i] - m) * rstd * s[c] + b[c];
    }
}

// ---------------- weight transpose + fp32->bf16: src [K][N] -> dst [N][K] bf16 ----------------
__global__ __launch_bounds__(256) void wt_kernel(const float* __restrict__ src,
                                                 unsigned short* __restrict__ dst,
                                                 int K, int N) {
    src += (size_t)blockIdx.z * K * N;
    dst += (size_t)blockIdx.z * K * N;
    __shared__ float t[32][33];
    int k0 = blockIdx.y * 32, n0 = blockIdx.x * 32;
    int tx = threadIdx.x & 31, ty = threadIdx.x >> 5;   // ty 0..7
#pragma unroll
    for (int i = 0; i < 4; i++)
        t[ty * 4 + i][tx] = src[(size_t)(k0 + ty * 4 + i) * N + n0 + tx];
    __syncthreads();
#pragma unroll
    for (int i = 0; i < 4; i++)
        dst[(size_t)(n0 + ty * 4 + i) * K + k0 + tx] = f2bf(t[tx][ty * 4 + i]);
}

// ---------------- V transpose: qkv[.,1024+h*64+d] -> Vt[b,h,d,s] (bf16) ----------------
__global__ __launch_bounds__(256) void vtr_kernel(const unsigned short* __restrict__ QKV,
                                                  unsigned short* __restrict__ Vt) {
    int st = blockIdx.x, hh = blockIdx.y, bb = blockIdx.z;
    __shared__ unsigned short t[64][72];
    int r = threadIdx.x >> 3, g = threadIdx.x & 7;
#pragma unroll
    for (int i = 0; i < 2; i++) {
        int row = r + i * 32;   // key within tile
        bf16x8 v = *(const bf16x8*)(QKV + (size_t)(bb * SEQ + st * 64 + row) * 1536 + 1024 + hh * 64 + g * 8);
        *(bf16x8*)&t[row][g * 8] = v;
    }
    __syncthreads();
#pragma unroll
    for (int i = 0; i < 2; i++) {
        int d = r + i * 32;
        bf16x8 v;
#pragma unroll
        for (int j = 0; j < 8; j++) v[j] = (short)t[g * 8 + j][d];
        *(bf16x8*)(Vt + (size_t)((bb * NHEAD + hh) * 64 + d) * SEQ + st * 64 + g * 8) = v;
    }
}

// ---------------- bf16 MFMA GEMM: C = A @ W (+bias)(+gelu)(+res) ----------------
// 128x128 tile, BK=64, 4 waves, 16x16x32 MFMA, 4x4 frags/wave. XOR-swizzled LDS.
template <bool GELU, bool DORES, bool GATHER, bool EXPERT, bool ABF16, bool OUTBF16>
__global__ __launch_bounds__(256, 2) void gemm_mfma(
    const void* __restrict__ Avoid, const unsigned short* __restrict__ Wt,
    const float* __restrict__ bias, const float* __restrict__ res,
    void* __restrict__ Cvoid, int M, int Nn, int Kk,
    const int* __restrict__ rowmap, const int* __restrict__ cntp,
    const int* __restrict__ offp) {
    int n0 = blockIdx.x * 128;
    int m0 = blockIdx.y * 128;
    const float* Af = (const float*)Avoid;
    const unsigned short* Ab = (const unsigned short*)Avoid;
    size_t cbase = 0;
    if (EXPERT) {
        int e = blockIdx.z;
        M = cntp[e];
        if (m0 >= M) return;
        Wt += (size_t)e * Nn * Kk;
        bias += (size_t)e * Nn;
        int oe = offp[e];
        cbase = (size_t)oe * Nn;
        if (GATHER) rowmap += oe;
        else { Af += (size_t)oe * Kk; Ab += (size_t)oe * Kk; }
    }
    __shared__ short As[128 * 64];
    __shared__ short Bs[128 * 64];
    char* asb = (char*)As;
    char* bsb = (char*)Bs;
    int tid = threadIdx.x;
    int wave = tid >> 6, lane = tid & 63;
    int wm = wave >> 1, wn = wave & 1;
    int l15 = lane & 15, l16 = lane >> 4;
    int srow = tid >> 3;
    int sk8 = tid & 7;

    f32x4 acc[4][4];
#pragma unroll
    for (int m = 0; m < 4; m++)
#pragma unroll
        for (int n = 0; n < 4; n++)
#pragma unroll
            for (int j = 0; j < 4; j++) acc[m][n][j] = 0.f;

    for (int k0 = 0; k0 < Kk; k0 += 64) {
#pragma unroll
        for (int i = 0; i < 4; i++) {
            int row = srow + i * 32;
            int grow = m0 + row;
            bool valid = grow < M;
            int arow = grow;
            if (GATHER) arow = valid ? rowmap[grow] : 0;
            bf16x8 v;
            if (ABF16) {
#pragma unroll
                for (int j = 0; j < 8; j++) v[j] = 0;
                if (valid) v = *(const bf16x8*)(Ab + (size_t)arow * Kk + k0 + sk8 * 8);
            } else {
                float4 f0 = make_float4(0.f, 0.f, 0.f, 0.f), f1 = f0;
                if (valid) {
                    const float* p = Af + (size_t)arow * Kk + k0 + sk8 * 8;
                    f0 = *(const float4*)p;
                    f1 = *(const float4*)(p + 4);
                }
                v[0] = (short)f2bf(f0.x); v[1] = (short)f2bf(f0.y);
                v[2] = (short)f2bf(f0.z); v[3] = (short)f2bf(f0.w);
                v[4] = (short)f2bf(f1.x); v[5] = (short)f2bf(f1.y);
                v[6] = (short)f2bf(f1.z); v[7] = (short)f2bf(f1.w);
            }
            *(bf16x8*)(asb + row * 128 + ((sk8 * 16) ^ ((row & 7) << 4))) = v;
        }
#pragma unroll
        for (int i = 0; i < 4; i++) {
            int nrow = srow + i * 32;
            bf16x8 v = *(const bf16x8*)(Wt + (size_t)(n0 + nrow) * Kk + k0 + sk8 * 8);
            *(bf16x8*)(bsb + nrow * 128 + ((sk8 * 16) ^ ((nrow & 7) << 4))) = v;
        }
        __syncthreads();
#pragma unroll
        for (int kk = 0; kk < 2; kk++) {
            int k8 = kk * 4 + l16;
            bf16x8 a[4], b[4];
#pragma unroll
            for (int m = 0; m < 4; m++) {
                int row = wm * 64 + m * 16 + l15;
                a[m] = *(const bf16x8*)(asb + row * 128 + ((k8 * 16) ^ ((row & 7) << 4)));
            }
#pragma unroll
            for (int n = 0; n < 4; n++) {
                int row = wn * 64 + n * 16 + l15;
                b[n] = *(const bf16x8*)(bsb + row * 128 + ((k8 * 16) ^ ((row & 7) << 4)));
            }
#pragma unroll
            for (int m = 0; m < 4; m++)
#pragma unroll
                for (int n = 0; n < 4; n++)
                    acc[m][n] = __builtin_amdgcn_mfma_f32_16x16x32_bf16(a[m], b[n], acc[m][n], 0, 0, 0);
        }
        __syncthreads();
    }

#pragma unroll
    for (int m = 0; m < 4; m++) {
#pragma unroll
        for (int n = 0; n < 4; n++) {
            int col = n0 + wn * 64 + n * 16 + l15;
            float bv = bias ? bias[col] : 0.f;
#pragma unroll
            for (int j = 0; j < 4; j++) {
                int row = m0 + wm * 64 + m * 16 + l16 * 4 + j;
                if (row >= M) continue;
                float val = acc[m][n][j] + bv;
                if (GELU) val = gelu_f(val);
                if (DORES) val += res[(size_t)row * Nn + col];
                if (OUTBF16)
                    ((unsigned short*)Cvoid)[cbase + (size_t)row * Nn + col] = f2bf(val);
                else
                    ((float*)Cvoid)[cbase + (size_t)row * Nn + col] = val;
            }
        }
    }
}

// ---------------- small fp32 GEMM (router only) ----------------
template <bool GELU, bool DORES, bool GATHER, bool EXPERT>
__global__ __launch_bounds__(256) void gemm_tile(
    const float* __restrict__ A, const float* __restrict__ W,
    const float* __restrict__ bias, const float* __restrict__ res,
    float* __restrict__ C, int M, int Nn, int Kk, int lda,
    const int* __restrict__ rowmap, const int* __restrict__ cntp,
    const int* __restrict__ offp) {
    int n0 = blockIdx.x * 64;
    int m0 = blockIdx.y * 64;
    __shared__ float Asf[16][68];
    __shared__ float Wsf[16][68];
    int tid = threadIdx.x;
    int ml = tid >> 2, kl = (tid & 3) << 2;
    bool avalid = (m0 + ml) < M;
    int arow = m0 + ml;
    const float* aptr = A + (size_t)arow * lda + kl;
    int kr = tid >> 4, nc = (tid & 15) << 2;
    bool wvalid = (n0 + nc) < Nn;
    const float* wptr = W + (size_t)kr * Nn + n0 + nc;
    int tm = (tid >> 4) << 2, tn = (tid & 15) << 2;
    float acc[4][4] = {{0.f}};
    for (int k0 = 0; k0 < Kk; k0 += 16) {
        float4 av = make_float4(0.f, 0.f, 0.f, 0.f);
        float4 wv = make_float4(0.f, 0.f, 0.f, 0.f);
        if (avalid) av = *(const float4*)(aptr + k0);
        if (wvalid) wv = *(const float4*)(wptr + (size_t)k0 * Nn);
        Asf[kl + 0][ml] = av.x; Asf[kl + 1][ml] = av.y;
        Asf[kl + 2][ml] = av.z; Asf[kl + 3][ml] = av.w;
        *(float4*)&Wsf[kr][nc] = wv;
        __syncthreads();
#pragma unroll
        for (int kk = 0; kk < 16; kk++) {
            float4 a4 = *(const float4*)&Asf[kk][tm];
            float4 w4 = *(const float4*)&Wsf[kk][tn];
            acc[0][0] += a4.x * w4.x; acc[0][1] += a4.x * w4.y; acc[0][2] += a4.x * w4.z; acc[0][3] += a4.x * w4.w;
            acc[1][0] += a4.y * w4.x; acc[1][1] += a4.y * w4.y; acc[1][2] += a4.y * w4.z; acc[1][3] += a4.y * w4.w;
            acc[2][0] += a4.z * w4.x; acc[2][1] += a4.z * w4.y; acc[2][2] += a4.z * w4.z; acc[2][3] += a4.z * w4.w;
            acc[3][0] += a4.w * w4.x; acc[3][1] += a4.w * w4.y; acc[3][2] += a4.w * w4.z; acc[3][3] += a4.w * w4.w;
        }
        __syncthreads();
    }
#pragma unroll
    for (int i = 0; i < 4; i++) {
        int mm = m0 + tm + i;
        if (mm >= M) break;
        float* crow = C + (size_t)mm * Nn;
#pragma unroll
        for (int j = 0; j < 4; j++) {
            int nn = n0 + tn + j;
            if (nn >= Nn) continue;
            float val = acc[i][j];
            if (bias) val += bias[nn];
            if (GELU) val = gelu_f(val);
            if (DORES) val += res[(size_t)mm * Nn + nn];
            crow[nn] = val;
        }
    }
}

// ---------------- MFMA flash attention: block = (64 q-rows, head, batch), 4 waves ----------------
__global__ __launch_bounds__(256, 2) void attn_mfma(const unsigned short* __restrict__ QKV,
                                                    const unsigned short* __restrict__ Vt,
                                                    unsigned short* __restrict__ O) {
    int qt = blockIdx.x, hh = blockIdx.y, bb = blockIdx.z;
    __shared__ char lds[32768];
    char* Qs = lds;            // 64 rows x 128B, swizzled
    char* Ks = lds + 8192;
    char* Vs = lds + 16384;    // row = d
    char* Ps = lds + 24576;    // 4 waves x (16 rows x 128B)
    int tid = threadIdx.x;
    int w = tid >> 6, l = tid & 63;
    int l15 = l & 15, l16 = l >> 4;

    // stage Q tile
    {
        int r = tid >> 3, g = tid & 7;
        const unsigned short* qbase = QKV + (size_t)(bb * SEQ + qt * QBLK) * 1536 + hh * 64;
#pragma unroll
        for (int i = 0; i < 2; i++) {
            int row = r + i * 32;
            bf16x8 v = *(const bf16x8*)(qbase + (size_t)row * 1536 + g * 8);
            *(bf16x8*)(Qs + row * 128 + ((g * 16) ^ ((row & 7) << 4))) = v;
        }
    }
    f32x4 accO[4];
#pragma unroll
    for (int n = 0; n < 4; n++)
#pragma unroll
        for (int j = 0; j < 4; j++) accO[n][j] = 0.f;
    float m_r[4] = {-1e30f, -1e30f, -1e30f, -1e30f};
    float l_r[4] = {0.f, 0.f, 0.f, 0.f};

    const unsigned short* kbase = QKV + (size_t)(bb * SEQ) * 1536 + 512 + hh * 64;
    const unsigned short* vbase = Vt + (size_t)((bb * NHEAD + hh) * 64) * SEQ;

    for (int kt = 0; kt < SEQ / KBLK; kt++) {
        __syncthreads();   // prev PV done (and Q staging visible at kt=0)
        {
            int r = tid >> 3, g = tid & 7;
#pragma unroll
            for (int i = 0; i < 2; i++) {
                int row = r + i * 32;
                bf16x8 kv = *(const bf16x8*)(kbase + (size_t)(kt * KBLK + row) * 1536 + g * 8);
                *(bf16x8*)(Ks + row * 128 + ((g * 16) ^ ((row & 7) << 4))) = kv;
                bf16x8 vv = *(const bf16x8*)(vbase + (size_t)row * SEQ + kt * KBLK + g * 8);
                *(bf16x8*)(Vs + row * 128 + ((g * 16) ^ ((row & 7) << 4))) = vv;
            }
        }
        __syncthreads();
        // S = Q @ K^T
        f32x4 s_acc[4];
#pragma unroll
        for (int n = 0; n < 4; n++)
#pragma unroll
            for (int j = 0; j < 4; j++) s_acc[n][j] = 0.f;
#pragma unroll
        for (int st = 0; st < 2; st++) {
            int kb = st * 64 + l16 * 16;
            int qrow = w * 16 + l15;
            bf16x8 a = *(const bf16x8*)(Qs + qrow * 128 + (kb ^ ((qrow & 7) << 4)));
#pragma unroll
            for (int n = 0; n < 4; n++) {
                int kr = n * 16 + l15;
                bf16x8 b = *(const bf16x8*)(Ks + kr * 128 + (kb ^ ((kr & 7) << 4)));
                s_acc[n] = __builtin_amdgcn_mfma_f32_16x16x32_bf16(a, b, s_acc[n], 0, 0, 0);
            }
        }
        // online softmax per owned row (C-layout: col=l15, row=l16*4+j)
        char* pw = Ps + w * 2048;
#pragma unroll
        for (int j = 0; j < 4; j++) {
            float s0 = s_acc[0][j] * 0.125f, s1 = s_acc[1][j] * 0.125f;
            float s2 = s_acc[2][j] * 0.125f, s3 = s_acc[3][j] * 0.125f;
            float tmax = fmaxf(fmaxf(s0, s1), fmaxf(s2, s3));
#pragma unroll
            for (int o = 1; o < 16; o <<= 1) tmax = fmaxf(tmax, __shfl_xor(tmax, o));
            float mnew = fmaxf(m_r[j], tmax);
            float resc = __expf(m_r[j] - mnew);
            float p0 = __expf(s0 - mnew), p1 = __expf(s1 - mnew);
            float p2 = __expf(s2 - mnew), p3 = __expf(s3 - mnew);
            float ps = p0 + p1 + p2 + p3;
#pragma unroll
            for (int o = 1; o < 16; o <<= 1) ps += __shfl_xor(ps, o);
            l_r[j] = l_r[j] * resc + ps;
            m_r[j] = mnew;
            accO[0][j] *= resc; accO[1][j] *= resc;
            accO[2][j] *= resc; accO[3][j] *= resc;
            int prow = l16 * 4 + j;
            int sw = (prow & 7) << 4;
            *(unsigned short*)(pw + prow * 128 + ((2 * l15) ^ sw)) = f2bf(p0);
            *(unsigned short*)(pw + prow * 128 + ((2 * l15 + 32) ^ sw)) = f2bf(p1);
            *(unsigned short*)(pw + prow * 128 + ((2 * l15 + 64) ^ sw)) = f2bf(p2);
            *(unsigned short*)(pw + prow * 128 + ((2 * l15 + 96) ^ sw)) = f2bf(p3);
        }
        // O += P @ V (per-wave P region: no barrier needed)
#pragma unroll
        for (int st = 0; st < 2; st++) {
            int kb = st * 64 + l16 * 16;
            bf16x8 pa = *(const bf16x8*)(pw + l15 * 128 + (kb ^ ((l15 & 7) << 4)));
#pragma unroll
            for (int n = 0; n < 4; n++) {
                int vr = n * 16 + l15;
                bf16x8 vb = *(const bf16x8*)(Vs + vr * 128 + (kb ^ ((vr & 7) << 4)));
                accO[n] = __builtin_amdgcn_mfma_f32_16x16x32_bf16(pa, vb, accO[n], 0, 0, 0);
            }
        }
    }
    unsigned short* obase = O + (size_t)(bb * SEQ + qt * QBLK + w * 16) * DMODEL + hh * 64;
#pragma unroll
    for (int j = 0; j < 4; j++) {
        float inv = 1.f / l_r[j];
        int row = l16 * 4 + j;
#pragma unroll
        for (int n = 0; n < 4; n++)
            obase[(size_t)row * DMODEL + n * 16 + l15] = f2bf(accO[n][j] * inv);
    }
}

// ---------------- router / MoE plumbing ----------------
__global__ __launch_bounds__(256) void router_topk(const float* __restrict__ rsc,
                                                   float* __restrict__ topw,
                                                   int* __restrict__ topi,
                                                   int* __restrict__ cnt,
                                                   float* __restrict__ sumP,
                                                   float* __restrict__ zacc) {
    int n = blockIdx.x * blockDim.x + threadIdx.x;
    if (n >= NTOK) return;
    float sc[NEXP];
    float mx = -1e30f;
#pragma unroll
    for (int e = 0; e < NEXP; e++) { sc[e] = rsc[n * NEXP + e]; mx = fmaxf(mx, sc[e]); }
    float se = 0.f;
#pragma unroll
    for (int e = 0; e < NEXP; e++) { sc[e] = expf(sc[e] - mx); se += sc[e]; }
    float invse = 1.f / se;
    float lse = mx + logf(se);
    atomicAdd(zacc, lse * lse);
#pragma unroll
    for (int e = 0; e < NEXP; e++) atomicAdd(&sumP[e], sc[e] * invse);
    float tv[TOPK]; int ti[TOPK];
#pragma unroll
    for (int k = 0; k < TOPK; k++) {
        float best = -1.f; int bi = 0;
#pragma unroll
        for (int e = 0; e < NEXP; e++) {
            if (sc[e] > best) { best = sc[e]; bi = e; }
        }
        tv[k] = best * invse; ti[k] = bi; sc[bi] = -1.f;
    }
    float s4 = tv[0] + tv[1] + tv[2] + tv[3];
#pragma unroll
    for (int k = 0; k < TOPK; k++) {
        topw[n * TOPK + k] = tv[k] / s4;
        topi[n * TOPK + k] = ti[k];
        atomicAdd(&cnt[ti[k]], 1);
    }
}

__global__ void scan_kernel(const int* __restrict__ cnt, int* __restrict__ off) {
    int a = 0;
    for (int e = 0; e < NEXP; e++) { off[e] = a; a += cnt[e]; }
}

__global__ __launch_bounds__(256) void scatter_kernel(const int* __restrict__ topi,
                                                      const int* __restrict__ off,
                                                      int* __restrict__ cursor,
                                                      int* __restrict__ perm,
                                                      int* __restrict__ pos) {
    int i = blockIdx.x * 256 + threadIdx.x;
    int e = topi[i];
    int r = atomicAdd(&cursor[e], 1);
    int g = off[e] + r;
    perm[g] = i >> 2;
    pos[i] = g;
}

__global__ __launch_bounds__(256) void combine_kernel(const float* __restrict__ xb,
                                                      const unsigned short* __restrict__ eogb,
                                                      const float* __restrict__ topw,
                                                      const int* __restrict__ pos,
                                                      float* __restrict__ t2) {
    int idx = blockIdx.x * 256 + threadIdx.x;
    int n = idx >> 9;
    int d = idx & 511;
    float acc = xb[idx];
#pragma unroll
    for (int k = 0; k < TOPK; k++)
        acc += topw[n * TOPK + k] * bf2f(eogb[(size_t)pos[n * TOPK + k] * DMODEL + d]);
    t2[idx] = acc;
}

__global__ void aux_kernel(const int* __restrict__ cnt, const float* __restrict__ sumP,
                           const float* __restrict__ zacc, float* __restrict__ out_aux, int l) {
    float lb = 0.f;
    for (int e = 0; e < NEXP; e++)
        lb += ((float)cnt[e] / (float)NTOK) * (sumP[e] / (float)NTOK);
    lb *= (float)NEXP / (float)TOPK;
    out_aux[l] = lb;
    out_aux[NLAYER + l] = zacc[0] / (float)NTOK;
}

// ---------------- launcher ----------------
extern "C" void kernel_launch(void* const* d_in, const int* in_sizes, int n_in,
                              void* d_out, int out_size, void* d_ws, size_t ws_size,
                              hipStream_t stream) {
    (void)in_sizes; (void)n_in; (void)out_size; (void)ws_size;
    const float* x_in  = (const float*)d_in[0];
    const float* ln1_s = (const float*)d_in[1];
    const float* ln1_b = (const float*)d_in[2];
    const float* ln2_s = (const float*)d_in[3];
    const float* ln2_b = (const float*)d_in[4];
    const float* wq = (const float*)d_in[5];
    const float* bq = (const float*)d_in[6];
    const float* wk = (const float*)d_in[7];
    const float* bk = (const float*)d_in[8];
    const float* wv = (const float*)d_in[9];
    const float* bv = (const float*)d_in[10];
    const float* wo = (const float*)d_in[11];
    const float* bo = (const float*)d_in[12];
    const float* rdw = (const float*)d_in[13];
    const float* ruw = (const float*)d_in[14];
    const float* w1 = (const float*)d_in[15];
    const float* b1 = (const float*)d_in[16];
    const float* w2 = (const float*)d_in[17];
    const float* b2 = (const float*)d_in[18];
    const float* ws1 = (const float*)d_in[19];
    const float* bs1 = (const float*)d_in[20];
    const float* ws2 = (const float*)d_in[21];
    const float* bs2 = (const float*)d_in[22];
    const float* fn_s = (const float*)d_in[23];
    const float* fn_b = (const float*)d_in[24];

    float* ws = (float*)d_ws;
    const size_t ND = (size_t)NTOK * DMODEL;
    size_t o = 0;
    float* xb  = ws + o; o += ND;
    float* h   = ws + o; o += ND;
    float* t2  = ws + o; o += ND;
    unsigned short* qkv_bf = (unsigned short*)(ws + o); o += (size_t)NTOK * 1536 / 2;
    unsigned short* vT     = (unsigned short*)(ws + o); o += ND / 2;
    unsigned short* t1b    = (unsigned short*)(ws + o); o += ND / 2;
    unsigned short* hidb   = (unsigned short*)(ws + o); o += (size_t)NTOK * HSHARED / 2;
    unsigned short* eogb   = (unsigned short*)(ws + o); o += (size_t)NTOK * TOPK * DMODEL / 2;
    float* rhid = ws + o; o += (size_t)NTOK * RRANK;
    float* rsc  = ws + o; o += (size_t)NTOK * NEXP;
    float* topw = ws + o; o += (size_t)NTOK * TOPK;
    float* bqkv = ws + o; o += 1536;
    int* topi = (int*)(ws + o); o += (size_t)NTOK * TOPK;
    int* pos  = (int*)(ws + o); o += (size_t)NTOK * TOPK;
    int* perm = (int*)(ws + o); o += (size_t)NTOK * TOPK;
    int* stats = (int*)(ws + o); o += 256;
    int* cnt = stats;
    int* cursor = stats + 32;
    int* off = stats + 64;
    float* sumP = (float*)(stats + 96);
    float* zacc = sumP + 32;
    // bf16 transposed weights (per-layer, reused)
    unsigned short* wbf = (unsigned short*)(ws + o);
    const size_t DDu = (size_t)DMODEL * DMODEL;
    unsigned short* wqkvt = wbf;                            // [1536][512]
    unsigned short* wot  = wqkvt + 3 * DDu;
    unsigned short* w1t  = wot + DDu;                       // 32x [H][D]
    unsigned short* w2t  = w1t + (size_t)NEXP * DDu;        // 32x [D][H]
    unsigned short* ws1t = w2t + (size_t)NEXP * DDu;        // [HS][D]
    unsigned short* ws2t = ws1t + (size_t)DMODEL * HSHARED; // [D][HS]

    float* out_x = (float*)d_out;
    float* out_aux = out_x + ND;

    hipMemcpyAsync(xb, x_in, ND * sizeof(float), hipMemcpyDeviceToDevice, stream);

    dim3 blk(256);
    dim3 gQKV(1536 / 128, NTOK / 128);        // (12, 32)
    dim3 gD(DMODEL / 128, NTOK / 128);        // (4, 32)
    dim3 gHS(HSHARED / 128, NTOK / 128);      // (32, 32)
    dim3 gE1(HEXP / 128, NTOK * TOPK / 128, NEXP);
    dim3 gE2(DMODEL / 128, NTOK * TOPK / 128, NEXP);
    dim3 gR1(1, NTOK / 64);
    dim3 gR2(1, NTOK / 64);

    for (int l = 0; l < NLAYER; l++) {
        const size_t DD = (size_t)DMODEL * DMODEL;
        // ---- weight transpose+convert for this layer ----
        wt_kernel<<<dim3(16, 16, 1), blk, 0, stream>>>(wq + l * DD, wqkvt, DMODEL, DMODEL);
        wt_kernel<<<dim3(16, 16, 1), blk, 0, stream>>>(wk + l * DD, wqkvt + DDu, DMODEL, DMODEL);
        wt_kernel<<<dim3(16, 16, 1), blk, 0, stream>>>(wv + l * DD, wqkvt + 2 * DDu, DMODEL, DMODEL);
        wt_kernel<<<dim3(16, 16, 1), blk, 0, stream>>>(wo + l * DD, wot, DMODEL, DMODEL);
        wt_kernel<<<dim3(16, 16, NEXP), blk, 0, stream>>>(w1 + (size_t)l * NEXP * DD, w1t, DMODEL, HEXP);
        wt_kernel<<<dim3(16, 16, NEXP), blk, 0, stream>>>(w2 + (size_t)l * NEXP * DD, w2t, HEXP, DMODEL);
        wt_kernel<<<dim3(HSHARED / 32, 16, 1), blk, 0, stream>>>(ws1 + (size_t)l * DMODEL * HSHARED, ws1t, DMODEL, HSHARED);
        wt_kernel<<<dim3(16, HSHARED / 32, 1), blk, 0, stream>>>(ws2 + (size_t)l * HSHARED * DMODEL, ws2t, HSHARED, DMODEL);
        hipMemcpyAsync(bqkv, bq + l * DMODEL, DMODEL * sizeof(float), hipMemcpyDeviceToDevice, stream);
        hipMemcpyAsync(bqkv + 512, bk + l * DMODEL, DMODEL * sizeof(float), hipMemcpyDeviceToDevice, stream);
        hipMemcpyAsync(bqkv + 1024, bv + l * DMODEL, DMODEL * sizeof(float), hipMemcpyDeviceToDevice, stream);

        // ---- LN1 ----
        ln_kernel<<<NTOK / 4, blk, 0, stream>>>(xb, ln1_s + l * DMODEL, ln1_b + l * DMODEL, h);
        // ---- fused QKV (bf16 out, packed [4096][1536]) ----
        gemm_mfma<false, false, false, false, false, true><<<gQKV, blk, 0, stream>>>(
            h, wqkvt, bqkv, nullptr, qkv_bf, NTOK, 1536, DMODEL, nullptr, nullptr, nullptr);
        // ---- V transpose ----
        vtr_kernel<<<dim3(SEQ / 64, NHEAD, BATCH), blk, 0, stream>>>(qkv_bf, vT);
        // ---- MFMA attention ----
        attn_mfma<<<dim3(SEQ / QBLK, NHEAD, BATCH), blk, 0, stream>>>(qkv_bf, vT, t1b);
        // ---- out proj + residual ----
        gemm_mfma<false, true, false, false, true, false><<<gD, blk, 0, stream>>>(
            t1b, wot, bo + l * DMODEL, xb, xb, NTOK, DMODEL, DMODEL, nullptr, nullptr, nullptr);
        // ---- LN2 ----
        ln_kernel<<<NTOK / 4, blk, 0, stream>>>(xb, ln2_s + l * DMODEL, ln2_b + l * DMODEL, h);
        // ---- router (fp32) ----
        hipMemsetAsync(stats, 0, 640, stream);
        gemm_tile<false, false, false, false><<<gR1, blk, 0, stream>>>(
            h, rdw + (size_t)l * DMODEL * RRANK, nullptr, nullptr, rhid, NTOK, RRANK, DMODEL, DMODEL, nullptr, nullptr, nullptr);
        gemm_tile<false, false, false, false><<<gR2, blk, 0, stream>>>(
            rhid, ruw + (size_t)l * RRANK * NEXP, nullptr, nullptr, rsc, NTOK, NEXP, RRANK, RRANK, nullptr, nullptr, nullptr);
        router_topk<<<NTOK / 256, blk, 0, stream>>>(rsc, topw, topi, cnt, sumP, zacc);
        scan_kernel<<<1, 1, 0, stream>>>(cnt, off);
        scatter_kernel<<<NTOK * TOPK / 256, blk, 0, stream>>>(topi, off, cursor, perm, pos);
        aux_kernel<<<1, 1, 0, stream>>>(cnt, sumP, zacc, out_aux, l);
        // ---- expert FFN (gathered, bf16 MFMA) ----
        gemm_mfma<true, false, true, true, false, true><<<gE1, blk, 0, stream>>>(
            h, w1t, b1 + (size_t)l * NEXP * HEXP, nullptr,
            hidb, 0, HEXP, DMODEL, perm, cnt, off);
        gemm_mfma<false, false, false, true, true, true><<<gE2, blk, 0, stream>>>(
            hidb, w2t, b2 + (size_t)l * NEXP * DMODEL, nullptr,
            eogb, 0, DMODEL, HEXP, nullptr, cnt, off);
        // ---- combine ----
        combine_kernel<<<ND / 256, blk, 0, stream>>>(xb, eogb, topw, pos, t2);
        // ---- shared FFN (bf16 MFMA) ----
        gemm_mfma<true, false, false, false, false, true><<<gHS, blk, 0, stream>>>(
            h, ws1t, bs1 + (size_t)l * HSHARED, nullptr,
            hidb, NTOK, HSHARED, DMODEL, nullptr, nullptr, nullptr);
        gemm_mfma<false, true, false, false, true, false><<<gD, blk, 0, stream>>>(
            hidb, ws2t, bs2 + l * DMODEL, t2,
            xb, NTOK, DMODEL, HSHARED, nullptr, nullptr, nullptr);
    }
    ln_kernel<<<NTOK / 4, blk, 0, stream>>>(xb, fn_s, fn_b, out_x);
}

// Round 5
// 1147.192 us; speedup vs baseline: 5.1753x; 1.1747x over previous
//
#include <hip/hip_runtime.h>
#include <math.h>

// ---- problem constants ----
#define NTOK    4096      // B*S
#define DMODEL  512
#define NEXP    32
#define RRANK   64
#define HEXP    512
#define HSHARED 4096
#define SEQ     1024
#define BATCH   4
#define NHEAD   8
#define TOPK    4
#define NLAYER  2
#define QBLK    64
#define KBLK    64

typedef __attribute__((ext_vector_type(8))) short bf16x8;   // 8 bf16 (4 VGPRs)
typedef __attribute__((ext_vector_type(4))) float f32x4;

__device__ __forceinline__ float gelu_f(float x) {
    float t = tanhf(0.7978845608028654f * (x + 0.044715f * x * x * x));
    return 0.5f * x * (1.f + t);
}

// fp32 -> bf16 round-to-nearest-even
__device__ __forceinline__ unsigned short f2bf(float f) {
    unsigned int u = __float_as_uint(f);
    u += 0x7FFFu + ((u >> 16) & 1u);
    return (unsigned short)(u >> 16);
}
__device__ __forceinline__ float bf2f(unsigned short u) {
    return __uint_as_float((unsigned int)u << 16);
}

// ---------------- LayerNorm: one wave per row of 512 ----------------
__global__ __launch_bounds__(256) void ln_kernel(const float* __restrict__ x,
                                                 const float* __restrict__ s,
                                                 const float* __restrict__ b,
                                                 float* __restrict__ out) {
    int wave = threadIdx.x >> 6, lane = threadIdx.x & 63;
    int row = blockIdx.x * 4 + wave;
    const float* xr = x + (size_t)row * DMODEL;
    float v[8];
    float sum = 0.f;
#pragma unroll
    for (int i = 0; i < 8; i++) { v[i] = xr[lane + i * 64]; sum += v[i]; }
#pragma unroll
    for (int o = 32; o; o >>= 1) sum += __shfl_xor(sum, o);
    float m = sum * (1.f / DMODEL);
    float vs = 0.f;
#pragma unroll
    for (int i = 0; i < 8; i++) { float d = v[i] - m; vs += d * d; }
#pragma unroll
    for (int o = 32; o; o >>= 1) vs += __shfl_xor(vs, o);
    float rstd = rsqrtf(vs * (1.f / DMODEL) + 1e-5f);
    float* orow = out + (size_t)row * DMODEL;
#pragma unroll
    for (int i = 0; i < 8; i++) {
        int c = lane + i * 64;
        orow[c] = (v[i] - m) * rstd * s[c] + b[c];
    }
}

// ---------------- weight transpose + fp32->bf16: src [K][N] -> dst [N][K] bf16 ----------------
// 64x64 tile: float4 reads, bf16x8 writes.
__global__ __launch_bounds__(256) void wt_kernel(const float* __restrict__ src,
                                                 unsigned short* __restrict__ dst,
                                                 int K, int N) {
    src += (size_t)blockIdx.z * K * N;
    dst += (size_t)blockIdx.z * K * N;
    __shared__ float t[64][68];
    int k0 = blockIdx.y * 64, n0 = blockIdx.x * 64;
    int tid = threadIdx.x;
    int r = tid >> 2;            // k-row 0..63
    int cb = (tid & 3) * 4;      // col base
#pragma unroll
    for (int i = 0; i < 4; i++)
        *(float4*)&t[r][cb + i * 16] = *(const float4*)(src + (size_t)(k0 + r) * N + n0 + cb + i * 16);
    __syncthreads();
    int g = tid & 7;             // k-group of 8
    int nr = tid >> 3;           // 0..31
#pragma unroll
    for (int i = 0; i < 2; i++) {
        int n = nr + i * 32;
        bf16x8 v;
#pragma unroll
        for (int j = 0; j < 8; j++) v[j] = (short)f2bf(t[g * 8 + j][n]);
        *(bf16x8*)(dst + (size_t)(n0 + n) * K + k0 + g * 8) = v;
    }
}

// ---------------- V transpose: qkv[.,1024+h*64+d] -> Vt[b,h,d,s] (bf16) ----------------
__global__ __launch_bounds__(256) void vtr_kernel(const unsigned short* __restrict__ QKV,
                                                  unsigned short* __restrict__ Vt) {
    int st = blockIdx.x, hh = blockIdx.y, bb = blockIdx.z;
    __shared__ unsigned short t[64][72];
    int r = threadIdx.x >> 3, g = threadIdx.x & 7;
#pragma unroll
    for (int i = 0; i < 2; i++) {
        int row = r + i * 32;
        bf16x8 v = *(const bf16x8*)(QKV + (size_t)(bb * SEQ + st * 64 + row) * 1536 + 1024 + hh * 64 + g * 8);
        *(bf16x8*)&t[row][g * 8] = v;
    }
    __syncthreads();
#pragma unroll
    for (int i = 0; i < 2; i++) {
        int d = r + i * 32;
        bf16x8 v;
#pragma unroll
        for (int j = 0; j < 8; j++) v[j] = (short)t[g * 8 + j][d];
        *(bf16x8*)(Vt + (size_t)((bb * NHEAD + hh) * 64 + d) * SEQ + st * 64 + g * 8) = v;
    }
}

// ---------------- bf16 MFMA GEMM: C = A @ W (+bias)(+gelu)(+res); optional split-K ----------------
// 128x128 tile, BK=64, 4 waves, 16x16x32 MFMA, 4x4 frags/wave. XOR-swizzled LDS.
// SK>1: blockIdx.z = k-slice; partial fp32 written to Cvoid at slice offset (no bias/gelu/res).
template <bool GELU, bool DORES, bool GATHER, bool EXPERT, bool ABF16, bool OUTBF16, int SK = 1>
__global__ __launch_bounds__(256, 2) void gemm_mfma(
    const void* __restrict__ Avoid, const unsigned short* __restrict__ Wt,
    const float* __restrict__ bias, const float* __restrict__ res,
    void* __restrict__ Cvoid, int M, int Nn, int Kk,
    const int* __restrict__ rowmap, const int* __restrict__ cntp,
    const int* __restrict__ offp) {
    int n0 = blockIdx.x * 128;
    int m0 = blockIdx.y * 128;
    const float* Af = (const float*)Avoid;
    const unsigned short* Ab = (const unsigned short*)Avoid;
    size_t cbase = 0;
    int kbeg = 0, kend = Kk;
    if (EXPERT) {
        int e = blockIdx.z;
        M = cntp[e];
        if (m0 >= M) return;
        Wt += (size_t)e * Nn * Kk;
        bias += (size_t)e * Nn;
        int oe = offp[e];
        cbase = (size_t)oe * Nn;
        if (GATHER) rowmap += oe;
        else { Af += (size_t)oe * Kk; Ab += (size_t)oe * Kk; }
    }
    if (SK > 1) {
        int s = blockIdx.z;
        int chunk = Kk / SK;
        kbeg = s * chunk;
        kend = kbeg + chunk;
        cbase = (size_t)s * M * Nn;
    }
    __shared__ short As[128 * 64];
    __shared__ short Bs[128 * 64];
    char* asb = (char*)As;
    char* bsb = (char*)Bs;
    int tid = threadIdx.x;
    int wave = tid >> 6, lane = tid & 63;
    int wm = wave >> 1, wn = wave & 1;
    int l15 = lane & 15, l16 = lane >> 4;
    int srow = tid >> 3;
    int sk8 = tid & 7;

    f32x4 acc[4][4];
#pragma unroll
    for (int m = 0; m < 4; m++)
#pragma unroll
        for (int n = 0; n < 4; n++)
#pragma unroll
            for (int j = 0; j < 4; j++) acc[m][n][j] = 0.f;

    for (int k0 = kbeg; k0 < kend; k0 += 64) {
#pragma unroll
        for (int i = 0; i < 4; i++) {
            int row = srow + i * 32;
            int grow = m0 + row;
            bool valid = grow < M;
            int arow = grow;
            if (GATHER) arow = valid ? rowmap[grow] : 0;
            bf16x8 v;
            if (ABF16) {
#pragma unroll
                for (int j = 0; j < 8; j++) v[j] = 0;
                if (valid) v = *(const bf16x8*)(Ab + (size_t)arow * Kk + k0 + sk8 * 8);
            } else {
                float4 f0 = make_float4(0.f, 0.f, 0.f, 0.f), f1 = f0;
                if (valid) {
                    const float* p = Af + (size_t)arow * Kk + k0 + sk8 * 8;
                    f0 = *(const float4*)p;
                    f1 = *(const float4*)(p + 4);
                }
                v[0] = (short)f2bf(f0.x); v[1] = (short)f2bf(f0.y);
                v[2] = (short)f2bf(f0.z); v[3] = (short)f2bf(f0.w);
                v[4] = (short)f2bf(f1.x); v[5] = (short)f2bf(f1.y);
                v[6] = (short)f2bf(f1.z); v[7] = (short)f2bf(f1.w);
            }
            *(bf16x8*)(asb + row * 128 + ((sk8 * 16) ^ ((row & 7) << 4))) = v;
        }
#pragma unroll
        for (int i = 0; i < 4; i++) {
            int nrow = srow + i * 32;
            bf16x8 v = *(const bf16x8*)(Wt + (size_t)(n0 + nrow) * Kk + k0 + sk8 * 8);
            *(bf16x8*)(bsb + nrow * 128 + ((sk8 * 16) ^ ((nrow & 7) << 4))) = v;
        }
        __syncthreads();
#pragma unroll
        for (int kk = 0; kk < 2; kk++) {
            int k8 = kk * 4 + l16;
            bf16x8 a[4], b[4];
#pragma unroll
            for (int m = 0; m < 4; m++) {
                int row = wm * 64 + m * 16 + l15;
                a[m] = *(const bf16x8*)(asb + row * 128 + ((k8 * 16) ^ ((row & 7) << 4)));
            }
#pragma unroll
            for (int n = 0; n < 4; n++) {
                int row = wn * 64 + n * 16 + l15;
                b[n] = *(const bf16x8*)(bsb + row * 128 + ((k8 * 16) ^ ((row & 7) << 4)));
            }
#pragma unroll
            for (int m = 0; m < 4; m++)
#pragma unroll
                for (int n = 0; n < 4; n++)
                    acc[m][n] = __builtin_amdgcn_mfma_f32_16x16x32_bf16(a[m], b[n], acc[m][n], 0, 0, 0);
        }
        __syncthreads();
    }

#pragma unroll
    for (int m = 0; m < 4; m++) {
#pragma unroll
        for (int n = 0; n < 4; n++) {
            int col = n0 + wn * 64 + n * 16 + l15;
            float bv = (SK == 1 && bias) ? bias[col] : 0.f;
#pragma unroll
            for (int j = 0; j < 4; j++) {
                int row = m0 + wm * 64 + m * 16 + l16 * 4 + j;
                if (row >= M) continue;
                float val = acc[m][n][j] + bv;
                if (SK == 1 && GELU) val = gelu_f(val);
                if (SK == 1 && DORES) val += res[(size_t)row * Nn + col];
                if (SK == 1 && OUTBF16)
                    ((unsigned short*)Cvoid)[cbase + (size_t)row * Nn + col] = f2bf(val);
                else
                    ((float*)Cvoid)[cbase + (size_t)row * Nn + col] = val;
            }
        }
    }
}

// ---------------- split-K reduce (+bias +residual-in-place, optional MoE combine) ----------------
template <int SK, bool MOE>
__global__ __launch_bounds__(256) void reduce_kernel(
    const float* __restrict__ pbuf, const float* __restrict__ bias,
    const unsigned short* __restrict__ eogb, const float* __restrict__ topw,
    const int* __restrict__ pos, float* __restrict__ xb) {
    int idx = (blockIdx.x * 256 + threadIdx.x) * 4;
    int n = idx >> 9, col = idx & 511;
    float4 v = *(float4*)(xb + idx);
    float4 bv = *(const float4*)(bias + col);
    v.x += bv.x; v.y += bv.y; v.z += bv.z; v.w += bv.w;
#pragma unroll
    for (int s = 0; s < SK; s++) {
        float4 p = *(const float4*)(pbuf + (size_t)s * NTOK * DMODEL + idx);
        v.x += p.x; v.y += p.y; v.z += p.z; v.w += p.w;
    }
    if (MOE) {
#pragma unroll
        for (int k = 0; k < TOPK; k++) {
            float w = topw[n * TOPK + k];
            const unsigned short* e = eogb + (size_t)pos[n * TOPK + k] * DMODEL + col;
            ushort4 u = *(const ushort4*)e;
            v.x += w * bf2f(u.x); v.y += w * bf2f(u.y);
            v.z += w * bf2f(u.z); v.w += w * bf2f(u.w);
        }
    }
    *(float4*)(xb + idx) = v;
}

// ---------------- small fp32 GEMM (router only) ----------------
template <bool GELU>
__global__ __launch_bounds__(256) void gemm_tile(
    const float* __restrict__ A, const float* __restrict__ W,
    float* __restrict__ C, int M, int Nn, int Kk, int lda) {
    int n0 = blockIdx.x * 64;
    int m0 = blockIdx.y * 64;
    __shared__ float Asf[16][68];
    __shared__ float Wsf[16][68];
    int tid = threadIdx.x;
    int ml = tid >> 2, kl = (tid & 3) << 2;
    bool avalid = (m0 + ml) < M;
    int arow = m0 + ml;
    const float* aptr = A + (size_t)arow * lda + kl;
    int kr = tid >> 4, nc = (tid & 15) << 2;
    bool wvalid = (n0 + nc) < Nn;
    const float* wptr = W + (size_t)kr * Nn + n0 + nc;
    int tm = (tid >> 4) << 2, tn = (tid & 15) << 2;
    float acc[4][4] = {{0.f}};
    for (int k0 = 0; k0 < Kk; k0 += 16) {
        float4 av = make_float4(0.f, 0.f, 0.f, 0.f);
        float4 wv = make_float4(0.f, 0.f, 0.f, 0.f);
        if (avalid) av = *(const float4*)(aptr + k0);
        if (wvalid) wv = *(const float4*)(wptr + (size_t)k0 * Nn);
        Asf[kl + 0][ml] = av.x; Asf[kl + 1][ml] = av.y;
        Asf[kl + 2][ml] = av.z; Asf[kl + 3][ml] = av.w;
        *(float4*)&Wsf[kr][nc] = wv;
        __syncthreads();
#pragma unroll
        for (int kk = 0; kk < 16; kk++) {
            float4 a4 = *(const float4*)&Asf[kk][tm];
            float4 w4 = *(const float4*)&Wsf[kk][tn];
            acc[0][0] += a4.x * w4.x; acc[0][1] += a4.x * w4.y; acc[0][2] += a4.x * w4.z; acc[0][3] += a4.x * w4.w;
            acc[1][0] += a4.y * w4.x; acc[1][1] += a4.y * w4.y; acc[1][2] += a4.y * w4.z; acc[1][3] += a4.y * w4.w;
            acc[2][0] += a4.z * w4.x; acc[2][1] += a4.z * w4.y; acc[2][2] += a4.z * w4.z; acc[2][3] += a4.z * w4.w;
            acc[3][0] += a4.w * w4.x; acc[3][1] += a4.w * w4.y; acc[3][2] += a4.w * w4.z; acc[3][3] += a4.w * w4.w;
        }
        __syncthreads();
    }
#pragma unroll
    for (int i = 0; i < 4; i++) {
        int mm = m0 + tm + i;
        if (mm >= M) break;
        float* crow = C + (size_t)mm * Nn;
#pragma unroll
        for (int j = 0; j < 4; j++) {
            int nn = n0 + tn + j;
            if (nn >= Nn) continue;
            float val = acc[i][j];
            if (GELU) val = gelu_f(val);
            crow[nn] = val;
        }
    }
}

// ---------------- MFMA flash attention: block = (64 q-rows, head, batch), 4 waves ----------------
__global__ __launch_bounds__(256, 2) void attn_mfma(const unsigned short* __restrict__ QKV,
                                                    const unsigned short* __restrict__ Vt,
                                                    unsigned short* __restrict__ O) {
    int qt = blockIdx.x, hh = blockIdx.y, bb = blockIdx.z;
    __shared__ char lds[32768];
    char* Qs = lds;
    char* Ks = lds + 8192;
    char* Vs = lds + 16384;
    char* Ps = lds + 24576;
    int tid = threadIdx.x;
    int w = tid >> 6, l = tid & 63;
    int l15 = l & 15, l16 = l >> 4;

    {
        int r = tid >> 3, g = tid & 7;
        const unsigned short* qbase = QKV + (size_t)(bb * SEQ + qt * QBLK) * 1536 + hh * 64;
#pragma unroll
        for (int i = 0; i < 2; i++) {
            int row = r + i * 32;
            bf16x8 v = *(const bf16x8*)(qbase + (size_t)row * 1536 + g * 8);
            *(bf16x8*)(Qs + row * 128 + ((g * 16) ^ ((row & 7) << 4))) = v;
        }
    }
    f32x4 accO[4];
#pragma unroll
    for (int n = 0; n < 4; n++)
#pragma unroll
        for (int j = 0; j < 4; j++) accO[n][j] = 0.f;
    float m_r[4] = {-1e30f, -1e30f, -1e30f, -1e30f};
    float l_r[4] = {0.f, 0.f, 0.f, 0.f};

    const unsigned short* kbase = QKV + (size_t)(bb * SEQ) * 1536 + 512 + hh * 64;
    const unsigned short* vbase = Vt + (size_t)((bb * NHEAD + hh) * 64) * SEQ;

    for (int kt = 0; kt < SEQ / KBLK; kt++) {
        __syncthreads();
        {
            int r = tid >> 3, g = tid & 7;
#pragma unroll
            for (int i = 0; i < 2; i++) {
                int row = r + i * 32;
                bf16x8 kv = *(const bf16x8*)(kbase + (size_t)(kt * KBLK + row) * 1536 + g * 8);
                *(bf16x8*)(Ks + row * 128 + ((g * 16) ^ ((row & 7) << 4))) = kv;
                bf16x8 vv = *(const bf16x8*)(vbase + (size_t)row * SEQ + kt * KBLK + g * 8);
                *(bf16x8*)(Vs + row * 128 + ((g * 16) ^ ((row & 7) << 4))) = vv;
            }
        }
        __syncthreads();
        f32x4 s_acc[4];
#pragma unroll
        for (int n = 0; n < 4; n++)
#pragma unroll
            for (int j = 0; j < 4; j++) s_acc[n][j] = 0.f;
#pragma unroll
        for (int st = 0; st < 2; st++) {
            int kb = st * 64 + l16 * 16;
            int qrow = w * 16 + l15;
            bf16x8 a = *(const bf16x8*)(Qs + qrow * 128 + (kb ^ ((qrow & 7) << 4)));
#pragma unroll
            for (int n = 0; n < 4; n++) {
                int kr = n * 16 + l15;
                bf16x8 b = *(const bf16x8*)(Ks + kr * 128 + (kb ^ ((kr & 7) << 4)));
                s_acc[n] = __builtin_amdgcn_mfma_f32_16x16x32_bf16(a, b, s_acc[n], 0, 0, 0);
            }
        }
        char* pw = Ps + w * 2048;
#pragma unroll
        for (int j = 0; j < 4; j++) {
            float s0 = s_acc[0][j] * 0.125f, s1 = s_acc[1][j] * 0.125f;
            float s2 = s_acc[2][j] * 0.125f, s3 = s_acc[3][j] * 0.125f;
            float tmax = fmaxf(fmaxf(s0, s1), fmaxf(s2, s3));
#pragma unroll
            for (int o = 1; o < 16; o <<= 1) tmax = fmaxf(tmax, __shfl_xor(tmax, o));
            float mnew = fmaxf(m_r[j], tmax);
            float resc = __expf(m_r[j] - mnew);
            float p0 = __expf(s0 - mnew), p1 = __expf(s1 - mnew);
            float p2 = __expf(s2 - mnew), p3 = __expf(s3 - mnew);
            float ps = p0 + p1 + p2 + p3;
#pragma unroll
            for (int o = 1; o < 16; o <<= 1) ps += __shfl_xor(ps, o);
            l_r[j] = l_r[j] * resc + ps;
            m_r[j] = mnew;
            accO[0][j] *= resc; accO[1][j] *= resc;
            accO[2][j] *= resc; accO[3][j] *= resc;
            int prow = l16 * 4 + j;
            int sw = (prow & 7) << 4;
            *(unsigned short*)(pw + prow * 128 + ((2 * l15) ^ sw)) = f2bf(p0);
            *(unsigned short*)(pw + prow * 128 + ((2 * l15 + 32) ^ sw)) = f2bf(p1);
            *(unsigned short*)(pw + prow * 128 + ((2 * l15 + 64) ^ sw)) = f2bf(p2);
            *(unsigned short*)(pw + prow * 128 + ((2 * l15 + 96) ^ sw)) = f2bf(p3);
        }
#pragma unroll
        for (int st = 0; st < 2; st++) {
            int kb = st * 64 + l16 * 16;
            bf16x8 pa = *(const bf16x8*)(pw + l15 * 128 + (kb ^ ((l15 & 7) << 4)));
#pragma unroll
            for (int n = 0; n < 4; n++) {
                int vr = n * 16 + l15;
                bf16x8 vb = *(const bf16x8*)(Vs + vr * 128 + (kb ^ ((vr & 7) << 4)));
                accO[n] = __builtin_amdgcn_mfma_f32_16x16x32_bf16(pa, vb, accO[n], 0, 0, 0);
            }
        }
    }
    unsigned short* obase = O + (size_t)(bb * SEQ + qt * QBLK + w * 16) * DMODEL + hh * 64;
#pragma unroll
    for (int j = 0; j < 4; j++) {
        float inv = 1.f / l_r[j];
        int row = l16 * 4 + j;
#pragma unroll
        for (int n = 0; n < 4; n++)
            obase[(size_t)row * DMODEL + n * 16 + l15] = f2bf(accO[n][j] * inv);
    }
}

// ---------------- router / MoE plumbing ----------------
__global__ __launch_bounds__(256) void router_topk(const float* __restrict__ rsc,
                                                   float* __restrict__ topw,
                                                   int* __restrict__ topi,
                                                   int* __restrict__ cnt,
                                                   float* __restrict__ sumP,
                                                   float* __restrict__ zacc) {
    int n = blockIdx.x * blockDim.x + threadIdx.x;
    if (n >= NTOK) return;
    float sc[NEXP];
    float mx = -1e30f;
#pragma unroll
    for (int e = 0; e < NEXP; e++) { sc[e] = rsc[n * NEXP + e]; mx = fmaxf(mx, sc[e]); }
    float se = 0.f;
#pragma unroll
    for (int e = 0; e < NEXP; e++) { sc[e] = expf(sc[e] - mx); se += sc[e]; }
    float invse = 1.f / se;
    float lse = mx + logf(se);
    atomicAdd(zacc, lse * lse);
#pragma unroll
    for (int e = 0; e < NEXP; e++) atomicAdd(&sumP[e], sc[e] * invse);
    float tv[TOPK]; int ti[TOPK];
#pragma unroll
    for (int k = 0; k < TOPK; k++) {
        float best = -1.f; int bi = 0;
#pragma unroll
        for (int e = 0; e < NEXP; e++) {
            if (sc[e] > best) { best = sc[e]; bi = e; }
        }
        tv[k] = best * invse; ti[k] = bi; sc[bi] = -1.f;
    }
    float s4 = tv[0] + tv[1] + tv[2] + tv[3];
#pragma unroll
    for (int k = 0; k < TOPK; k++) {
        topw[n * TOPK + k] = tv[k] / s4;
        topi[n * TOPK + k] = ti[k];
        atomicAdd(&cnt[ti[k]], 1);
    }
}

__global__ void scanaux_kernel(const int* __restrict__ cnt, int* __restrict__ off,
                               const float* __restrict__ sumP, const float* __restrict__ zacc,
                               float* __restrict__ out_aux, int l) {
    int a = 0;
    float lb = 0.f;
    for (int e = 0; e < NEXP; e++) {
        off[e] = a; a += cnt[e];
        lb += ((float)cnt[e] / (float)NTOK) * (sumP[e] / (float)NTOK);
    }
    out_aux[l] = lb * (float)NEXP / (float)TOPK;
    out_aux[NLAYER + l] = zacc[0] / (float)NTOK;
}

__global__ __launch_bounds__(256) void scatter_kernel(const int* __restrict__ topi,
                                                      const int* __restrict__ off,
                                                      int* __restrict__ cursor,
                                                      int* __restrict__ perm,
                                                      int* __restrict__ pos) {
    int i = blockIdx.x * 256 + threadIdx.x;
    int e = topi[i];
    int r = atomicAdd(&cursor[e], 1);
    int g = off[e] + r;
    perm[g] = i >> 2;
    pos[i] = g;
}

// ---------------- launcher ----------------
extern "C" void kernel_launch(void* const* d_in, const int* in_sizes, int n_in,
                              void* d_out, int out_size, void* d_ws, size_t ws_size,
                              hipStream_t stream) {
    (void)in_sizes; (void)n_in; (void)out_size; (void)ws_size;
    const float* x_in  = (const float*)d_in[0];
    const float* ln1_s = (const float*)d_in[1];
    const float* ln1_b = (const float*)d_in[2];
    const float* ln2_s = (const float*)d_in[3];
    const float* ln2_b = (const float*)d_in[4];
    const float* wq = (const float*)d_in[5];
    const float* bq = (const float*)d_in[6];
    const float* wk = (const float*)d_in[7];
    const float* bk = (const float*)d_in[8];
    const float* wv = (const float*)d_in[9];
    const float* bv = (const float*)d_in[10];
    const float* wo = (const float*)d_in[11];
    const float* bo = (const float*)d_in[12];
    const float* rdw = (const float*)d_in[13];
    const float* ruw = (const float*)d_in[14];
    const float* w1 = (const float*)d_in[15];
    const float* b1 = (const float*)d_in[16];
    const float* w2 = (const float*)d_in[17];
    const float* b2 = (const float*)d_in[18];
    const float* ws1 = (const float*)d_in[19];
    const float* bs1 = (const float*)d_in[20];
    const float* ws2 = (const float*)d_in[21];
    const float* bs2 = (const float*)d_in[22];
    const float* fn_s = (const float*)d_in[23];
    const float* fn_b = (const float*)d_in[24];

    float* ws = (float*)d_ws;
    const size_t ND = (size_t)NTOK * DMODEL;
    size_t o = 0;
    float* xb  = ws + o; o += ND;
    float* h   = ws + o; o += ND;
    unsigned short* qkv_bf = (unsigned short*)(ws + o); o += (size_t)NTOK * 1536 / 2;
    unsigned short* vT     = (unsigned short*)(ws + o); o += ND / 2;
    unsigned short* t1b    = (unsigned short*)(ws + o); o += ND / 2;
    unsigned short* hidb   = (unsigned short*)(ws + o); o += (size_t)NTOK * HSHARED / 2;
    unsigned short* eogb   = (unsigned short*)(ws + o); o += (size_t)NTOK * TOPK * DMODEL / 2;
    float* pbuf = ws + o; o += 4 * ND;                 // split-K partials (max SK=4)
    float* rhid = ws + o; o += (size_t)NTOK * RRANK;
    float* rsc  = ws + o; o += (size_t)NTOK * NEXP;
    float* topw = ws + o; o += (size_t)NTOK * TOPK;
    float* bqkv = ws + o; o += 1536;
    int* topi = (int*)(ws + o); o += (size_t)NTOK * TOPK;
    int* pos  = (int*)(ws + o); o += (size_t)NTOK * TOPK;
    int* perm = (int*)(ws + o); o += (size_t)NTOK * TOPK;
    int* stats = (int*)(ws + o); o += 256;
    int* cnt = stats;
    int* cursor = stats + 32;
    int* off = stats + 64;
    float* sumP = (float*)(stats + 96);
    float* zacc = sumP + 32;
    // bf16 transposed weights (per-layer, reused)
    unsigned short* wbf = (unsigned short*)(ws + o);
    const size_t DDu = (size_t)DMODEL * DMODEL;
    unsigned short* wqkvt = wbf;                            // [1536][512]
    unsigned short* wot  = wqkvt + 3 * DDu;
    unsigned short* w1t  = wot + DDu;                       // 32x [H][D]
    unsigned short* w2t  = w1t + (size_t)NEXP * DDu;        // 32x [D][H]
    unsigned short* ws1t = w2t + (size_t)NEXP * DDu;        // [HS][D]
    unsigned short* ws2t = ws1t + (size_t)DMODEL * HSHARED; // [D][HS]

    float* out_x = (float*)d_out;
    float* out_aux = out_x + ND;

    hipMemcpyAsync(xb, x_in, ND * sizeof(float), hipMemcpyDeviceToDevice, stream);

    dim3 blk(256);
    dim3 gQKV(1536 / 128, NTOK / 128);
    dim3 gOP(DMODEL / 128, NTOK / 128, 2);      // O-proj split-K=2
    dim3 gF2(DMODEL / 128, NTOK / 128, 4);      // shared FFN2 split-K=4
    dim3 gHS(HSHARED / 128, NTOK / 128);
    dim3 gE1(HEXP / 128, NTOK * TOPK / 128, NEXP);
    dim3 gE2(DMODEL / 128, NTOK * TOPK / 128, NEXP);
    dim3 gR1(1, NTOK / 64);
    dim3 gR2(1, NTOK / 64);

    for (int l = 0; l < NLAYER; l++) {
        const size_t DD = (size_t)DMODEL * DMODEL;
        // ---- weight transpose+convert for this layer (64x64-tile kernel) ----
        wt_kernel<<<dim3(8, 8, 1), blk, 0, stream>>>(wq + l * DD, wqkvt, DMODEL, DMODEL);
        wt_kernel<<<dim3(8, 8, 1), blk, 0, stream>>>(wk + l * DD, wqkvt + DDu, DMODEL, DMODEL);
        wt_kernel<<<dim3(8, 8, 1), blk, 0, stream>>>(wv + l * DD, wqkvt + 2 * DDu, DMODEL, DMODEL);
        wt_kernel<<<dim3(8, 8, 1), blk, 0, stream>>>(wo + l * DD, wot, DMODEL, DMODEL);
        wt_kernel<<<dim3(8, 8, NEXP), blk, 0, stream>>>(w1 + (size_t)l * NEXP * DD, w1t, DMODEL, HEXP);
        wt_kernel<<<dim3(8, 8, NEXP), blk, 0, stream>>>(w2 + (size_t)l * NEXP * DD, w2t, HEXP, DMODEL);
        wt_kernel<<<dim3(HSHARED / 64, 8, 1), blk, 0, stream>>>(ws1 + (size_t)l * DMODEL * HSHARED, ws1t, DMODEL, HSHARED);
        wt_kernel<<<dim3(8, HSHARED / 64, 1), blk, 0, stream>>>(ws2 + (size_t)l * HSHARED * DMODEL, ws2t, HSHARED, DMODEL);
        hipMemcpyAsync(bqkv, bq + l * DMODEL, DMODEL * sizeof(float), hipMemcpyDeviceToDevice, stream);
        hipMemcpyAsync(bqkv + 512, bk + l * DMODEL, DMODEL * sizeof(float), hipMemcpyDeviceToDevice, stream);
        hipMemcpyAsync(bqkv + 1024, bv + l * DMODEL, DMODEL * sizeof(float), hipMemcpyDeviceToDevice, stream);

        // ---- LN1 ----
        ln_kernel<<<NTOK / 4, blk, 0, stream>>>(xb, ln1_s + l * DMODEL, ln1_b + l * DMODEL, h);
        // ---- fused QKV (bf16 out, packed [4096][1536]) ----
        gemm_mfma<false, false, false, false, false, true><<<gQKV, blk, 0, stream>>>(
            h, wqkvt, bqkv, nullptr, qkv_bf, NTOK, 1536, DMODEL, nullptr, nullptr, nullptr);
        // ---- V transpose ----
        vtr_kernel<<<dim3(SEQ / 64, NHEAD, BATCH), blk, 0, stream>>>(qkv_bf, vT);
        // ---- MFMA attention ----
        attn_mfma<<<dim3(SEQ / QBLK, NHEAD, BATCH), blk, 0, stream>>>(qkv_bf, vT, t1b);
        // ---- out proj: split-K=2 -> pbuf; reduce adds bias + residual into xb ----
        gemm_mfma<false, false, false, false, true, false, 2><<<gOP, blk, 0, stream>>>(
            t1b, wot, nullptr, nullptr, pbuf, NTOK, DMODEL, DMODEL, nullptr, nullptr, nullptr);
        reduce_kernel<2, false><<<ND / 1024, blk, 0, stream>>>(
            pbuf, bo + l * DMODEL, nullptr, nullptr, nullptr, xb);
        // ---- LN2 ----
        ln_kernel<<<NTOK / 4, blk, 0, stream>>>(xb, ln2_s + l * DMODEL, ln2_b + l * DMODEL, h);
        // ---- router (fp32) ----
        hipMemsetAsync(stats, 0, 640, stream);
        gemm_tile<false><<<gR1, blk, 0, stream>>>(
            h, rdw + (size_t)l * DMODEL * RRANK, rhid, NTOK, RRANK, DMODEL, DMODEL);
        gemm_tile<false><<<gR2, blk, 0, stream>>>(
            rhid, ruw + (size_t)l * RRANK * NEXP, rsc, NTOK, NEXP, RRANK, RRANK);
        router_topk<<<NTOK / 256, blk, 0, stream>>>(rsc, topw, topi, cnt, sumP, zacc);
        scanaux_kernel<<<1, 1, 0, stream>>>(cnt, off, sumP, zacc, out_aux, l);
        scatter_kernel<<<NTOK * TOPK / 256, blk, 0, stream>>>(topi, off, cursor, perm, pos);
        // ---- expert FFN (gathered, bf16 MFMA) ----
        gemm_mfma<true, false, true, true, false, true><<<gE1, blk, 0, stream>>>(
            h, w1t, b1 + (size_t)l * NEXP * HEXP, nullptr,
            hidb, 0, HEXP, DMODEL, perm, cnt, off);
        gemm_mfma<false, false, false, true, true, true><<<gE2, blk, 0, stream>>>(
            hidb, w2t, b2 + (size_t)l * NEXP * DMODEL, nullptr,
            eogb, 0, DMODEL, HEXP, nullptr, cnt, off);
        // ---- shared FFN1 ----
        gemm_mfma<true, false, false, false, false, true><<<gHS, blk, 0, stream>>>(
            h, ws1t, bs1 + (size_t)l * HSHARED, nullptr,
            hidb, NTOK, HSHARED, DMODEL, nullptr, nullptr, nullptr);
        // ---- shared FFN2: split-K=4 -> pbuf; fused reduce adds bias + residual + MoE combine ----
        gemm_mfma<false, false, false, false, true, false, 4><<<gF2, blk, 0, stream>>>(
            hidb, ws2t, nullptr, nullptr, pbuf, NTOK, DMODEL, HSHARED, nullptr, nullptr, nullptr);
        reduce_kernel<4, true><<<ND / 1024, blk, 0, stream>>>(
            pbuf, bs2 + l * DMODEL, eogb, topw, pos, xb);
    }
    ln_kernel<<<NTOK / 4, blk, 0, stream>>>(xb, fn_s, fn_b, out_x);
}

// Round 6
// 931.834 us; speedup vs baseline: 6.3714x; 1.2311x over previous
//
#include <hip/hip_runtime.h>
#include <math.h>

// ---- problem constants ----
#define NTOK    4096      // B*S
#define DMODEL  512
#define NEXP    32
#define RRANK   64
#define HEXP    512
#define HSHARED 4096
#define SEQ     1024
#define BATCH   4
#define NHEAD   8
#define TOPK    4
#define NLAYER  2
#define QBLK    64
#define KBLK    64
#define MAXTILE 160       // max padded expert m-tiles: 16384/128 + 32

typedef __attribute__((ext_vector_type(8))) short bf16x8;
typedef __attribute__((ext_vector_type(4))) float f32x4;

__device__ __forceinline__ float gelu_f(float x) {
    float t = tanhf(0.7978845608028654f * (x + 0.044715f * x * x * x));
    return 0.5f * x * (1.f + t);
}
__device__ __forceinline__ unsigned short f2bf(float f) {
    unsigned int u = __float_as_uint(f);
    u += 0x7FFFu + ((u >> 16) & 1u);
    return (unsigned short)(u >> 16);
}
__device__ __forceinline__ float bf2f(unsigned short u) {
    return __uint_as_float((unsigned int)u << 16);
}

// ---------------- LayerNorm: one wave per row of 512; MODE 0=f32, 1=bf16, 2=both ----------------
template <int MODE>
__global__ __launch_bounds__(256) void ln_kernel(const float* __restrict__ x,
                                                 const float* __restrict__ s,
                                                 const float* __restrict__ b,
                                                 float* __restrict__ outf,
                                                 unsigned short* __restrict__ outb) {
    int wave = threadIdx.x >> 6, lane = threadIdx.x & 63;
    int row = blockIdx.x * 4 + wave;
    const float* xr = x + (size_t)row * DMODEL;
    float v[8];
    float sum = 0.f;
#pragma unroll
    for (int i = 0; i < 8; i++) { v[i] = xr[lane + i * 64]; sum += v[i]; }
#pragma unroll
    for (int o = 32; o; o >>= 1) sum += __shfl_xor(sum, o);
    float m = sum * (1.f / DMODEL);
    float vs = 0.f;
#pragma unroll
    for (int i = 0; i < 8; i++) { float d = v[i] - m; vs += d * d; }
#pragma unroll
    for (int o = 32; o; o >>= 1) vs += __shfl_xor(vs, o);
    float rstd = rsqrtf(vs * (1.f / DMODEL) + 1e-5f);
#pragma unroll
    for (int i = 0; i < 8; i++) {
        int c = lane + i * 64;
        float r = (v[i] - m) * rstd * s[c] + b[c];
        if (MODE != 1) outf[(size_t)row * DMODEL + c] = r;
        if (MODE != 0) outb[(size_t)row * DMODEL + c] = f2bf(r);
    }
}

// ---------------- weight transpose + fp32->bf16: src [K][N] -> dst [N][K] bf16 ----------------
__global__ __launch_bounds__(256) void wt_kernel(const float* __restrict__ src,
                                                 unsigned short* __restrict__ dst,
                                                 int K, int N) {
    src += (size_t)blockIdx.z * K * N;
    dst += (size_t)blockIdx.z * K * N;
    __shared__ float t[64][68];
    int k0 = blockIdx.y * 64, n0 = blockIdx.x * 64;
    int tid = threadIdx.x;
    int r = tid >> 2;
    int cb = (tid & 3) * 4;
#pragma unroll
    for (int i = 0; i < 4; i++)
        *(float4*)&t[r][cb + i * 16] = *(const float4*)(src + (size_t)(k0 + r) * N + n0 + cb + i * 16);
    __syncthreads();
    int g = tid & 7;
    int nr = tid >> 3;
#pragma unroll
    for (int i = 0; i < 2; i++) {
        int n = nr + i * 32;
        bf16x8 v;
#pragma unroll
        for (int j = 0; j < 8; j++) v[j] = (short)f2bf(t[g * 8 + j][n]);
        *(bf16x8*)(dst + (size_t)(n0 + n) * K + k0 + g * 8) = v;
    }
}

// ---------------- V transpose: qkv[.,1024+h*64+d] -> Vt[b,h,d,s] (bf16) ----------------
__global__ __launch_bounds__(256) void vtr_kernel(const unsigned short* __restrict__ QKV,
                                                  unsigned short* __restrict__ Vt) {
    int st = blockIdx.x, hh = blockIdx.y, bb = blockIdx.z;
    __shared__ unsigned short t[64][72];
    int r = threadIdx.x >> 3, g = threadIdx.x & 7;
#pragma unroll
    for (int i = 0; i < 2; i++) {
        int row = r + i * 32;
        bf16x8 v = *(const bf16x8*)(QKV + (size_t)(bb * SEQ + st * 64 + row) * 1536 + 1024 + hh * 64 + g * 8);
        *(bf16x8*)&t[row][g * 8] = v;
    }
    __syncthreads();
#pragma unroll
    for (int i = 0; i < 2; i++) {
        int d = r + i * 32;
        bf16x8 v;
#pragma unroll
        for (int j = 0; j < 8; j++) v[j] = (short)t[g * 8 + j][d];
        *(bf16x8*)(Vt + (size_t)((bb * NHEAD + hh) * 64 + d) * SEQ + st * 64 + g * 8) = v;
    }
}

// ---------------- bf16 MFMA GEMM (128x128 tile, BK=64, XOR-swizzled LDS) ----------------
// EXPERT: blockIdx.y = padded supertile; tinfo[0]=ntiles, tinfo[1+2t]=e, tinfo[2+2t]=m0.
template <bool GELU, bool DORES, bool GATHER, bool EXPERT, bool ABF16, bool OUTBF16, int SK = 1>
__global__ __launch_bounds__(256, 2) void gemm_mfma(
    const void* __restrict__ Avoid, const unsigned short* __restrict__ Wt,
    const float* __restrict__ bias, const float* __restrict__ res,
    void* __restrict__ Cvoid, int M, int Nn, int Kk,
    const int* __restrict__ rowmap, const int* __restrict__ cntp,
    const int* __restrict__ offp, const int* __restrict__ tinfo) {
    int n0 = blockIdx.x * 128;
    int m0;
    const float* Af = (const float*)Avoid;
    const unsigned short* Ab = (const unsigned short*)Avoid;
    size_t cbase = 0;
    int kbeg = 0, kend = Kk;
    if (EXPERT) {
        int t = blockIdx.y;
        if (t >= tinfo[0]) return;
        int e = tinfo[1 + 2 * t];
        m0 = tinfo[2 + 2 * t];
        M = cntp[e];
        Wt += (size_t)e * Nn * Kk;
        bias += (size_t)e * Nn;
        int oe = offp[e];
        cbase = (size_t)oe * Nn;
        if (GATHER) rowmap += oe;
        else Ab += (size_t)oe * Kk;
    } else {
        m0 = blockIdx.y * 128;
    }
    if (SK > 1) {
        int s = blockIdx.z;
        int chunk = Kk / SK;
        kbeg = s * chunk;
        kend = kbeg + chunk;
        cbase = (size_t)s * M * Nn;
    }
    __shared__ short As[128 * 64];
    __shared__ short Bs[128 * 64];
    char* asb = (char*)As;
    char* bsb = (char*)Bs;
    int tid = threadIdx.x;
    int wave = tid >> 6, lane = tid & 63;
    int wm = wave >> 1, wn = wave & 1;
    int l15 = lane & 15, l16 = lane >> 4;
    int srow = tid >> 3;
    int sk8 = tid & 7;

    f32x4 acc[4][4];
#pragma unroll
    for (int m = 0; m < 4; m++)
#pragma unroll
        for (int n = 0; n < 4; n++)
#pragma unroll
            for (int j = 0; j < 4; j++) acc[m][n][j] = 0.f;

    for (int k0 = kbeg; k0 < kend; k0 += 64) {
#pragma unroll
        for (int i = 0; i < 4; i++) {
            int row = srow + i * 32;
            int grow = m0 + row;
            bool valid = grow < M;
            int arow = grow;
            if (GATHER) arow = valid ? rowmap[grow] : 0;
            bf16x8 v;
            if (ABF16) {
#pragma unroll
                for (int j = 0; j < 8; j++) v[j] = 0;
                if (valid) v = *(const bf16x8*)(Ab + (size_t)arow * Kk + k0 + sk8 * 8);
            } else {
                float4 f0 = make_float4(0.f, 0.f, 0.f, 0.f), f1 = f0;
                if (valid) {
                    const float* p = Af + (size_t)arow * Kk + k0 + sk8 * 8;
                    f0 = *(const float4*)p;
                    f1 = *(const float4*)(p + 4);
                }
                v[0] = (short)f2bf(f0.x); v[1] = (short)f2bf(f0.y);
                v[2] = (short)f2bf(f0.z); v[3] = (short)f2bf(f0.w);
                v[4] = (short)f2bf(f1.x); v[5] = (short)f2bf(f1.y);
                v[6] = (short)f2bf(f1.z); v[7] = (short)f2bf(f1.w);
            }
            *(bf16x8*)(asb + row * 128 + ((sk8 * 16) ^ ((row & 7) << 4))) = v;
        }
#pragma unroll
        for (int i = 0; i < 4; i++) {
            int nrow = srow + i * 32;
            bf16x8 v = *(const bf16x8*)(Wt + (size_t)(n0 + nrow) * Kk + k0 + sk8 * 8);
            *(bf16x8*)(bsb + nrow * 128 + ((sk8 * 16) ^ ((nrow & 7) << 4))) = v;
        }
        __syncthreads();
#pragma unroll
        for (int kk = 0; kk < 2; kk++) {
            int k8 = kk * 4 + l16;
            bf16x8 a[4], b[4];
#pragma unroll
            for (int m = 0; m < 4; m++) {
                int row = wm * 64 + m * 16 + l15;
                a[m] = *(const bf16x8*)(asb + row * 128 + ((k8 * 16) ^ ((row & 7) << 4)));
            }
#pragma unroll
            for (int n = 0; n < 4; n++) {
                int row = wn * 64 + n * 16 + l15;
                b[n] = *(const bf16x8*)(bsb + row * 128 + ((k8 * 16) ^ ((row & 7) << 4)));
            }
#pragma unroll
            for (int m = 0; m < 4; m++)
#pragma unroll
                for (int n = 0; n < 4; n++)
                    acc[m][n] = __builtin_amdgcn_mfma_f32_16x16x32_bf16(a[m], b[n], acc[m][n], 0, 0, 0);
        }
        __syncthreads();
    }

#pragma unroll
    for (int m = 0; m < 4; m++) {
#pragma unroll
        for (int n = 0; n < 4; n++) {
            int col = n0 + wn * 64 + n * 16 + l15;
            float bv = (SK == 1 && bias) ? bias[col] : 0.f;
#pragma unroll
            for (int j = 0; j < 4; j++) {
                int row = m0 + wm * 64 + m * 16 + l16 * 4 + j;
                if (row >= M) continue;
                float val = acc[m][n][j] + bv;
                if (SK == 1 && GELU) val = gelu_f(val);
                if (SK == 1 && DORES) val += res[(size_t)row * Nn + col];
                if (SK == 1 && OUTBF16)
                    ((unsigned short*)Cvoid)[cbase + (size_t)row * Nn + col] = f2bf(val);
                else
                    ((float*)Cvoid)[cbase + (size_t)row * Nn + col] = val;
            }
        }
    }
}

// ---------------- split-K reduce (+bias +residual, optional MoE combine) ----------------
template <int SK, bool MOE>
__global__ __launch_bounds__(256) void reduce_kernel(
    const float* __restrict__ pbuf, const float* __restrict__ bias,
    const unsigned short* __restrict__ eogb, const float* __restrict__ topw,
    const int* __restrict__ pos, float* __restrict__ xb) {
    int idx = (blockIdx.x * 256 + threadIdx.x) * 4;
    int n = idx >> 9, col = idx & 511;
    float4 v = *(float4*)(xb + idx);
    float4 bv = *(const float4*)(bias + col);
    v.x += bv.x; v.y += bv.y; v.z += bv.z; v.w += bv.w;
#pragma unroll
    for (int s = 0; s < SK; s++) {
        float4 p = *(const float4*)(pbuf + (size_t)s * NTOK * DMODEL + idx);
        v.x += p.x; v.y += p.y; v.z += p.z; v.w += p.w;
    }
    if (MOE) {
#pragma unroll
        for (int k = 0; k < TOPK; k++) {
            float w = topw[n * TOPK + k];
            const unsigned short* e = eogb + (size_t)pos[n * TOPK + k] * DMODEL + col;
            ushort4 u = *(const ushort4*)e;
            v.x += w * bf2f(u.x); v.y += w * bf2f(u.y);
            v.z += w * bf2f(u.z); v.w += w * bf2f(u.w);
        }
    }
    *(float4*)(xb + idx) = v;
}

// ---------------- small fp32 GEMM (router only) ----------------
template <bool GELU>
__global__ __launch_bounds__(256) void gemm_tile(
    const float* __restrict__ A, const float* __restrict__ W,
    float* __restrict__ C, int M, int Nn, int Kk, int lda) {
    int n0 = blockIdx.x * 64;
    int m0 = blockIdx.y * 64;
    __shared__ float Asf[16][68];
    __shared__ float Wsf[16][68];
    int tid = threadIdx.x;
    int ml = tid >> 2, kl = (tid & 3) << 2;
    bool avalid = (m0 + ml) < M;
    int arow = m0 + ml;
    const float* aptr = A + (size_t)arow * lda + kl;
    int kr = tid >> 4, nc = (tid & 15) << 2;
    bool wvalid = (n0 + nc) < Nn;
    const float* wptr = W + (size_t)kr * Nn + n0 + nc;
    int tm = (tid >> 4) << 2, tn = (tid & 15) << 2;
    float acc[4][4] = {{0.f}};
    for (int k0 = 0; k0 < Kk; k0 += 16) {
        float4 av = make_float4(0.f, 0.f, 0.f, 0.f);
        float4 wv = make_float4(0.f, 0.f, 0.f, 0.f);
        if (avalid) av = *(const float4*)(aptr + k0);
        if (wvalid) wv = *(const float4*)(wptr + (size_t)k0 * Nn);
        Asf[kl + 0][ml] = av.x; Asf[kl + 1][ml] = av.y;
        Asf[kl + 2][ml] = av.z; Asf[kl + 3][ml] = av.w;
        *(float4*)&Wsf[kr][nc] = wv;
        __syncthreads();
#pragma unroll
        for (int kk = 0; kk < 16; kk++) {
            float4 a4 = *(const float4*)&Asf[kk][tm];
            float4 w4 = *(const float4*)&Wsf[kk][tn];
            acc[0][0] += a4.x * w4.x; acc[0][1] += a4.x * w4.y; acc[0][2] += a4.x * w4.z; acc[0][3] += a4.x * w4.w;
            acc[1][0] += a4.y * w4.x; acc[1][1] += a4.y * w4.y; acc[1][2] += a4.y * w4.z; acc[1][3] += a4.y * w4.w;
            acc[2][0] += a4.z * w4.x; acc[2][1] += a4.z * w4.y; acc[2][2] += a4.z * w4.z; acc[2][3] += a4.z * w4.w;
            acc[3][0] += a4.w * w4.x; acc[3][1] += a4.w * w4.y; acc[3][2] += a4.w * w4.z; acc[3][3] += a4.w * w4.w;
        }
        __syncthreads();
    }
#pragma unroll
    for (int i = 0; i < 4; i++) {
        int mm = m0 + tm + i;
        if (mm >= M) break;
        float* crow = C + (size_t)mm * Nn;
#pragma unroll
        for (int j = 0; j < 4; j++) {
            int nn = n0 + tn + j;
            if (nn >= Nn) continue;
            float val = acc[i][j];
            if (GELU) val = gelu_f(val);
            crow[nn] = val;
        }
    }
}

// ---------------- MFMA flash attention: block = (64 q-rows, head, batch), 4 waves ----------------
__global__ __launch_bounds__(256, 2) void attn_mfma(const unsigned short* __restrict__ QKV,
                                                    const unsigned short* __restrict__ Vt,
                                                    unsigned short* __restrict__ O) {
    int qt = blockIdx.x, hh = blockIdx.y, bb = blockIdx.z;
    __shared__ char lds[32768];
    char* Qs = lds;
    char* Ks = lds + 8192;
    char* Vs = lds + 16384;
    char* Ps = lds + 24576;
    int tid = threadIdx.x;
    int w = tid >> 6, l = tid & 63;
    int l15 = l & 15, l16 = l >> 4;

    {
        int r = tid >> 3, g = tid & 7;
        const unsigned short* qbase = QKV + (size_t)(bb * SEQ + qt * QBLK) * 1536 + hh * 64;
#pragma unroll
        for (int i = 0; i < 2; i++) {
            int row = r + i * 32;
            bf16x8 v = *(const bf16x8*)(qbase + (size_t)row * 1536 + g * 8);
            *(bf16x8*)(Qs + row * 128 + ((g * 16) ^ ((row & 7) << 4))) = v;
        }
    }
    f32x4 accO[4];
#pragma unroll
    for (int n = 0; n < 4; n++)
#pragma unroll
        for (int j = 0; j < 4; j++) accO[n][j] = 0.f;
    float m_r[4] = {-1e30f, -1e30f, -1e30f, -1e30f};
    float l_r[4] = {0.f, 0.f, 0.f, 0.f};

    const unsigned short* kbase = QKV + (size_t)(bb * SEQ) * 1536 + 512 + hh * 64;
    const unsigned short* vbase = Vt + (size_t)((bb * NHEAD + hh) * 64) * SEQ;

    for (int kt = 0; kt < SEQ / KBLK; kt++) {
        __syncthreads();
        {
            int r = tid >> 3, g = tid & 7;
#pragma unroll
            for (int i = 0; i < 2; i++) {
                int row = r + i * 32;
                bf16x8 kv = *(const bf16x8*)(kbase + (size_t)(kt * KBLK + row) * 1536 + g * 8);
                *(bf16x8*)(Ks + row * 128 + ((g * 16) ^ ((row & 7) << 4))) = kv;
                bf16x8 vv = *(const bf16x8*)(vbase + (size_t)row * SEQ + kt * KBLK + g * 8);
                *(bf16x8*)(Vs + row * 128 + ((g * 16) ^ ((row & 7) << 4))) = vv;
            }
        }
        __syncthreads();
        f32x4 s_acc[4];
#pragma unroll
        for (int n = 0; n < 4; n++)
#pragma unroll
            for (int j = 0; j < 4; j++) s_acc[n][j] = 0.f;
#pragma unroll
        for (int st = 0; st < 2; st++) {
            int kb = st * 64 + l16 * 16;
            int qrow = w * 16 + l15;
            bf16x8 a = *(const bf16x8*)(Qs + qrow * 128 + (kb ^ ((qrow & 7) << 4)));
#pragma unroll
            for (int n = 0; n < 4; n++) {
                int kr = n * 16 + l15;
                bf16x8 b = *(const bf16x8*)(Ks + kr * 128 + (kb ^ ((kr & 7) << 4)));
                s_acc[n] = __builtin_amdgcn_mfma_f32_16x16x32_bf16(a, b, s_acc[n], 0, 0, 0);
            }
        }
        char* pw = Ps + w * 2048;
#pragma unroll
        for (int j = 0; j < 4; j++) {
            float s0 = s_acc[0][j] * 0.125f, s1 = s_acc[1][j] * 0.125f;
            float s2 = s_acc[2][j] * 0.125f, s3 = s_acc[3][j] * 0.125f;
            float tmax = fmaxf(fmaxf(s0, s1), fmaxf(s2, s3));
#pragma unroll
            for (int o = 1; o < 16; o <<= 1) tmax = fmaxf(tmax, __shfl_xor(tmax, o));
            float mnew = fmaxf(m_r[j], tmax);
            float resc = __expf(m_r[j] - mnew);
            float p0 = __expf(s0 - mnew), p1 = __expf(s1 - mnew);
            float p2 = __expf(s2 - mnew), p3 = __expf(s3 - mnew);
            float ps = p0 + p1 + p2 + p3;
#pragma unroll
            for (int o = 1; o < 16; o <<= 1) ps += __shfl_xor(ps, o);
            l_r[j] = l_r[j] * resc + ps;
            m_r[j] = mnew;
            accO[0][j] *= resc; accO[1][j] *= resc;
            accO[2][j] *= resc; accO[3][j] *= resc;
            int prow = l16 * 4 + j;
            int sw = (prow & 7) << 4;
            *(unsigned short*)(pw + prow * 128 + ((2 * l15) ^ sw)) = f2bf(p0);
            *(unsigned short*)(pw + prow * 128 + ((2 * l15 + 32) ^ sw)) = f2bf(p1);
            *(unsigned short*)(pw + prow * 128 + ((2 * l15 + 64) ^ sw)) = f2bf(p2);
            *(unsigned short*)(pw + prow * 128 + ((2 * l15 + 96) ^ sw)) = f2bf(p3);
        }
#pragma unroll
        for (int st = 0; st < 2; st++) {
            int kb = st * 64 + l16 * 16;
            bf16x8 pa = *(const bf16x8*)(pw + l15 * 128 + (kb ^ ((l15 & 7) << 4)));
#pragma unroll
            for (int n = 0; n < 4; n++) {
                int vr = n * 16 + l15;
                bf16x8 vb = *(const bf16x8*)(Vs + vr * 128 + (kb ^ ((vr & 7) << 4)));
                accO[n] = __builtin_amdgcn_mfma_f32_16x16x32_bf16(pa, vb, accO[n], 0, 0, 0);
            }
        }
    }
    unsigned short* obase = O + (size_t)(bb * SEQ + qt * QBLK + w * 16) * DMODEL + hh * 64;
#pragma unroll
    for (int j = 0; j < 4; j++) {
        float inv = 1.f / l_r[j];
        int row = l16 * 4 + j;
#pragma unroll
        for (int n = 0; n < 4; n++)
            obase[(size_t)row * DMODEL + n * 16 + l15] = f2bf(accO[n][j] * inv);
    }
}

// ---------------- router: LDS-accumulated stats (one global atomic per expert per block) ----------------
__global__ __launch_bounds__(256) void router_topk(const float* __restrict__ rsc,
                                                   float* __restrict__ topw,
                                                   int* __restrict__ topi,
                                                   int* __restrict__ cnt,
                                                   float* __restrict__ sumP,
                                                   float* __restrict__ zacc) {
    __shared__ float sP[NEXP];
    __shared__ int sC[NEXP];
    __shared__ float sZ;
    if (threadIdx.x < NEXP) { sP[threadIdx.x] = 0.f; sC[threadIdx.x] = 0; }
    if (threadIdx.x == 0) sZ = 0.f;
    __syncthreads();
    int n = blockIdx.x * blockDim.x + threadIdx.x;
    float sc[NEXP];
    float mx = -1e30f;
#pragma unroll
    for (int e = 0; e < NEXP; e++) { sc[e] = rsc[n * NEXP + e]; mx = fmaxf(mx, sc[e]); }
    float se = 0.f;
#pragma unroll
    for (int e = 0; e < NEXP; e++) { sc[e] = expf(sc[e] - mx); se += sc[e]; }
    float invse = 1.f / se;
    float lse = mx + logf(se);
    atomicAdd(&sZ, lse * lse);
#pragma unroll
    for (int e = 0; e < NEXP; e++) atomicAdd(&sP[e], sc[e] * invse);
    float tv[TOPK]; int ti[TOPK];
#pragma unroll
    for (int k = 0; k < TOPK; k++) {
        float best = -1.f; int bi = 0;
#pragma unroll
        for (int e = 0; e < NEXP; e++) {
            if (sc[e] > best) { best = sc[e]; bi = e; }
        }
        tv[k] = best * invse; ti[k] = bi; sc[bi] = -1.f;
    }
    float s4 = tv[0] + tv[1] + tv[2] + tv[3];
#pragma unroll
    for (int k = 0; k < TOPK; k++) {
        topw[n * TOPK + k] = tv[k] / s4;
        topi[n * TOPK + k] = ti[k];
        atomicAdd(&sC[ti[k]], 1);
    }
    __syncthreads();
    if (threadIdx.x < NEXP) {
        atomicAdd(&sumP[threadIdx.x], sP[threadIdx.x]);
        atomicAdd(&cnt[threadIdx.x], sC[threadIdx.x]);
    }
    if (threadIdx.x == 0) atomicAdd(zacc, sZ);
}

// ---------------- scan: padded offsets + tile map + aux losses ----------------
__global__ void scanaux_kernel(const int* __restrict__ cnt, int* __restrict__ poff,
                               int* __restrict__ tinfo,
                               const float* __restrict__ sumP, const float* __restrict__ zacc,
                               float* __restrict__ out_aux, int l) {
    int a = 0, t = 0;
    float lb = 0.f;
    for (int e = 0; e < NEXP; e++) {
        poff[e] = a;
        int c = cnt[e];
        int nt = (c + 127) >> 7;
        for (int i = 0; i < nt; i++) {
            tinfo[1 + 2 * t] = e;
            tinfo[2 + 2 * t] = i * 128;
            t++;
        }
        a += nt * 128;
        lb += ((float)c / (float)NTOK) * (sumP[e] / (float)NTOK);
    }
    tinfo[0] = t;
    out_aux[l] = lb * (float)NEXP / (float)TOPK;
    out_aux[NLAYER + l] = zacc[0] / (float)NTOK;
}

__global__ __launch_bounds__(256) void scatter_kernel(const int* __restrict__ topi,
                                                      const int* __restrict__ poff,
                                                      int* __restrict__ cursor,
                                                      int* __restrict__ perm,
                                                      int* __restrict__ pos) {
    int i = blockIdx.x * 256 + threadIdx.x;
    int e = topi[i];
    int r = atomicAdd(&cursor[e], 1);
    int g = poff[e] + r;
    perm[g] = i >> 2;
    pos[i] = g;
}

// ---------------- launcher ----------------
extern "C" void kernel_launch(void* const* d_in, const int* in_sizes, int n_in,
                              void* d_out, int out_size, void* d_ws, size_t ws_size,
                              hipStream_t stream) {
    (void)in_sizes; (void)n_in; (void)out_size; (void)ws_size;
    const float* x_in  = (const float*)d_in[0];
    const float* ln1_s = (const float*)d_in[1];
    const float* ln1_b = (const float*)d_in[2];
    const float* ln2_s = (const float*)d_in[3];
    const float* ln2_b = (const float*)d_in[4];
    const float* wq = (const float*)d_in[5];
    const float* bq = (const float*)d_in[6];
    const float* wk = (const float*)d_in[7];
    const float* bk = (const float*)d_in[8];
    const float* wv = (const float*)d_in[9];
    const float* bv = (const float*)d_in[10];
    const float* wo = (const float*)d_in[11];
    const float* bo = (const float*)d_in[12];
    const float* rdw = (const float*)d_in[13];
    const float* ruw = (const float*)d_in[14];
    const float* w1 = (const float*)d_in[15];
    const float* b1 = (const float*)d_in[16];
    const float* w2 = (const float*)d_in[17];
    const float* b2 = (const float*)d_in[18];
    const float* ws1 = (const float*)d_in[19];
    const float* bs1 = (const float*)d_in[20];
    const float* ws2 = (const float*)d_in[21];
    const float* bs2 = (const float*)d_in[22];
    const float* fn_s = (const float*)d_in[23];
    const float* fn_b = (const float*)d_in[24];

    float* ws = (float*)d_ws;
    const size_t ND = (size_t)NTOK * DMODEL;
    const size_t PADROWS = (size_t)MAXTILE * 128;   // 20480
    size_t o = 0;
    float* xb  = ws + o; o += ND;
    float* h   = ws + o; o += ND;
    unsigned short* hb     = (unsigned short*)(ws + o); o += ND / 2;
    unsigned short* qkv_bf = (unsigned short*)(ws + o); o += (size_t)NTOK * 1536 / 2;
    unsigned short* vT     = (unsigned short*)(ws + o); o += ND / 2;
    unsigned short* t1b    = (unsigned short*)(ws + o); o += ND / 2;
    unsigned short* hidb   = (unsigned short*)(ws + o); o += (size_t)NTOK * HSHARED / 2;
    unsigned short* eogb   = (unsigned short*)(ws + o); o += PADROWS * DMODEL / 2;
    float* pbuf = ws + o; o += 4 * ND;
    float* rhid = ws + o; o += (size_t)NTOK * RRANK;
    float* rsc  = ws + o; o += (size_t)NTOK * NEXP;
    float* topw = ws + o; o += (size_t)NTOK * TOPK;
    float* bqkv = ws + o; o += 1536;
    int* topi = (int*)(ws + o); o += (size_t)NTOK * TOPK;
    int* pos  = (int*)(ws + o); o += (size_t)NTOK * TOPK;
    int* perm = (int*)(ws + o); o += PADROWS;
    int* stats = (int*)(ws + o); o += 256;
    int* tinfo = (int*)(ws + o); o += 512;
    int* cnt = stats;
    int* cursor = stats + 32;
    int* poff = stats + 64;
    float* sumP = (float*)(stats + 96);
    float* zacc = sumP + 32;
    // bf16 transposed weights (per-layer, reused)
    unsigned short* wbf = (unsigned short*)(ws + o);
    const size_t DDu = (size_t)DMODEL * DMODEL;
    unsigned short* wqkvt = wbf;                            // [1536][512]
    unsigned short* wot  = wqkvt + 3 * DDu;
    unsigned short* w1t  = wot + DDu;
    unsigned short* w2t  = w1t + (size_t)NEXP * DDu;
    unsigned short* ws1t = w2t + (size_t)NEXP * DDu;
    unsigned short* ws2t = ws1t + (size_t)DMODEL * HSHARED;

    float* out_x = (float*)d_out;
    float* out_aux = out_x + ND;

    hipMemcpyAsync(xb, x_in, ND * sizeof(float), hipMemcpyDeviceToDevice, stream);

    dim3 blk(256);
    dim3 gQKV(1536 / 128, NTOK / 128);
    dim3 gOP(DMODEL / 128, NTOK / 128, 2);
    dim3 gF2(DMODEL / 128, NTOK / 128, 4);
    dim3 gHS(HSHARED / 128, NTOK / 128);
    dim3 gE1(HEXP / 128, MAXTILE);
    dim3 gE2(DMODEL / 128, MAXTILE);
    dim3 gR1(1, NTOK / 64);
    dim3 gR2(1, NTOK / 64);

    for (int l = 0; l < NLAYER; l++) {
        const size_t DD = (size_t)DMODEL * DMODEL;
        // ---- weight transpose+convert ----
        wt_kernel<<<dim3(8, 8, 1), blk, 0, stream>>>(wq + l * DD, wqkvt, DMODEL, DMODEL);
        wt_kernel<<<dim3(8, 8, 1), blk, 0, stream>>>(wk + l * DD, wqkvt + DDu, DMODEL, DMODEL);
        wt_kernel<<<dim3(8, 8, 1), blk, 0, stream>>>(wv + l * DD, wqkvt + 2 * DDu, DMODEL, DMODEL);
        wt_kernel<<<dim3(8, 8, 1), blk, 0, stream>>>(wo + l * DD, wot, DMODEL, DMODEL);
        wt_kernel<<<dim3(8, 8, NEXP), blk, 0, stream>>>(w1 + (size_t)l * NEXP * DD, w1t, DMODEL, HEXP);
        wt_kernel<<<dim3(8, 8, NEXP), blk, 0, stream>>>(w2 + (size_t)l * NEXP * DD, w2t, HEXP, DMODEL);
        wt_kernel<<<dim3(HSHARED / 64, 8, 1), blk, 0, stream>>>(ws1 + (size_t)l * DMODEL * HSHARED, ws1t, DMODEL, HSHARED);
        wt_kernel<<<dim3(8, HSHARED / 64, 1), blk, 0, stream>>>(ws2 + (size_t)l * HSHARED * DMODEL, ws2t, HSHARED, DMODEL);
        hipMemcpyAsync(bqkv, bq + l * DMODEL, DMODEL * sizeof(float), hipMemcpyDeviceToDevice, stream);
        hipMemcpyAsync(bqkv + 512, bk + l * DMODEL, DMODEL * sizeof(float), hipMemcpyDeviceToDevice, stream);
        hipMemcpyAsync(bqkv + 1024, bv + l * DMODEL, DMODEL * sizeof(float), hipMemcpyDeviceToDevice, stream);

        // ---- LN1 (bf16 out only) ----
        ln_kernel<1><<<NTOK / 4, blk, 0, stream>>>(xb, ln1_s + l * DMODEL, ln1_b + l * DMODEL, nullptr, hb);
        // ---- fused QKV (bf16 A) ----
        gemm_mfma<false, false, false, false, true, true><<<gQKV, blk, 0, stream>>>(
            hb, wqkvt, bqkv, nullptr, qkv_bf, NTOK, 1536, DMODEL, nullptr, nullptr, nullptr, nullptr);
        // ---- V transpose ----
        vtr_kernel<<<dim3(SEQ / 64, NHEAD, BATCH), blk, 0, stream>>>(qkv_bf, vT);
        // ---- MFMA attention ----
        attn_mfma<<<dim3(SEQ / QBLK, NHEAD, BATCH), blk, 0, stream>>>(qkv_bf, vT, t1b);
        // ---- out proj: split-K=2 + reduce(bias+residual) ----
        gemm_mfma<false, false, false, false, true, false, 2><<<gOP, blk, 0, stream>>>(
            t1b, wot, nullptr, nullptr, pbuf, NTOK, DMODEL, DMODEL, nullptr, nullptr, nullptr, nullptr);
        reduce_kernel<2, false><<<ND / 1024, blk, 0, stream>>>(
            pbuf, bo + l * DMODEL, nullptr, nullptr, nullptr, xb);
        // ---- LN2 (f32 for router + bf16 for GEMMs) ----
        ln_kernel<2><<<NTOK / 4, blk, 0, stream>>>(xb, ln2_s + l * DMODEL, ln2_b + l * DMODEL, h, hb);
        // ---- router ----
        hipMemsetAsync(stats, 0, 640, stream);
        gemm_tile<false><<<gR1, blk, 0, stream>>>(
            h, rdw + (size_t)l * DMODEL * RRANK, rhid, NTOK, RRANK, DMODEL, DMODEL);
        gemm_tile<false><<<gR2, blk, 0, stream>>>(
            rhid, ruw + (size_t)l * RRANK * NEXP, rsc, NTOK, NEXP, RRANK, RRANK);
        router_topk<<<NTOK / 256, blk, 0, stream>>>(rsc, topw, topi, cnt, sumP, zacc);
        scanaux_kernel<<<1, 1, 0, stream>>>(cnt, poff, tinfo, sumP, zacc, out_aux, l);
        scatter_kernel<<<NTOK * TOPK / 256, blk, 0, stream>>>(topi, poff, cursor, perm, pos);
        // ---- expert FFN (padded supergrid, bf16 A) ----
        gemm_mfma<true, false, true, true, true, true><<<gE1, blk, 0, stream>>>(
            hb, w1t, b1 + (size_t)l * NEXP * HEXP, nullptr,
            hidb, 0, HEXP, DMODEL, perm, cnt, poff, tinfo);
        gemm_mfma<false, false, false, true, true, true><<<gE2, blk, 0, stream>>>(
            hidb, w2t, b2 + (size_t)l * NEXP * DMODEL, nullptr,
            eogb, 0, DMODEL, HEXP, nullptr, cnt, poff, tinfo);
        // ---- shared FFN1 (bf16 A) ----
        gemm_mfma<true, false, false, false, true, true><<<gHS, blk, 0, stream>>>(
            hb, ws1t, bs1 + (size_t)l * HSHARED, nullptr,
            hidb, NTOK, HSHARED, DMODEL, nullptr, nullptr, nullptr, nullptr);
        // ---- shared FFN2: split-K=4 + fused reduce (bias+residual+MoE combine) ----
        gemm_mfma<false, false, false, false, true, false, 4><<<gF2, blk, 0, stream>>>(
            hidb, ws2t, nullptr, nullptr, pbuf, NTOK, DMODEL, HSHARED, nullptr, nullptr, nullptr, nullptr);
        reduce_kernel<4, true><<<ND / 1024, blk, 0, stream>>>(
            pbuf, bs2 + l * DMODEL, eogb, topw, pos, xb);
    }
    ln_kernel<0><<<NTOK / 4, blk, 0, stream>>>(xb, fn_s, fn_b, out_x, nullptr);
}

// Round 7
// 753.558 us; speedup vs baseline: 7.8787x; 1.2366x over previous
//
#include <hip/hip_runtime.h>
#include <math.h>

// ---- problem constants ----
#define NTOK    4096      // B*S
#define DMODEL  512
#define NEXP    32
#define RRANK   64
#define HEXP    512
#define HSHARED 4096
#define SEQ     1024
#define BATCH   4
#define NHEAD   8
#define TOPK    4
#define NLAYER  2
#define QBLK    64
#define KBLK    64
#define MAXTILE 160       // max padded expert m-tiles: 16384/128 + 32

typedef __attribute__((ext_vector_type(8))) short bf16x8;
typedef __attribute__((ext_vector_type(4))) float f32x4;

__device__ __forceinline__ float gelu_f(float x) {
    float t = tanhf(0.7978845608028654f * (x + 0.044715f * x * x * x));
    return 0.5f * x * (1.f + t);
}
__device__ __forceinline__ unsigned short f2bf(float f) {
    unsigned int u = __float_as_uint(f);
    u += 0x7FFFu + ((u >> 16) & 1u);
    return (unsigned short)(u >> 16);
}
__device__ __forceinline__ float bf2f(unsigned short u) {
    return __uint_as_float((unsigned int)u << 16);
}

// ---------------- LayerNorm: one wave per row of 512; MODE 0=f32, 1=bf16, 2=both ----------------
template <int MODE>
__global__ __launch_bounds__(256) void ln_kernel(const float* __restrict__ x,
                                                 const float* __restrict__ s,
                                                 const float* __restrict__ b,
                                                 float* __restrict__ outf,
                                                 unsigned short* __restrict__ outb) {
    int wave = threadIdx.x >> 6, lane = threadIdx.x & 63;
    int row = blockIdx.x * 4 + wave;
    const float* xr = x + (size_t)row * DMODEL;
    float v[8];
    float sum = 0.f;
#pragma unroll
    for (int i = 0; i < 8; i++) { v[i] = xr[lane + i * 64]; sum += v[i]; }
#pragma unroll
    for (int o = 32; o; o >>= 1) sum += __shfl_xor(sum, o);
    float m = sum * (1.f / DMODEL);
    float vs = 0.f;
#pragma unroll
    for (int i = 0; i < 8; i++) { float d = v[i] - m; vs += d * d; }
#pragma unroll
    for (int o = 32; o; o >>= 1) vs += __shfl_xor(vs, o);
    float rstd = rsqrtf(vs * (1.f / DMODEL) + 1e-5f);
#pragma unroll
    for (int i = 0; i < 8; i++) {
        int c = lane + i * 64;
        float r = (v[i] - m) * rstd * s[c] + b[c];
        if (MODE != 1) outf[(size_t)row * DMODEL + c] = r;
        if (MODE != 0) outb[(size_t)row * DMODEL + c] = f2bf(r);
    }
}

// ---------------- weight transpose + fp32->bf16: src [K][N] -> dst [N][K] bf16 ----------------
__global__ __launch_bounds__(256) void wt_kernel(const float* __restrict__ src,
                                                 unsigned short* __restrict__ dst,
                                                 int K, int N) {
    src += (size_t)blockIdx.z * K * N;
    dst += (size_t)blockIdx.z * K * N;
    __shared__ float t[64][68];
    int k0 = blockIdx.y * 64, n0 = blockIdx.x * 64;
    int tid = threadIdx.x;
    int r = tid >> 2;
    int cb = (tid & 3) * 4;
#pragma unroll
    for (int i = 0; i < 4; i++)
        *(float4*)&t[r][cb + i * 16] = *(const float4*)(src + (size_t)(k0 + r) * N + n0 + cb + i * 16);
    __syncthreads();
    int g = tid & 7;
    int nr = tid >> 3;
#pragma unroll
    for (int i = 0; i < 2; i++) {
        int n = nr + i * 32;
        bf16x8 v;
#pragma unroll
        for (int j = 0; j < 8; j++) v[j] = (short)f2bf(t[g * 8 + j][n]);
        *(bf16x8*)(dst + (size_t)(n0 + n) * K + k0 + g * 8) = v;
    }
}

// ---------------- V transpose: qkv[.,1024+h*64+d] -> Vt[b,h,d,s] (bf16) ----------------
__global__ __launch_bounds__(256) void vtr_kernel(const unsigned short* __restrict__ QKV,
                                                  unsigned short* __restrict__ Vt) {
    int st = blockIdx.x, hh = blockIdx.y, bb = blockIdx.z;
    __shared__ unsigned short t[64][72];
    int r = threadIdx.x >> 3, g = threadIdx.x & 7;
#pragma unroll
    for (int i = 0; i < 2; i++) {
        int row = r + i * 32;
        bf16x8 v = *(const bf16x8*)(QKV + (size_t)(bb * SEQ + st * 64 + row) * 1536 + 1024 + hh * 64 + g * 8);
        *(bf16x8*)&t[row][g * 8] = v;
    }
    __syncthreads();
#pragma unroll
    for (int i = 0; i < 2; i++) {
        int d = r + i * 32;
        bf16x8 v;
#pragma unroll
        for (int j = 0; j < 8; j++) v[j] = (short)t[g * 8 + j][d];
        *(bf16x8*)(Vt + (size_t)((bb * NHEAD + hh) * 64 + d) * SEQ + st * 64 + g * 8) = v;
    }
}

// ---------------- bf16 MFMA GEMM (128x128 tile, BK=64, XOR-swizzled LDS) ----------------
template <bool GELU, bool DORES, bool GATHER, bool EXPERT, bool ABF16, bool OUTBF16, int SK = 1>
__global__ __launch_bounds__(256, 2) void gemm_mfma(
    const void* __restrict__ Avoid, const unsigned short* __restrict__ Wt,
    const float* __restrict__ bias, const float* __restrict__ res,
    void* __restrict__ Cvoid, int M, int Nn, int Kk,
    const int* __restrict__ rowmap, const int* __restrict__ cntp,
    const int* __restrict__ offp, const int* __restrict__ tinfo) {
    int n0 = blockIdx.x * 128;
    int m0;
    const float* Af = (const float*)Avoid;
    const unsigned short* Ab = (const unsigned short*)Avoid;
    size_t cbase = 0;
    int kbeg = 0, kend = Kk;
    if (EXPERT) {
        int t = blockIdx.y;
        if (t >= tinfo[0]) return;
        int e = tinfo[1 + 2 * t];
        m0 = tinfo[2 + 2 * t];
        M = cntp[e];
        Wt += (size_t)e * Nn * Kk;
        bias += (size_t)e * Nn;
        int oe = offp[e];
        cbase = (size_t)oe * Nn;
        if (GATHER) rowmap += oe;
        else Ab += (size_t)oe * Kk;
    } else {
        m0 = blockIdx.y * 128;
    }
    if (SK > 1) {
        int s = blockIdx.z;
        int chunk = Kk / SK;
        kbeg = s * chunk;
        kend = kbeg + chunk;
        cbase = (size_t)s * M * Nn;
    }
    __shared__ short As[128 * 64];
    __shared__ short Bs[128 * 64];
    char* asb = (char*)As;
    char* bsb = (char*)Bs;
    int tid = threadIdx.x;
    int wave = tid >> 6, lane = tid & 63;
    int wm = wave >> 1, wn = wave & 1;
    int l15 = lane & 15, l16 = lane >> 4;
    int srow = tid >> 3;
    int sk8 = tid & 7;

    f32x4 acc[4][4];
#pragma unroll
    for (int m = 0; m < 4; m++)
#pragma unroll
        for (int n = 0; n < 4; n++)
#pragma unroll
            for (int j = 0; j < 4; j++) acc[m][n][j] = 0.f;

    for (int k0 = kbeg; k0 < kend; k0 += 64) {
#pragma unroll
        for (int i = 0; i < 4; i++) {
            int row = srow + i * 32;
            int grow = m0 + row;
            bool valid = grow < M;
            int arow = grow;
            if (GATHER) arow = valid ? rowmap[grow] : 0;
            bf16x8 v;
            if (ABF16) {
#pragma unroll
                for (int j = 0; j < 8; j++) v[j] = 0;
                if (valid) v = *(const bf16x8*)(Ab + (size_t)arow * Kk + k0 + sk8 * 8);
            } else {
                float4 f0 = make_float4(0.f, 0.f, 0.f, 0.f), f1 = f0;
                if (valid) {
                    const float* p = Af + (size_t)arow * Kk + k0 + sk8 * 8;
                    f0 = *(const float4*)p;
                    f1 = *(const float4*)(p + 4);
                }
                v[0] = (short)f2bf(f0.x); v[1] = (short)f2bf(f0.y);
                v[2] = (short)f2bf(f0.z); v[3] = (short)f2bf(f0.w);
                v[4] = (short)f2bf(f1.x); v[5] = (short)f2bf(f1.y);
                v[6] = (short)f2bf(f1.z); v[7] = (short)f2bf(f1.w);
            }
            *(bf16x8*)(asb + row * 128 + ((sk8 * 16) ^ ((row & 7) << 4))) = v;
        }
#pragma unroll
        for (int i = 0; i < 4; i++) {
            int nrow = srow + i * 32;
            bf16x8 v = *(const bf16x8*)(Wt + (size_t)(n0 + nrow) * Kk + k0 + sk8 * 8);
            *(bf16x8*)(bsb + nrow * 128 + ((sk8 * 16) ^ ((nrow & 7) << 4))) = v;
        }
        __syncthreads();
#pragma unroll
        for (int kk = 0; kk < 2; kk++) {
            int k8 = kk * 4 + l16;
            bf16x8 a[4], b[4];
#pragma unroll
            for (int m = 0; m < 4; m++) {
                int row = wm * 64 + m * 16 + l15;
                a[m] = *(const bf16x8*)(asb + row * 128 + ((k8 * 16) ^ ((row & 7) << 4)));
            }
#pragma unroll
            for (int n = 0; n < 4; n++) {
                int row = wn * 64 + n * 16 + l15;
                b[n] = *(const bf16x8*)(bsb + row * 128 + ((k8 * 16) ^ ((row & 7) << 4)));
            }
#pragma unroll
            for (int m = 0; m < 4; m++)
#pragma unroll
                for (int n = 0; n < 4; n++)
                    acc[m][n] = __builtin_amdgcn_mfma_f32_16x16x32_bf16(a[m], b[n], acc[m][n], 0, 0, 0);
        }
        __syncthreads();
    }

#pragma unroll
    for (int m = 0; m < 4; m++) {
#pragma unroll
        for (int n = 0; n < 4; n++) {
            int col = n0 + wn * 64 + n * 16 + l15;
            float bv = (SK == 1 && bias) ? bias[col] : 0.f;
#pragma unroll
            for (int j = 0; j < 4; j++) {
                int row = m0 + wm * 64 + m * 16 + l16 * 4 + j;
                if (row >= M) continue;
                float val = acc[m][n][j] + bv;
                if (SK == 1 && GELU) val = gelu_f(val);
                if (SK == 1 && DORES) val += res[(size_t)row * Nn + col];
                if (SK == 1 && OUTBF16)
                    ((unsigned short*)Cvoid)[cbase + (size_t)row * Nn + col] = f2bf(val);
                else
                    ((float*)Cvoid)[cbase + (size_t)row * Nn + col] = val;
            }
        }
    }
}

// ---------------- split-K reduce (+bias +residual, optional MoE combine) ----------------
template <int SK, bool MOE>
__global__ __launch_bounds__(256) void reduce_kernel(
    const float* __restrict__ pbuf, const float* __restrict__ bias,
    const unsigned short* __restrict__ eogb, const float* __restrict__ topw,
    const int* __restrict__ pos, float* __restrict__ xb) {
    int idx = (blockIdx.x * 256 + threadIdx.x) * 4;
    int n = idx >> 9, col = idx & 511;
    float4 v = *(float4*)(xb + idx);
    float4 bv = *(const float4*)(bias + col);
    v.x += bv.x; v.y += bv.y; v.z += bv.z; v.w += bv.w;
#pragma unroll
    for (int s = 0; s < SK; s++) {
        float4 p = *(const float4*)(pbuf + (size_t)s * NTOK * DMODEL + idx);
        v.x += p.x; v.y += p.y; v.z += p.z; v.w += p.w;
    }
    if (MOE) {
#pragma unroll
        for (int k = 0; k < TOPK; k++) {
            float w = topw[n * TOPK + k];
            const unsigned short* e = eogb + (size_t)pos[n * TOPK + k] * DMODEL + col;
            ushort4 u = *(const ushort4*)e;
            v.x += w * bf2f(u.x); v.y += w * bf2f(u.y);
            v.z += w * bf2f(u.z); v.w += w * bf2f(u.w);
        }
    }
    *(float4*)(xb + idx) = v;
}

// ---------------- small fp32 GEMM (router only) ----------------
template <bool GELU>
__global__ __launch_bounds__(256) void gemm_tile(
    const float* __restrict__ A, const float* __restrict__ W,
    float* __restrict__ C, int M, int Nn, int Kk, int lda) {
    int n0 = blockIdx.x * 64;
    int m0 = blockIdx.y * 64;
    __shared__ float Asf[16][68];
    __shared__ float Wsf[16][68];
    int tid = threadIdx.x;
    int ml = tid >> 2, kl = (tid & 3) << 2;
    bool avalid = (m0 + ml) < M;
    int arow = m0 + ml;
    const float* aptr = A + (size_t)arow * lda + kl;
    int kr = tid >> 4, nc = (tid & 15) << 2;
    bool wvalid = (n0 + nc) < Nn;
    const float* wptr = W + (size_t)kr * Nn + n0 + nc;
    int tm = (tid >> 4) << 2, tn = (tid & 15) << 2;
    float acc[4][4] = {{0.f}};
    for (int k0 = 0; k0 < Kk; k0 += 16) {
        float4 av = make_float4(0.f, 0.f, 0.f, 0.f);
        float4 wv = make_float4(0.f, 0.f, 0.f, 0.f);
        if (avalid) av = *(const float4*)(aptr + k0);
        if (wvalid) wv = *(const float4*)(wptr + (size_t)k0 * Nn);
        Asf[kl + 0][ml] = av.x; Asf[kl + 1][ml] = av.y;
        Asf[kl + 2][ml] = av.z; Asf[kl + 3][ml] = av.w;
        *(float4*)&Wsf[kr][nc] = wv;
        __syncthreads();
#pragma unroll
        for (int kk = 0; kk < 16; kk++) {
            float4 a4 = *(const float4*)&Asf[kk][tm];
            float4 w4 = *(const float4*)&Wsf[kk][tn];
            acc[0][0] += a4.x * w4.x; acc[0][1] += a4.x * w4.y; acc[0][2] += a4.x * w4.z; acc[0][3] += a4.x * w4.w;
            acc[1][0] += a4.y * w4.x; acc[1][1] += a4.y * w4.y; acc[1][2] += a4.y * w4.z; acc[1][3] += a4.y * w4.w;
            acc[2][0] += a4.z * w4.x; acc[2][1] += a4.z * w4.y; acc[2][2] += a4.z * w4.z; acc[2][3] += a4.z * w4.w;
            acc[3][0] += a4.w * w4.x; acc[3][1] += a4.w * w4.y; acc[3][2] += a4.w * w4.z; acc[3][3] += a4.w * w4.w;
        }
        __syncthreads();
    }
#pragma unroll
    for (int i = 0; i < 4; i++) {
        int mm = m0 + tm + i;
        if (mm >= M) break;
        float* crow = C + (size_t)mm * Nn;
#pragma unroll
        for (int j = 0; j < 4; j++) {
            int nn = n0 + tn + j;
            if (nn >= Nn) continue;
            float val = acc[i][j];
            if (GELU) val = gelu_f(val);
            crow[nn] = val;
        }
    }
}

// ---------------- MFMA flash attention: block = (64 q-rows, head, batch), 4 waves ----------------
__global__ __launch_bounds__(256, 2) void attn_mfma(const unsigned short* __restrict__ QKV,
                                                    const unsigned short* __restrict__ Vt,
                                                    unsigned short* __restrict__ O) {
    int qt = blockIdx.x, hh = blockIdx.y, bb = blockIdx.z;
    __shared__ char lds[32768];
    char* Qs = lds;
    char* Ks = lds + 8192;
    char* Vs = lds + 16384;
    char* Ps = lds + 24576;
    int tid = threadIdx.x;
    int w = tid >> 6, l = tid & 63;
    int l15 = l & 15, l16 = l >> 4;

    {
        int r = tid >> 3, g = tid & 7;
        const unsigned short* qbase = QKV + (size_t)(bb * SEQ + qt * QBLK) * 1536 + hh * 64;
#pragma unroll
        for (int i = 0; i < 2; i++) {
            int row = r + i * 32;
            bf16x8 v = *(const bf16x8*)(qbase + (size_t)row * 1536 + g * 8);
            *(bf16x8*)(Qs + row * 128 + ((g * 16) ^ ((row & 7) << 4))) = v;
        }
    }
    f32x4 accO[4];
#pragma unroll
    for (int n = 0; n < 4; n++)
#pragma unroll
        for (int j = 0; j < 4; j++) accO[n][j] = 0.f;
    float m_r[4] = {-1e30f, -1e30f, -1e30f, -1e30f};
    float l_r[4] = {0.f, 0.f, 0.f, 0.f};

    const unsigned short* kbase = QKV + (size_t)(bb * SEQ) * 1536 + 512 + hh * 64;
    const unsigned short* vbase = Vt + (size_t)((bb * NHEAD + hh) * 64) * SEQ;

    for (int kt = 0; kt < SEQ / KBLK; kt++) {
        __syncthreads();
        {
            int r = tid >> 3, g = tid & 7;
#pragma unroll
            for (int i = 0; i < 2; i++) {
                int row = r + i * 32;
                bf16x8 kv = *(const bf16x8*)(kbase + (size_t)(kt * KBLK + row) * 1536 + g * 8);
                *(bf16x8*)(Ks + row * 128 + ((g * 16) ^ ((row & 7) << 4))) = kv;
                bf16x8 vv = *(const bf16x8*)(vbase + (size_t)row * SEQ + kt * KBLK + g * 8);
                *(bf16x8*)(Vs + row * 128 + ((g * 16) ^ ((row & 7) << 4))) = vv;
            }
        }
        __syncthreads();
        f32x4 s_acc[4];
#pragma unroll
        for (int n = 0; n < 4; n++)
#pragma unroll
            for (int j = 0; j < 4; j++) s_acc[n][j] = 0.f;
#pragma unroll
        for (int st = 0; st < 2; st++) {
            int kb = st * 64 + l16 * 16;
            int qrow = w * 16 + l15;
            bf16x8 a = *(const bf16x8*)(Qs + qrow * 128 + (kb ^ ((qrow & 7) << 4)));
#pragma unroll
            for (int n = 0; n < 4; n++) {
                int kr = n * 16 + l15;
                bf16x8 b = *(const bf16x8*)(Ks + kr * 128 + (kb ^ ((kr & 7) << 4)));
                s_acc[n] = __builtin_amdgcn_mfma_f32_16x16x32_bf16(a, b, s_acc[n], 0, 0, 0);
            }
        }
        char* pw = Ps + w * 2048;
#pragma unroll
        for (int j = 0; j < 4; j++) {
            float s0 = s_acc[0][j] * 0.125f, s1 = s_acc[1][j] * 0.125f;
            float s2 = s_acc[2][j] * 0.125f, s3 = s_acc[3][j] * 0.125f;
            float tmax = fmaxf(fmaxf(s0, s1), fmaxf(s2, s3));
#pragma unroll
            for (int o = 1; o < 16; o <<= 1) tmax = fmaxf(tmax, __shfl_xor(tmax, o));
            float mnew = fmaxf(m_r[j], tmax);
            float resc = __expf(m_r[j] - mnew);
            float p0 = __expf(s0 - mnew), p1 = __expf(s1 - mnew);
            float p2 = __expf(s2 - mnew), p3 = __expf(s3 - mnew);
            float ps = p0 + p1 + p2 + p3;
#pragma unroll
            for (int o = 1; o < 16; o <<= 1) ps += __shfl_xor(ps, o);
            l_r[j] = l_r[j] * resc + ps;
            m_r[j] = mnew;
            accO[0][j] *= resc; accO[1][j] *= resc;
            accO[2][j] *= resc; accO[3][j] *= resc;
            int prow = l16 * 4 + j;
            int sw = (prow & 7) << 4;
            *(unsigned short*)(pw + prow * 128 + ((2 * l15) ^ sw)) = f2bf(p0);
            *(unsigned short*)(pw + prow * 128 + ((2 * l15 + 32) ^ sw)) = f2bf(p1);
            *(unsigned short*)(pw + prow * 128 + ((2 * l15 + 64) ^ sw)) = f2bf(p2);
            *(unsigned short*)(pw + prow * 128 + ((2 * l15 + 96) ^ sw)) = f2bf(p3);
        }
#pragma unroll
        for (int st = 0; st < 2; st++) {
            int kb = st * 64 + l16 * 16;
            bf16x8 pa = *(const bf16x8*)(pw + l15 * 128 + (kb ^ ((l15 & 7) << 4)));
#pragma unroll
            for (int n = 0; n < 4; n++) {
                int vr = n * 16 + l15;
                bf16x8 vb = *(const bf16x8*)(Vs + vr * 128 + (kb ^ ((vr & 7) << 4)));
                accO[n] = __builtin_amdgcn_mfma_f32_16x16x32_bf16(pa, vb, accO[n], 0, 0, 0);
            }
        }
    }
    unsigned short* obase = O + (size_t)(bb * SEQ + qt * QBLK + w * 16) * DMODEL + hh * 64;
#pragma unroll
    for (int j = 0; j < 4; j++) {
        float inv = 1.f / l_r[j];
        int row = l16 * 4 + j;
#pragma unroll
        for (int n = 0; n < 4; n++)
            obase[(size_t)row * DMODEL + n * 16 + l15] = f2bf(accO[n][j] * inv);
    }
}

// ---------------- router: shuffle-reduced stats, no same-address atomics on hot path ----------------
__global__ __launch_bounds__(256) void router_topk(const float* __restrict__ rsc,
                                                   float* __restrict__ topw,
                                                   int* __restrict__ topi,
                                                   int* __restrict__ cnt,
                                                   float* __restrict__ sumP,
                                                   float* __restrict__ zacc) {
    __shared__ float wP[4][NEXP];
    __shared__ int wC[4][NEXP];
    __shared__ float wZ[4];
    int tid = threadIdx.x;
    int wv = tid >> 6, lane = tid & 63;
    int n = blockIdx.x * 256 + tid;
    float sc[NEXP];
    float mx = -1e30f;
#pragma unroll
    for (int e = 0; e < NEXP; e++) { sc[e] = rsc[n * NEXP + e]; mx = fmaxf(mx, sc[e]); }
    float se = 0.f;
#pragma unroll
    for (int e = 0; e < NEXP; e++) { sc[e] = expf(sc[e] - mx); se += sc[e]; }
    float invse = 1.f / se;
    float lse = mx + logf(se);
    // z: wave butterfly
    float z = lse * lse;
#pragma unroll
    for (int o = 32; o; o >>= 1) z += __shfl_xor(z, o);
    if (lane == 0) wZ[wv] = z;
    // P sums: per-expert wave butterfly (no atomics)
#pragma unroll
    for (int e = 0; e < NEXP; e++) {
        float pv = sc[e] * invse;
#pragma unroll
        for (int o = 32; o; o >>= 1) pv += __shfl_xor(pv, o);
        if (lane == 0) wP[wv][e] = pv;
    }
    // top-4 selection (destroys sc)
    float tv[TOPK]; int ti[TOPK];
#pragma unroll
    for (int k = 0; k < TOPK; k++) {
        float best = -1.f; int bi = 0;
#pragma unroll
        for (int e = 0; e < NEXP; e++) {
            if (sc[e] > best) { best = sc[e]; bi = e; }
        }
        tv[k] = best * invse; ti[k] = bi; sc[bi] = -1.f;
    }
    float s4 = tv[0] + tv[1] + tv[2] + tv[3];
#pragma unroll
    for (int k = 0; k < TOPK; k++) {
        topw[n * TOPK + k] = tv[k] / s4;
        topi[n * TOPK + k] = ti[k];
    }
    // counts: ballot + popcount per expert
#pragma unroll
    for (int e = 0; e < NEXP; e++) {
        unsigned long long b0 = __ballot(ti[0] == e);
        unsigned long long b1 = __ballot(ti[1] == e);
        unsigned long long b2 = __ballot(ti[2] == e);
        unsigned long long b3 = __ballot(ti[3] == e);
        if (lane == 0)
            wC[wv][e] = __popcll(b0) + __popcll(b1) + __popcll(b2) + __popcll(b3);
    }
    __syncthreads();
    if (tid < NEXP) {
        atomicAdd(&sumP[tid], wP[0][tid] + wP[1][tid] + wP[2][tid] + wP[3][tid]);
        atomicAdd(&cnt[tid], wC[0][tid] + wC[1][tid] + wC[2][tid] + wC[3][tid]);
    }
    if (tid == 0) atomicAdd(zacc, wZ[0] + wZ[1] + wZ[2] + wZ[3]);
}

// ---------------- scan (1 wave, shuffle prefix): padded offsets + tile map + aux ----------------
__global__ void scanaux_kernel(const int* __restrict__ cnt, int* __restrict__ poff,
                               int* __restrict__ tinfo,
                               const float* __restrict__ sumP, const float* __restrict__ zacc,
                               float* __restrict__ out_aux, int l) {
    int lane = threadIdx.x;          // 64 threads, lanes 0..31 active for experts
    int c = (lane < NEXP) ? cnt[lane] : 0;
    int nt = (c + 127) >> 7;
    int x = nt;
#pragma unroll
    for (int o = 1; o < 32; o <<= 1) {
        int y = __shfl_up(x, o);
        if (lane >= o) x += y;
    }
    int excl = x - nt;
    if (lane < NEXP) {
        poff[lane] = excl * 128;
        for (int i = 0; i < nt; i++) {
            tinfo[1 + 2 * (excl + i)] = lane;
            tinfo[2 + 2 * (excl + i)] = i * 128;
        }
    }
    float lb = (lane < NEXP) ? ((float)c / (float)NTOK) * (sumP[lane] / (float)NTOK) : 0.f;
#pragma unroll
    for (int o = 32; o; o >>= 1) lb += __shfl_xor(lb, o);
    if (lane == 31) {
        tinfo[0] = x;   // inclusive total at lane 31
        out_aux[l] = lb * (float)NEXP / (float)TOPK;
        out_aux[NLAYER + l] = zacc[0] / (float)NTOK;
    }
}

// ---------------- scatter: LDS-aggregated per-block bases ----------------
__global__ __launch_bounds__(256) void scatter_kernel(const int* __restrict__ topi,
                                                      const int* __restrict__ poff,
                                                      int* __restrict__ cursor,
                                                      int* __restrict__ perm,
                                                      int* __restrict__ pos) {
    __shared__ int lcnt[NEXP];
    __shared__ int lbase[NEXP];
    if (threadIdx.x < NEXP) lcnt[threadIdx.x] = 0;
    __syncthreads();
    int i = blockIdx.x * 256 + threadIdx.x;
    int e = topi[i];
    int lr = atomicAdd(&lcnt[e], 1);
    __syncthreads();
    if (threadIdx.x < NEXP && lcnt[threadIdx.x] > 0)
        lbase[threadIdx.x] = atomicAdd(&cursor[threadIdx.x], lcnt[threadIdx.x]);
    __syncthreads();
    int g = poff[e] + lbase[e] + lr;
    perm[g] = i >> 2;
    pos[i] = g;
}

// ---------------- launcher ----------------
extern "C" void kernel_launch(void* const* d_in, const int* in_sizes, int n_in,
                              void* d_out, int out_size, void* d_ws, size_t ws_size,
                              hipStream_t stream) {
    (void)in_sizes; (void)n_in; (void)out_size; (void)ws_size;
    const float* x_in  = (const float*)d_in[0];
    const float* ln1_s = (const float*)d_in[1];
    const float* ln1_b = (const float*)d_in[2];
    const float* ln2_s = (const float*)d_in[3];
    const float* ln2_b = (const float*)d_in[4];
    const float* wq = (const float*)d_in[5];
    const float* bq = (const float*)d_in[6];
    const float* wk = (const float*)d_in[7];
    const float* bk = (const float*)d_in[8];
    const float* wv = (const float*)d_in[9];
    const float* bv = (const float*)d_in[10];
    const float* wo = (const float*)d_in[11];
    const float* bo = (const float*)d_in[12];
    const float* rdw = (const float*)d_in[13];
    const float* ruw = (const float*)d_in[14];
    const float* w1 = (const float*)d_in[15];
    const float* b1 = (const float*)d_in[16];
    const float* w2 = (const float*)d_in[17];
    const float* b2 = (const float*)d_in[18];
    const float* ws1 = (const float*)d_in[19];
    const float* bs1 = (const float*)d_in[20];
    const float* ws2 = (const float*)d_in[21];
    const float* bs2 = (const float*)d_in[22];
    const float* fn_s = (const float*)d_in[23];
    const float* fn_b = (const float*)d_in[24];

    float* ws = (float*)d_ws;
    const size_t ND = (size_t)NTOK * DMODEL;
    const size_t PADROWS = (size_t)MAXTILE * 128;
    size_t o = 0;
    float* xb  = ws + o; o += ND;
    float* h   = ws + o; o += ND;
    unsigned short* hb     = (unsigned short*)(ws + o); o += ND / 2;
    unsigned short* qkv_bf = (unsigned short*)(ws + o); o += (size_t)NTOK * 1536 / 2;
    unsigned short* vT     = (unsigned short*)(ws + o); o += ND / 2;
    unsigned short* t1b    = (unsigned short*)(ws + o); o += ND / 2;
    unsigned short* hidb   = (unsigned short*)(ws + o); o += (size_t)NTOK * HSHARED / 2;
    unsigned short* eogb   = (unsigned short*)(ws + o); o += PADROWS * DMODEL / 2;
    float* pbuf = ws + o; o += 4 * ND;
    float* rdru = ws + o; o += (size_t)DMODEL * NEXP;
    float* rsc  = ws + o; o += (size_t)NTOK * NEXP;
    float* topw = ws + o; o += (size_t)NTOK * TOPK;
    float* bqkv = ws + o; o += 1536;
    int* topi = (int*)(ws + o); o += (size_t)NTOK * TOPK;
    int* pos  = (int*)(ws + o); o += (size_t)NTOK * TOPK;
    int* perm = (int*)(ws + o); o += PADROWS;
    int* stats = (int*)(ws + o); o += 256;
    int* tinfo = (int*)(ws + o); o += 512;
    int* cnt = stats;
    int* cursor = stats + 32;
    int* poff = stats + 64;
    float* sumP = (float*)(stats + 96);
    float* zacc = sumP + 32;
    unsigned short* wbf = (unsigned short*)(ws + o);
    const size_t DDu = (size_t)DMODEL * DMODEL;
    unsigned short* wqkvt = wbf;
    unsigned short* wot  = wqkvt + 3 * DDu;
    unsigned short* w1t  = wot + DDu;
    unsigned short* w2t  = w1t + (size_t)NEXP * DDu;
    unsigned short* ws1t = w2t + (size_t)NEXP * DDu;
    unsigned short* ws2t = ws1t + (size_t)DMODEL * HSHARED;

    float* out_x = (float*)d_out;
    float* out_aux = out_x + ND;

    hipMemcpyAsync(xb, x_in, ND * sizeof(float), hipMemcpyDeviceToDevice, stream);

    dim3 blk(256);
    dim3 gQKV(1536 / 128, NTOK / 128);
    dim3 gOP(DMODEL / 128, NTOK / 128, 2);
    dim3 gF2(DMODEL / 128, NTOK / 128, 4);
    dim3 gHS(HSHARED / 128, NTOK / 128);
    dim3 gE1(HEXP / 128, MAXTILE);
    dim3 gE2(DMODEL / 128, MAXTILE);

    for (int l = 0; l < NLAYER; l++) {
        const size_t DD = (size_t)DMODEL * DMODEL;
        // ---- weight transpose+convert ----
        wt_kernel<<<dim3(8, 8, 1), blk, 0, stream>>>(wq + l * DD, wqkvt, DMODEL, DMODEL);
        wt_kernel<<<dim3(8, 8, 1), blk, 0, stream>>>(wk + l * DD, wqkvt + DDu, DMODEL, DMODEL);
        wt_kernel<<<dim3(8, 8, 1), blk, 0, stream>>>(wv + l * DD, wqkvt + 2 * DDu, DMODEL, DMODEL);
        wt_kernel<<<dim3(8, 8, 1), blk, 0, stream>>>(wo + l * DD, wot, DMODEL, DMODEL);
        wt_kernel<<<dim3(8, 8, NEXP), blk, 0, stream>>>(w1 + (size_t)l * NEXP * DD, w1t, DMODEL, HEXP);
        wt_kernel<<<dim3(8, 8, NEXP), blk, 0, stream>>>(w2 + (size_t)l * NEXP * DD, w2t, HEXP, DMODEL);
        wt_kernel<<<dim3(HSHARED / 64, 8, 1), blk, 0, stream>>>(ws1 + (size_t)l * DMODEL * HSHARED, ws1t, DMODEL, HSHARED);
        wt_kernel<<<dim3(8, HSHARED / 64, 1), blk, 0, stream>>>(ws2 + (size_t)l * HSHARED * DMODEL, ws2t, HSHARED, DMODEL);
        hipMemcpyAsync(bqkv, bq + l * DMODEL, DMODEL * sizeof(float), hipMemcpyDeviceToDevice, stream);
        hipMemcpyAsync(bqkv + 512, bk + l * DMODEL, DMODEL * sizeof(float), hipMemcpyDeviceToDevice, stream);
        hipMemcpyAsync(bqkv + 1024, bv + l * DMODEL, DMODEL * sizeof(float), hipMemcpyDeviceToDevice, stream);
        // ---- router weight fold: rdru = rd @ ru  [512][32] fp32 ----
        gemm_tile<false><<<dim3(1, 8), blk, 0, stream>>>(
            rdw + (size_t)l * DMODEL * RRANK, ruw + (size_t)l * RRANK * NEXP, rdru, DMODEL, NEXP, RRANK, RRANK);

        // ---- LN1 (bf16 out only) ----
        ln_kernel<1><<<NTOK / 4, blk, 0, stream>>>(xb, ln1_s + l * DMODEL, ln1_b + l * DMODEL, nullptr, hb);
        // ---- fused QKV ----
        gemm_mfma<false, false, false, false, true, true><<<gQKV, blk, 0, stream>>>(
            hb, wqkvt, bqkv, nullptr, qkv_bf, NTOK, 1536, DMODEL, nullptr, nullptr, nullptr, nullptr);
        // ---- V transpose ----
        vtr_kernel<<<dim3(SEQ / 64, NHEAD, BATCH), blk, 0, stream>>>(qkv_bf, vT);
        // ---- MFMA attention ----
        attn_mfma<<<dim3(SEQ / QBLK, NHEAD, BATCH), blk, 0, stream>>>(qkv_bf, vT, t1b);
        // ---- out proj: split-K=2 + reduce(bias+residual) ----
        gemm_mfma<false, false, false, false, true, false, 2><<<gOP, blk, 0, stream>>>(
            t1b, wot, nullptr, nullptr, pbuf, NTOK, DMODEL, DMODEL, nullptr, nullptr, nullptr, nullptr);
        reduce_kernel<2, false><<<ND / 1024, blk, 0, stream>>>(
            pbuf, bo + l * DMODEL, nullptr, nullptr, nullptr, xb);
        // ---- LN2 ----
        ln_kernel<2><<<NTOK / 4, blk, 0, stream>>>(xb, ln2_s + l * DMODEL, ln2_b + l * DMODEL, h, hb);
        // ---- router: scores = h @ rdru ----
        hipMemsetAsync(stats, 0, 640, stream);
        gemm_tile<false><<<dim3(1, NTOK / 64), blk, 0, stream>>>(
            h, rdru, rsc, NTOK, NEXP, DMODEL, DMODEL);
        router_topk<<<NTOK / 256, blk, 0, stream>>>(rsc, topw, topi, cnt, sumP, zacc);
        scanaux_kernel<<<1, 64, 0, stream>>>(cnt, poff, tinfo, sumP, zacc, out_aux, l);
        scatter_kernel<<<NTOK * TOPK / 256, blk, 0, stream>>>(topi, poff, cursor, perm, pos);
        // ---- expert FFN ----
        gemm_mfma<true, false, true, true, true, true><<<gE1, blk, 0, stream>>>(
            hb, w1t, b1 + (size_t)l * NEXP * HEXP, nullptr,
            hidb, 0, HEXP, DMODEL, perm, cnt, poff, tinfo);
        gemm_mfma<false, false, false, true, true, true><<<gE2, blk, 0, stream>>>(
            hidb, w2t, b2 + (size_t)l * NEXP * DMODEL, nullptr,
            eogb, 0, DMODEL, HEXP, nullptr, cnt, poff, tinfo);
        // ---- shared FFN1 ----
        gemm_mfma<true, false, false, false, true, true><<<gHS, blk, 0, stream>>>(
            hb, ws1t, bs1 + (size_t)l * HSHARED, nullptr,
            hidb, NTOK, HSHARED, DMODEL, nullptr, nullptr, nullptr, nullptr);
        // ---- shared FFN2: split-K=4 + fused reduce ----
        gemm_mfma<false, false, false, false, true, false, 4><<<gF2, blk, 0, stream>>>(
            hidb, ws2t, nullptr, nullptr, pbuf, NTOK, DMODEL, HSHARED, nullptr, nullptr, nullptr, nullptr);
        reduce_kernel<4, true><<<ND / 1024, blk, 0, stream>>>(
            pbuf, bs2 + l * DMODEL, eogb, topw, pos, xb);
    }
    ln_kernel<0><<<NTOK / 4, blk, 0, stream>>>(xb, fn_s, fn_b, out_x, nullptr);
}

// Round 8
// 680.878 us; speedup vs baseline: 8.7197x; 1.1067x over previous
//
#include <hip/hip_runtime.h>
#include <math.h>

// ---- problem constants ----
#define NTOK    4096      // B*S
#define DMODEL  512
#define NEXP    32
#define RRANK   64
#define HEXP    512
#define HSHARED 4096
#define SEQ     1024
#define BATCH   4
#define NHEAD   8
#define TOPK    4
#define NLAYER  2
#define QBLK    64
#define KBLK    64
#define MAXTILE 160       // max padded expert m-tiles: 16384/128 + 32

typedef __attribute__((ext_vector_type(8))) short bf16x8;
typedef __attribute__((ext_vector_type(4))) float f32x4;

__device__ __forceinline__ float gelu_f(float x) {
    float t = tanhf(0.7978845608028654f * (x + 0.044715f * x * x * x));
    return 0.5f * x * (1.f + t);
}
__device__ __forceinline__ unsigned short f2bf(float f) {
    unsigned int u = __float_as_uint(f);
    u += 0x7FFFu + ((u >> 16) & 1u);
    return (unsigned short)(u >> 16);
}
__device__ __forceinline__ float bf2f(unsigned short u) {
    return __uint_as_float((unsigned int)u << 16);
}
// async global->LDS, 16B per lane; LDS dest wave-uniform base + lane*16
__device__ __forceinline__ void gl_lds16(const void* g, void* l) {
    __builtin_amdgcn_global_load_lds(
        (const __attribute__((address_space(1))) void*)g,
        (__attribute__((address_space(3))) void*)l, 16, 0, 0);
}

// ---------------- LayerNorm: one wave per row of 512; MODE 0=f32, 1=bf16, 2=both ----------------
template <int MODE>
__global__ __launch_bounds__(256) void ln_kernel(const float* __restrict__ x,
                                                 const float* __restrict__ s,
                                                 const float* __restrict__ b,
                                                 float* __restrict__ outf,
                                                 unsigned short* __restrict__ outb) {
    int wave = threadIdx.x >> 6, lane = threadIdx.x & 63;
    int row = blockIdx.x * 4 + wave;
    const float* xr = x + (size_t)row * DMODEL;
    float v[8];
    float sum = 0.f;
#pragma unroll
    for (int i = 0; i < 8; i++) { v[i] = xr[lane + i * 64]; sum += v[i]; }
#pragma unroll
    for (int o = 32; o; o >>= 1) sum += __shfl_xor(sum, o);
    float m = sum * (1.f / DMODEL);
    float vs = 0.f;
#pragma unroll
    for (int i = 0; i < 8; i++) { float d = v[i] - m; vs += d * d; }
#pragma unroll
    for (int o = 32; o; o >>= 1) vs += __shfl_xor(vs, o);
    float rstd = rsqrtf(vs * (1.f / DMODEL) + 1e-5f);
#pragma unroll
    for (int i = 0; i < 8; i++) {
        int c = lane + i * 64;
        float r = (v[i] - m) * rstd * s[c] + b[c];
        if (MODE != 1) outf[(size_t)row * DMODEL + c] = r;
        if (MODE != 0) outb[(size_t)row * DMODEL + c] = f2bf(r);
    }
}

// ---------------- weight transpose + fp32->bf16: src [K][N] -> dst [N][K] bf16 ----------------
__global__ __launch_bounds__(256) void wt_kernel(const float* __restrict__ src,
                                                 unsigned short* __restrict__ dst,
                                                 int K, int N) {
    src += (size_t)blockIdx.z * K * N;
    dst += (size_t)blockIdx.z * K * N;
    __shared__ float t[64][68];
    int k0 = blockIdx.y * 64, n0 = blockIdx.x * 64;
    int tid = threadIdx.x;
    int r = tid >> 2;
    int cb = (tid & 3) * 4;
#pragma unroll
    for (int i = 0; i < 4; i++)
        *(float4*)&t[r][cb + i * 16] = *(const float4*)(src + (size_t)(k0 + r) * N + n0 + cb + i * 16);
    __syncthreads();
    int g = tid & 7;
    int nr = tid >> 3;
#pragma unroll
    for (int i = 0; i < 2; i++) {
        int n = nr + i * 32;
        bf16x8 v;
#pragma unroll
        for (int j = 0; j < 8; j++) v[j] = (short)f2bf(t[g * 8 + j][n]);
        *(bf16x8*)(dst + (size_t)(n0 + n) * K + k0 + g * 8) = v;
    }
}

// ---------------- V transpose: qkv[.,1024+h*64+d] -> Vt[b,h,d,s] (bf16) ----------------
__global__ __launch_bounds__(256) void vtr_kernel(const unsigned short* __restrict__ QKV,
                                                  unsigned short* __restrict__ Vt) {
    int st = blockIdx.x, hh = blockIdx.y, bb = blockIdx.z;
    __shared__ unsigned short t[64][72];
    int r = threadIdx.x >> 3, g = threadIdx.x & 7;
#pragma unroll
    for (int i = 0; i < 2; i++) {
        int row = r + i * 32;
        bf16x8 v = *(const bf16x8*)(QKV + (size_t)(bb * SEQ + st * 64 + row) * 1536 + 1024 + hh * 64 + g * 8);
        *(bf16x8*)&t[row][g * 8] = v;
    }
    __syncthreads();
#pragma unroll
    for (int i = 0; i < 2; i++) {
        int d = r + i * 32;
        bf16x8 v;
#pragma unroll
        for (int j = 0; j < 8; j++) v[j] = (short)t[g * 8 + j][d];
        *(bf16x8*)(Vt + (size_t)((bb * NHEAD + hh) * 64 + d) * SEQ + st * 64 + g * 8) = v;
    }
}

// ---------------- bf16 MFMA GEMM (128x128 tile, BK=64, global_load_lds staging) ----------------
// LDS layout: linear dest per lane; XOR-swizzle pre-applied to the GLOBAL source offset
// (rule: both-sides-or-neither). ds_read side uses the same swizzle as before.
template <bool GELU, bool DORES, bool GATHER, bool EXPERT, bool OUTBF16, int SK = 1>
__global__ __launch_bounds__(256, 2) void gemm_mfma(
    const unsigned short* __restrict__ Ab, const unsigned short* __restrict__ Wt,
    const float* __restrict__ bias, const float* __restrict__ res,
    void* __restrict__ Cvoid, int M, int Nn, int Kk,
    const int* __restrict__ rowmap, const int* __restrict__ cntp,
    const int* __restrict__ offp, const int* __restrict__ tinfo) {
    int n0 = blockIdx.x * 128;
    int m0;
    size_t cbase = 0;
    int kbeg = 0, kend = Kk;
    if (EXPERT) {
        int t = blockIdx.y;
        if (t >= tinfo[0]) return;
        int e = tinfo[1 + 2 * t];
        m0 = tinfo[2 + 2 * t];
        M = cntp[e];
        Wt += (size_t)e * Nn * Kk;
        bias += (size_t)e * Nn;
        int oe = offp[e];
        cbase = (size_t)oe * Nn;
        if (GATHER) rowmap += oe;
        else Ab += (size_t)oe * Kk;
    } else {
        m0 = blockIdx.y * 128;
    }
    if (SK > 1) {
        int s = blockIdx.z;
        int chunk = Kk / SK;
        kbeg = s * chunk;
        kend = kbeg + chunk;
        cbase = (size_t)s * M * Nn;
    }
    __shared__ short As[128 * 64];
    __shared__ short Bs[128 * 64];
    char* asb = (char*)As;
    char* bsb = (char*)Bs;
    int tid = threadIdx.x;
    int wave = tid >> 6, lane = tid & 63;
    int wm = wave >> 1, wn = wave & 1;
    int l15 = lane & 15, l16 = lane >> 4;
    // staging geometry: lane covers row w*32 + j*8 + (lane>>3), 16B chunk (lane&7)
    int r8 = lane >> 3;                         // 0..7
    int srcoff = (((lane & 7) ^ r8) << 4);      // pre-swizzled byte offset in 128B row

    f32x4 acc[4][4];
#pragma unroll
    for (int m = 0; m < 4; m++)
#pragma unroll
        for (int n = 0; n < 4; n++)
#pragma unroll
            for (int j = 0; j < 4; j++) acc[m][n][j] = 0.f;

    for (int k0 = kbeg; k0 < kend; k0 += 64) {
        // ---- A tile: 4 issues/wave of 8 rows x 64k bf16 ----
#pragma unroll
        for (int j = 0; j < 4; j++) {
            int row = wave * 32 + j * 8 + r8;
            int grow = m0 + row;
            int arow = GATHER ? rowmap[grow] : grow;   // pad rows: rowmap=0 (memset), output discarded
            const char* src = (const char*)Ab + (((size_t)arow * Kk + k0) << 1) + srcoff;
            gl_lds16(src, asb + wave * 4096 + j * 1024);
        }
        // ---- B tile ----
#pragma unroll
        for (int j = 0; j < 4; j++) {
            int nrow = wave * 32 + j * 8 + r8;
            const char* src = (const char*)Wt + (((size_t)(n0 + nrow) * Kk + k0) << 1) + srcoff;
            gl_lds16(src, bsb + wave * 4096 + j * 1024);
        }
        __syncthreads();   // drains vmcnt -> LDS writes visible
#pragma unroll
        for (int kk = 0; kk < 2; kk++) {
            int k8 = kk * 4 + l16;
            bf16x8 a[4], b[4];
#pragma unroll
            for (int m = 0; m < 4; m++) {
                int row = wm * 64 + m * 16 + l15;
                a[m] = *(const bf16x8*)(asb + row * 128 + ((k8 * 16) ^ ((row & 7) << 4)));
            }
#pragma unroll
            for (int n = 0; n < 4; n++) {
                int row = wn * 64 + n * 16 + l15;
                b[n] = *(const bf16x8*)(bsb + row * 128 + ((k8 * 16) ^ ((row & 7) << 4)));
            }
#pragma unroll
            for (int m = 0; m < 4; m++)
#pragma unroll
                for (int n = 0; n < 4; n++)
                    acc[m][n] = __builtin_amdgcn_mfma_f32_16x16x32_bf16(a[m], b[n], acc[m][n], 0, 0, 0);
        }
        __syncthreads();
    }

#pragma unroll
    for (int m = 0; m < 4; m++) {
#pragma unroll
        for (int n = 0; n < 4; n++) {
            int col = n0 + wn * 64 + n * 16 + l15;
            float bv = (SK == 1 && bias) ? bias[col] : 0.f;
#pragma unroll
            for (int j = 0; j < 4; j++) {
                int row = m0 + wm * 64 + m * 16 + l16 * 4 + j;
                if (row >= M) continue;
                float val = acc[m][n][j] + bv;
                if (SK == 1 && GELU) val = gelu_f(val);
                if (SK == 1 && DORES) val += res[(size_t)row * Nn + col];
                if (SK == 1 && OUTBF16)
                    ((unsigned short*)Cvoid)[cbase + (size_t)row * Nn + col] = f2bf(val);
                else
                    ((float*)Cvoid)[cbase + (size_t)row * Nn + col] = val;
            }
        }
    }
}

// ---------------- split-K reduce (+bias +residual, optional MoE combine) ----------------
template <int SK, bool MOE>
__global__ __launch_bounds__(256) void reduce_kernel(
    const float* __restrict__ pbuf, const float* __restrict__ bias,
    const unsigned short* __restrict__ eogb, const float* __restrict__ topw,
    const int* __restrict__ pos, float* __restrict__ xb) {
    int idx = (blockIdx.x * 256 + threadIdx.x) * 4;
    int n = idx >> 9, col = idx & 511;
    float4 v = *(float4*)(xb + idx);
    float4 bv = *(const float4*)(bias + col);
    v.x += bv.x; v.y += bv.y; v.z += bv.z; v.w += bv.w;
#pragma unroll
    for (int s = 0; s < SK; s++) {
        float4 p = *(const float4*)(pbuf + (size_t)s * NTOK * DMODEL + idx);
        v.x += p.x; v.y += p.y; v.z += p.z; v.w += p.w;
    }
    if (MOE) {
#pragma unroll
        for (int k = 0; k < TOPK; k++) {
            float w = topw[n * TOPK + k];
            const unsigned short* e = eogb + (size_t)pos[n * TOPK + k] * DMODEL + col;
            ushort4 u = *(const ushort4*)e;
            v.x += w * bf2f(u.x); v.y += w * bf2f(u.y);
            v.z += w * bf2f(u.z); v.w += w * bf2f(u.w);
        }
    }
    *(float4*)(xb + idx) = v;
}

// ---------------- small fp32 GEMM (router only) ----------------
template <bool GELU>
__global__ __launch_bounds__(256) void gemm_tile(
    const float* __restrict__ A, const float* __restrict__ W,
    float* __restrict__ C, int M, int Nn, int Kk, int lda) {
    int n0 = blockIdx.x * 64;
    int m0 = blockIdx.y * 64;
    __shared__ float Asf[16][68];
    __shared__ float Wsf[16][68];
    int tid = threadIdx.x;
    int ml = tid >> 2, kl = (tid & 3) << 2;
    bool avalid = (m0 + ml) < M;
    int arow = m0 + ml;
    const float* aptr = A + (size_t)arow * lda + kl;
    int kr = tid >> 4, nc = (tid & 15) << 2;
    bool wvalid = (n0 + nc) < Nn;
    const float* wptr = W + (size_t)kr * Nn + n0 + nc;
    int tm = (tid >> 4) << 2, tn = (tid & 15) << 2;
    float acc[4][4] = {{0.f}};
    for (int k0 = 0; k0 < Kk; k0 += 16) {
        float4 av = make_float4(0.f, 0.f, 0.f, 0.f);
        float4 wv = make_float4(0.f, 0.f, 0.f, 0.f);
        if (avalid) av = *(const float4*)(aptr + k0);
        if (wvalid) wv = *(const float4*)(wptr + (size_t)k0 * Nn);
        Asf[kl + 0][ml] = av.x; Asf[kl + 1][ml] = av.y;
        Asf[kl + 2][ml] = av.z; Asf[kl + 3][ml] = av.w;
        *(float4*)&Wsf[kr][nc] = wv;
        __syncthreads();
#pragma unroll
        for (int kk = 0; kk < 16; kk++) {
            float4 a4 = *(const float4*)&Asf[kk][tm];
            float4 w4 = *(const float4*)&Wsf[kk][tn];
            acc[0][0] += a4.x * w4.x; acc[0][1] += a4.x * w4.y; acc[0][2] += a4.x * w4.z; acc[0][3] += a4.x * w4.w;
            acc[1][0] += a4.y * w4.x; acc[1][1] += a4.y * w4.y; acc[1][2] += a4.y * w4.z; acc[1][3] += a4.y * w4.w;
            acc[2][0] += a4.z * w4.x; acc[2][1] += a4.z * w4.y; acc[2][2] += a4.z * w4.z; acc[2][3] += a4.z * w4.w;
            acc[3][0] += a4.w * w4.x; acc[3][1] += a4.w * w4.y; acc[3][2] += a4.w * w4.z; acc[3][3] += a4.w * w4.w;
        }
        __syncthreads();
    }
#pragma unroll
    for (int i = 0; i < 4; i++) {
        int mm = m0 + tm + i;
        if (mm >= M) break;
        float* crow = C + (size_t)mm * Nn;
#pragma unroll
        for (int j = 0; j < 4; j++) {
            int nn = n0 + tn + j;
            if (nn >= Nn) continue;
            float val = acc[i][j];
            if (GELU) val = gelu_f(val);
            crow[nn] = val;
        }
    }
}

// ---------------- MFMA flash attention: block = (64 q-rows, head, batch), 4 waves ----------------
__global__ __launch_bounds__(256, 2) void attn_mfma(const unsigned short* __restrict__ QKV,
                                                    const unsigned short* __restrict__ Vt,
                                                    unsigned short* __restrict__ O) {
    int qt = blockIdx.x, hh = blockIdx.y, bb = blockIdx.z;
    __shared__ char lds[32768];
    char* Qs = lds;
    char* Ks = lds + 8192;
    char* Vs = lds + 16384;
    char* Ps = lds + 24576;
    int tid = threadIdx.x;
    int w = tid >> 6, l = tid & 63;
    int l15 = l & 15, l16 = l >> 4;

    {
        int r = tid >> 3, g = tid & 7;
        const unsigned short* qbase = QKV + (size_t)(bb * SEQ + qt * QBLK) * 1536 + hh * 64;
#pragma unroll
        for (int i = 0; i < 2; i++) {
            int row = r + i * 32;
            bf16x8 v = *(const bf16x8*)(qbase + (size_t)row * 1536 + g * 8);
            *(bf16x8*)(Qs + row * 128 + ((g * 16) ^ ((row & 7) << 4))) = v;
        }
    }
    f32x4 accO[4];
#pragma unroll
    for (int n = 0; n < 4; n++)
#pragma unroll
        for (int j = 0; j < 4; j++) accO[n][j] = 0.f;
    float m_r[4] = {-1e30f, -1e30f, -1e30f, -1e30f};
    float l_r[4] = {0.f, 0.f, 0.f, 0.f};

    const unsigned short* kbase = QKV + (size_t)(bb * SEQ) * 1536 + 512 + hh * 64;
    const unsigned short* vbase = Vt + (size_t)((bb * NHEAD + hh) * 64) * SEQ;

    for (int kt = 0; kt < SEQ / KBLK; kt++) {
        __syncthreads();
        {
            int r = tid >> 3, g = tid & 7;
#pragma unroll
            for (int i = 0; i < 2; i++) {
                int row = r + i * 32;
                bf16x8 kv = *(const bf16x8*)(kbase + (size_t)(kt * KBLK + row) * 1536 + g * 8);
                *(bf16x8*)(Ks + row * 128 + ((g * 16) ^ ((row & 7) << 4))) = kv;
                bf16x8 vv = *(const bf16x8*)(vbase + (size_t)row * SEQ + kt * KBLK + g * 8);
                *(bf16x8*)(Vs + row * 128 + ((g * 16) ^ ((row & 7) << 4))) = vv;
            }
        }
        __syncthreads();
        f32x4 s_acc[4];
#pragma unroll
        for (int n = 0; n < 4; n++)
#pragma unroll
            for (int j = 0; j < 4; j++) s_acc[n][j] = 0.f;
#pragma unroll
        for (int st = 0; st < 2; st++) {
            int kb = st * 64 + l16 * 16;
            int qrow = w * 16 + l15;
            bf16x8 a = *(const bf16x8*)(Qs + qrow * 128 + (kb ^ ((qrow & 7) << 4)));
#pragma unroll
            for (int n = 0; n < 4; n++) {
                int kr = n * 16 + l15;
                bf16x8 b = *(const bf16x8*)(Ks + kr * 128 + (kb ^ ((kr & 7) << 4)));
                s_acc[n] = __builtin_amdgcn_mfma_f32_16x16x32_bf16(a, b, s_acc[n], 0, 0, 0);
            }
        }
        char* pw = Ps + w * 2048;
#pragma unroll
        for (int j = 0; j < 4; j++) {
            float s0 = s_acc[0][j] * 0.125f, s1 = s_acc[1][j] * 0.125f;
            float s2 = s_acc[2][j] * 0.125f, s3 = s_acc[3][j] * 0.125f;
            float tmax = fmaxf(fmaxf(s0, s1), fmaxf(s2, s3));
#pragma unroll
            for (int o = 1; o < 16; o <<= 1) tmax = fmaxf(tmax, __shfl_xor(tmax, o));
            float mnew = fmaxf(m_r[j], tmax);
            float resc = __expf(m_r[j] - mnew);
            float p0 = __expf(s0 - mnew), p1 = __expf(s1 - mnew);
            float p2 = __expf(s2 - mnew), p3 = __expf(s3 - mnew);
            float ps = p0 + p1 + p2 + p3;
#pragma unroll
            for (int o = 1; o < 16; o <<= 1) ps += __shfl_xor(ps, o);
            l_r[j] = l_r[j] * resc + ps;
            m_r[j] = mnew;
            accO[0][j] *= resc; accO[1][j] *= resc;
            accO[2][j] *= resc; accO[3][j] *= resc;
            int prow = l16 * 4 + j;
            int sw = (prow & 7) << 4;
            *(unsigned short*)(pw + prow * 128 + ((2 * l15) ^ sw)) = f2bf(p0);
            *(unsigned short*)(pw + prow * 128 + ((2 * l15 + 32) ^ sw)) = f2bf(p1);
            *(unsigned short*)(pw + prow * 128 + ((2 * l15 + 64) ^ sw)) = f2bf(p2);
            *(unsigned short*)(pw + prow * 128 + ((2 * l15 + 96) ^ sw)) = f2bf(p3);
        }
#pragma unroll
        for (int st = 0; st < 2; st++) {
            int kb = st * 64 + l16 * 16;
            bf16x8 pa = *(const bf16x8*)(pw + l15 * 128 + (kb ^ ((l15 & 7) << 4)));
#pragma unroll
            for (int n = 0; n < 4; n++) {
                int vr = n * 16 + l15;
                bf16x8 vb = *(const bf16x8*)(Vs + vr * 128 + (kb ^ ((vr & 7) << 4)));
                accO[n] = __builtin_amdgcn_mfma_f32_16x16x32_bf16(pa, vb, accO[n], 0, 0, 0);
            }
        }
    }
    unsigned short* obase = O + (size_t)(bb * SEQ + qt * QBLK + w * 16) * DMODEL + hh * 64;
#pragma unroll
    for (int j = 0; j < 4; j++) {
        float inv = 1.f / l_r[j];
        int row = l16 * 4 + j;
#pragma unroll
        for (int n = 0; n < 4; n++)
            obase[(size_t)row * DMODEL + n * 16 + l15] = f2bf(accO[n][j] * inv);
    }
}

// ---------------- router: shuffle-reduced stats ----------------
__global__ __launch_bounds__(256) void router_topk(const float* __restrict__ rsc,
                                                   float* __restrict__ topw,
                                                   int* __restrict__ topi,
                                                   int* __restrict__ cnt,
                                                   float* __restrict__ sumP,
                                                   float* __restrict__ zacc) {
    __shared__ float wP[4][NEXP];
    __shared__ int wC[4][NEXP];
    __shared__ float wZ[4];
    int tid = threadIdx.x;
    int wv = tid >> 6, lane = tid & 63;
    int n = blockIdx.x * 256 + tid;
    float sc[NEXP];
    float mx = -1e30f;
#pragma unroll
    for (int e = 0; e < NEXP; e++) { sc[e] = rsc[n * NEXP + e]; mx = fmaxf(mx, sc[e]); }
    float se = 0.f;
#pragma unroll
    for (int e = 0; e < NEXP; e++) { sc[e] = expf(sc[e] - mx); se += sc[e]; }
    float invse = 1.f / se;
    float lse = mx + logf(se);
    float z = lse * lse;
#pragma unroll
    for (int o = 32; o; o >>= 1) z += __shfl_xor(z, o);
    if (lane == 0) wZ[wv] = z;
#pragma unroll
    for (int e = 0; e < NEXP; e++) {
        float pv = sc[e] * invse;
#pragma unroll
        for (int o = 32; o; o >>= 1) pv += __shfl_xor(pv, o);
        if (lane == 0) wP[wv][e] = pv;
    }
    float tv[TOPK]; int ti[TOPK];
#pragma unroll
    for (int k = 0; k < TOPK; k++) {
        float best = -1.f; int bi = 0;
#pragma unroll
        for (int e = 0; e < NEXP; e++) {
            if (sc[e] > best) { best = sc[e]; bi = e; }
        }
        tv[k] = best * invse; ti[k] = bi; sc[bi] = -1.f;
    }
    float s4 = tv[0] + tv[1] + tv[2] + tv[3];
#pragma unroll
    for (int k = 0; k < TOPK; k++) {
        topw[n * TOPK + k] = tv[k] / s4;
        topi[n * TOPK + k] = ti[k];
    }
#pragma unroll
    for (int e = 0; e < NEXP; e++) {
        unsigned long long b0 = __ballot(ti[0] == e);
        unsigned long long b1 = __ballot(ti[1] == e);
        unsigned long long b2 = __ballot(ti[2] == e);
        unsigned long long b3 = __ballot(ti[3] == e);
        if (lane == 0)
            wC[wv][e] = __popcll(b0) + __popcll(b1) + __popcll(b2) + __popcll(b3);
    }
    __syncthreads();
    if (tid < NEXP) {
        atomicAdd(&sumP[tid], wP[0][tid] + wP[1][tid] + wP[2][tid] + wP[3][tid]);
        atomicAdd(&cnt[tid], wC[0][tid] + wC[1][tid] + wC[2][tid] + wC[3][tid]);
    }
    if (tid == 0) atomicAdd(zacc, wZ[0] + wZ[1] + wZ[2] + wZ[3]);
}

// ---------------- scan (1 wave, shuffle prefix): padded offsets + tile map + aux ----------------
__global__ void scanaux_kernel(const int* __restrict__ cnt, int* __restrict__ poff,
                               int* __restrict__ tinfo,
                               const float* __restrict__ sumP, const float* __restrict__ zacc,
                               float* __restrict__ out_aux, int l) {
    int lane = threadIdx.x;
    int c = (lane < NEXP) ? cnt[lane] : 0;
    int nt = (c + 127) >> 7;
    int x = nt;
#pragma unroll
    for (int o = 1; o < 32; o <<= 1) {
        int y = __shfl_up(x, o);
        if (lane >= o) x += y;
    }
    int excl = x - nt;
    if (lane < NEXP) {
        poff[lane] = excl * 128;
        for (int i = 0; i < nt; i++) {
            tinfo[1 + 2 * (excl + i)] = lane;
            tinfo[2 + 2 * (excl + i)] = i * 128;
        }
    }
    float lb = (lane < NEXP) ? ((float)c / (float)NTOK) * (sumP[lane] / (float)NTOK) : 0.f;
#pragma unroll
    for (int o = 32; o; o >>= 1) lb += __shfl_xor(lb, o);
    if (lane == 31) {
        tinfo[0] = x;
        out_aux[l] = lb * (float)NEXP / (float)TOPK;
        out_aux[NLAYER + l] = zacc[0] / (float)NTOK;
    }
}

// ---------------- scatter: LDS-aggregated per-block bases ----------------
__global__ __launch_bounds__(256) void scatter_kernel(const int* __restrict__ topi,
                                                      const int* __restrict__ poff,
                                                      int* __restrict__ cursor,
                                                      int* __restrict__ perm,
                                                      int* __restrict__ pos) {
    __shared__ int lcnt[NEXP];
    __shared__ int lbase[NEXP];
    if (threadIdx.x < NEXP) lcnt[threadIdx.x] = 0;
    __syncthreads();
    int i = blockIdx.x * 256 + threadIdx.x;
    int e = topi[i];
    int lr = atomicAdd(&lcnt[e], 1);
    __syncthreads();
    if (threadIdx.x < NEXP && lcnt[threadIdx.x] > 0)
        lbase[threadIdx.x] = atomicAdd(&cursor[threadIdx.x], lcnt[threadIdx.x]);
    __syncthreads();
    int g = poff[e] + lbase[e] + lr;
    perm[g] = i >> 2;
    pos[i] = g;
}

// ---------------- launcher ----------------
extern "C" void kernel_launch(void* const* d_in, const int* in_sizes, int n_in,
                              void* d_out, int out_size, void* d_ws, size_t ws_size,
                              hipStream_t stream) {
    (void)in_sizes; (void)n_in; (void)out_size; (void)ws_size;
    const float* x_in  = (const float*)d_in[0];
    const float* ln1_s = (const float*)d_in[1];
    const float* ln1_b = (const float*)d_in[2];
    const float* ln2_s = (const float*)d_in[3];
    const float* ln2_b = (const float*)d_in[4];
    const float* wq = (const float*)d_in[5];
    const float* bq = (const float*)d_in[6];
    const float* wk = (const float*)d_in[7];
    const float* bk = (const float*)d_in[8];
    const float* wv = (const float*)d_in[9];
    const float* bv = (const float*)d_in[10];
    const float* wo = (const float*)d_in[11];
    const float* bo = (const float*)d_in[12];
    const float* rdw = (const float*)d_in[13];
    const float* ruw = (const float*)d_in[14];
    const float* w1 = (const float*)d_in[15];
    const float* b1 = (const float*)d_in[16];
    const float* w2 = (const float*)d_in[17];
    const float* b2 = (const float*)d_in[18];
    const float* ws1 = (const float*)d_in[19];
    const float* bs1 = (const float*)d_in[20];
    const float* ws2 = (const float*)d_in[21];
    const float* bs2 = (const float*)d_in[22];
    const float* fn_s = (const float*)d_in[23];
    const float* fn_b = (const float*)d_in[24];

    float* ws = (float*)d_ws;
    const size_t ND = (size_t)NTOK * DMODEL;
    const size_t PADROWS = (size_t)MAXTILE * 128;
    size_t o = 0;
    float* xb  = ws + o; o += ND;
    float* h   = ws + o; o += ND;
    unsigned short* hb     = (unsigned short*)(ws + o); o += ND / 2;
    unsigned short* qkv_bf = (unsigned short*)(ws + o); o += (size_t)NTOK * 1536 / 2;
    unsigned short* vT     = (unsigned short*)(ws + o); o += ND / 2;
    unsigned short* t1b    = (unsigned short*)(ws + o); o += ND / 2;
    unsigned short* hidb   = (unsigned short*)(ws + o); o += (size_t)NTOK * HSHARED / 2;
    unsigned short* eogb   = (unsigned short*)(ws + o); o += PADROWS * DMODEL / 2;
    float* pbuf = ws + o; o += 4 * ND;
    float* rdru = ws + o; o += (size_t)DMODEL * NEXP;
    float* rsc  = ws + o; o += (size_t)NTOK * NEXP;
    float* topw = ws + o; o += (size_t)NTOK * TOPK;
    float* bqkv = ws + o; o += 1536;
    int* topi = (int*)(ws + o); o += (size_t)NTOK * TOPK;
    int* pos  = (int*)(ws + o); o += (size_t)NTOK * TOPK;
    int* perm = (int*)(ws + o); o += PADROWS;
    int* stats = (int*)(ws + o); o += 256;
    int* tinfo = (int*)(ws + o); o += 512;
    int* cnt = stats;
    int* cursor = stats + 32;
    int* poff = stats + 64;
    float* sumP = (float*)(stats + 96);
    float* zacc = sumP + 32;
    unsigned short* wbf = (unsigned short*)(ws + o);
    const size_t DDu = (size_t)DMODEL * DMODEL;
    unsigned short* wqkvt = wbf;
    unsigned short* wot  = wqkvt + 3 * DDu;
    unsigned short* w1t  = wot + DDu;
    unsigned short* w2t  = w1t + (size_t)NEXP * DDu;
    unsigned short* ws1t = w2t + (size_t)NEXP * DDu;
    unsigned short* ws2t = ws1t + (size_t)DMODEL * HSHARED;

    float* out_x = (float*)d_out;
    float* out_aux = out_x + ND;

    hipMemcpyAsync(xb, x_in, ND * sizeof(float), hipMemcpyDeviceToDevice, stream);

    dim3 blk(256);
    dim3 gQKV(1536 / 128, NTOK / 128);
    dim3 gOP(DMODEL / 128, NTOK / 128, 2);
    dim3 gF2(DMODEL / 128, NTOK / 128, 4);
    dim3 gHS(HSHARED / 128, NTOK / 128);
    dim3 gE1(HEXP / 128, MAXTILE);
    dim3 gE2(DMODEL / 128, MAXTILE);

    for (int l = 0; l < NLAYER; l++) {
        const size_t DD = (size_t)DMODEL * DMODEL;
        // ---- weight transpose+convert ----
        wt_kernel<<<dim3(8, 8, 1), blk, 0, stream>>>(wq + l * DD, wqkvt, DMODEL, DMODEL);
        wt_kernel<<<dim3(8, 8, 1), blk, 0, stream>>>(wk + l * DD, wqkvt + DDu, DMODEL, DMODEL);
        wt_kernel<<<dim3(8, 8, 1), blk, 0, stream>>>(wv + l * DD, wqkvt + 2 * DDu, DMODEL, DMODEL);
        wt_kernel<<<dim3(8, 8, 1), blk, 0, stream>>>(wo + l * DD, wot, DMODEL, DMODEL);
        wt_kernel<<<dim3(8, 8, NEXP), blk, 0, stream>>>(w1 + (size_t)l * NEXP * DD, w1t, DMODEL, HEXP);
        wt_kernel<<<dim3(8, 8, NEXP), blk, 0, stream>>>(w2 + (size_t)l * NEXP * DD, w2t, HEXP, DMODEL);
        wt_kernel<<<dim3(HSHARED / 64, 8, 1), blk, 0, stream>>>(ws1 + (size_t)l * DMODEL * HSHARED, ws1t, DMODEL, HSHARED);
        wt_kernel<<<dim3(8, HSHARED / 64, 1), blk, 0, stream>>>(ws2 + (size_t)l * HSHARED * DMODEL, ws2t, HSHARED, DMODEL);
        hipMemcpyAsync(bqkv, bq + l * DMODEL, DMODEL * sizeof(float), hipMemcpyDeviceToDevice, stream);
        hipMemcpyAsync(bqkv + 512, bk + l * DMODEL, DMODEL * sizeof(float), hipMemcpyDeviceToDevice, stream);
        hipMemcpyAsync(bqkv + 1024, bv + l * DMODEL, DMODEL * sizeof(float), hipMemcpyDeviceToDevice, stream);
        // ---- router weight fold: rdru = rd @ ru ----
        gemm_tile<false><<<dim3(1, 8), blk, 0, stream>>>(
            rdw + (size_t)l * DMODEL * RRANK, ruw + (size_t)l * RRANK * NEXP, rdru, DMODEL, NEXP, RRANK, RRANK);

        // ---- LN1 (bf16 out only) ----
        ln_kernel<1><<<NTOK / 4, blk, 0, stream>>>(xb, ln1_s + l * DMODEL, ln1_b + l * DMODEL, nullptr, hb);
        // ---- fused QKV ----
        gemm_mfma<false, false, false, false, true><<<gQKV, blk, 0, stream>>>(
            hb, wqkvt, bqkv, nullptr, qkv_bf, NTOK, 1536, DMODEL, nullptr, nullptr, nullptr, nullptr);
        // ---- V transpose ----
        vtr_kernel<<<dim3(SEQ / 64, NHEAD, BATCH), blk, 0, stream>>>(qkv_bf, vT);
        // ---- MFMA attention ----
        attn_mfma<<<dim3(SEQ / QBLK, NHEAD, BATCH), blk, 0, stream>>>(qkv_bf, vT, t1b);
        // ---- out proj: split-K=2 + reduce ----
        gemm_mfma<false, false, false, false, false, 2><<<gOP, blk, 0, stream>>>(
            t1b, wot, nullptr, nullptr, pbuf, NTOK, DMODEL, DMODEL, nullptr, nullptr, nullptr, nullptr);
        reduce_kernel<2, false><<<ND / 1024, blk, 0, stream>>>(
            pbuf, bo + l * DMODEL, nullptr, nullptr, nullptr, xb);
        // ---- LN2 ----
        ln_kernel<2><<<NTOK / 4, blk, 0, stream>>>(xb, ln2_s + l * DMODEL, ln2_b + l * DMODEL, h, hb);
        // ---- router ----
        hipMemsetAsync(stats, 0, 640, stream);
        hipMemsetAsync(perm, 0, PADROWS * sizeof(int), stream);   // pad rows -> token 0 (outputs discarded)
        gemm_tile<false><<<dim3(1, NTOK / 64), blk, 0, stream>>>(
            h, rdru, rsc, NTOK, NEXP, DMODEL, DMODEL);
        router_topk<<<NTOK / 256, blk, 0, stream>>>(rsc, topw, topi, cnt, sumP, zacc);
        scanaux_kernel<<<1, 64, 0, stream>>>(cnt, poff, tinfo, sumP, zacc, out_aux, l);
        scatter_kernel<<<NTOK * TOPK / 256, blk, 0, stream>>>(topi, poff, cursor, perm, pos);
        // ---- expert FFN ----
        gemm_mfma<true, false, true, true, true><<<gE1, blk, 0, stream>>>(
            hb, w1t, b1 + (size_t)l * NEXP * HEXP, nullptr,
            hidb, 0, HEXP, DMODEL, perm, cnt, poff, tinfo);
        gemm_mfma<false, false, false, true, true><<<gE2, blk, 0, stream>>>(
            hidb, w2t, b2 + (size_t)l * NEXP * DMODEL, nullptr,
            eogb, 0, DMODEL, HEXP, nullptr, cnt, poff, tinfo);
        // ---- shared FFN1 ----
        gemm_mfma<true, false, false, false, true><<<gHS, blk, 0, stream>>>(
            hb, ws1t, bs1 + (size_t)l * HSHARED, nullptr,
            hidb, NTOK, HSHARED, DMODEL, nullptr, nullptr, nullptr, nullptr);
        // ---- shared FFN2: split-K=4 + fused reduce ----
        gemm_mfma<false, false, false, false, false, 4><<<gF2, blk, 0, stream>>>(
            hidb, ws2t, nullptr, nullptr, pbuf, NTOK, DMODEL, HSHARED, nullptr, nullptr, nullptr, nullptr);
        reduce_kernel<4, true><<<ND / 1024, blk, 0, stream>>>(
            pbuf, bs2 + l * DMODEL, eogb, topw, pos, xb);
    }
    ln_kernel<0><<<NTOK / 4, blk, 0, stream>>>(xb, fn_s, fn_b, out_x, nullptr);
}